// Round 1
// baseline (5866.416 us; speedup 1.0000x reference)
//
#include <hip/hip_runtime.h>
#include <math.h>

namespace {
constexpr int DIMC = 192;
constexpr int NB = 4;
constexpr int HH = 128, WW = 128;
constexpr int HW = HH * WW;              // 16384
constexpr int NH = 8, HD = 24;
constexpr int FW = 65;
constexpr int FHW = HH * FW;             // 8320
constexpr long PLANE = (long)DIMC * HH * FW;        // im-plane offset within batch: 1,597,440
constexpr long CBSZ  = (long)NB * 2 * DIMC * FHW;   // 12,779,520 floats per complex buffer
constexpr long OFF_CB0 = 0;
constexpr long OFF_CB1 = CBSZ;
constexpr long OFF_CB2 = 2 * CBSZ;
constexpr long OFF_A   = 3 * CBSZ;                       // 38,338,560 (chunk tmp / out1)
constexpr long OFF_E   = OFF_A + (long)NB * DIMC * HW;   // 50,921,472 (q2 / out2 tmp)
constexpr long OFF_S   = OFF_E + (long)NB * DIMC * HW;   // 63,504,384 (small)
constexpr long OFF_K2  = (long)NB * 2 * DIMC * HW;       // 25,165,824 (kv2 dw out)
constexpr long S_INVQ = OFF_S;                 // 768
constexpr long S_INVK = OFF_S + 768;           // 768
constexpr long S_WF   = OFF_S + 2048;          // 384*192 = 73728
constexpr long S_GP   = S_WF + (long)2 * DIMC * DIMC;   // 8*32*576 = 147456
constexpr long S_ATT  = S_GP + (long)8 * 32 * 576;      // 32*576 = 18432
}

// ---------- fused weight: Wf[o][c] = sum_m w_kv2[o][m] * w_proj1[m][c] ----------
__global__ void fusew_k(const float* __restrict__ wkv, const float* __restrict__ wproj,
                        float* __restrict__ wf) {
    int o = blockIdx.x;      // 0..383
    int c = threadIdx.x;     // 0..191
    float acc = 0.f;
    for (int m = 0; m < 192; ++m)
        acc += wkv[o * 192 + m] * wproj[m * 192 + c];
    wf[o * 192 + c] = acc;
}

// ---------- generic 1x1 conv (GEMM): out[b,o,p] = sum_c w[o,c] * in[b,c,p] ----------
__global__ void conv1x1_k(const float* __restrict__ in, long inBatch,
                          const float* __restrict__ w, int Cin,
                          float* __restrict__ out, long outBatch, int HWn) {
    int p = blockIdx.x * 256 + threadIdx.x;
    int o = blockIdx.y * 16;
    int b = blockIdx.z;
    const float* ip = in + (long)b * inBatch;
    float acc[16];
#pragma unroll
    for (int j = 0; j < 16; ++j) acc[j] = 0.f;
    bool ok = p < HWn;
    for (int c = 0; c < Cin; ++c) {
        float xv = ok ? ip[(long)c * HWn + p] : 0.f;
#pragma unroll
        for (int j = 0; j < 16; ++j) acc[j] += w[(o + j) * Cin + c] * xv;
    }
    if (ok) {
        float* op = out + (long)b * outBatch + (long)o * HWn + p;
#pragma unroll
        for (int j = 0; j < 16; ++j) op[(long)j * HWn] = acc[j];
    }
}

// ---------- depthwise 3x3, pad 1 ----------
__global__ void dw3_k(const float* __restrict__ in, long inBatch,
                      const float* __restrict__ w9,
                      float* __restrict__ out, long outBatch) {
    int p = blockIdx.x * 256 + threadIdx.x;
    int c = blockIdx.y, b = blockIdx.z;
    int y = p >> 7, x = p & 127;
    const float* ip = in + (long)b * inBatch + (long)c * HW;
    const float* wp = w9 + c * 9;
    float acc = 0.f;
#pragma unroll
    for (int ky = 0; ky < 3; ++ky) {
        int yy = y + ky - 1;
        if (yy < 0 || yy >= HH) continue;
#pragma unroll
        for (int kx = 0; kx < 3; ++kx) {
            int xx = x + kx - 1;
            if (xx < 0 || xx >= WW) continue;
            acc += ip[yy * WW + xx] * wp[ky * 3 + kx];
        }
    }
    out[(long)b * outBatch + (long)c * HW + p] = acc;
}

// ---------- row L2 norm (inverse, clamped) over HW per (b, channel-of-192) ----------
__global__ void rownorm_k(const float* __restrict__ x, long batchStride,
                          float* __restrict__ inv) {
    int r = blockIdx.x;               // 0..767
    int b = r / 192, c = r % 192;
    const float* p = x + (long)b * batchStride + (long)c * HW;
    float s = 0.f;
    for (int i = threadIdx.x; i < HW; i += 256) { float v = p[i]; s += v * v; }
    __shared__ float red[256];
    red[threadIdx.x] = s;
    __syncthreads();
    for (int st = 128; st > 0; st >>= 1) {
        if (threadIdx.x < st) red[threadIdx.x] += red[threadIdx.x + st];
        __syncthreads();
    }
    if (threadIdx.x == 0) inv[r] = 1.f / fmaxf(sqrtf(red[0]), 1e-12f);
}

// ---------- Gram partials: G[d][e] = sum_l q[d,l]*k[e,l], split over 8 l-slices ----------
__global__ __launch_bounds__(576) void gram_k(const float* __restrict__ q, long qB,
                                              const float* __restrict__ k, long kB,
                                              float* __restrict__ gp) {
    int bn = blockIdx.x;  // 0..31
    int ls = blockIdx.y;  // 0..7
    int b = bn >> 3, n = bn & 7;
    const float* qp = q + (long)b * qB + (long)(n * HD) * HW;
    const float* kp = k + (long)b * kB + (long)(n * HD) * HW;
    __shared__ float qs[HD][65], ks[HD][65];
    int tid = threadIdx.x;            // 0..575
    int d = tid / HD, e = tid % HD;
    float acc = 0.f;
    int l0 = ls * 2048, l1 = l0 + 2048;
    for (int l = l0; l < l1; l += 64) {
        __syncthreads();
        for (int idx = tid; idx < HD * 64; idx += 576) {
            int r = idx >> 6, j = idx & 63;
            qs[r][j] = qp[(long)r * HW + l + j];
            ks[r][j] = kp[(long)r * HW + l + j];
        }
        __syncthreads();
#pragma unroll 16
        for (int j = 0; j < 64; ++j) acc += qs[d][j] * ks[e][j];
    }
    gp[((long)ls * 32 + bn) * 576 + tid] = acc;
}

// ---------- normalize + temperature + softmax over e ----------
__global__ void softmax_k(const float* __restrict__ gp, const float* __restrict__ invq,
                          const float* __restrict__ invk, const float* __restrict__ temp,
                          float* __restrict__ attn) {
    int bn = blockIdx.x;
    int b = bn >> 3, n = bn & 7;
    int d = threadIdx.x;
    if (d >= HD) return;
    float t = temp[n];
    float iq = invq[b * 192 + n * HD + d];
    float row[HD];
#pragma unroll
    for (int e = 0; e < HD; ++e) {
        float g = 0.f;
        for (int s = 0; s < 8; ++s) g += gp[((long)s * 32 + bn) * 576 + d * HD + e];
        row[e] = g * iq * invk[b * 192 + n * HD + e] * t;
    }
    float m = row[0];
#pragma unroll
    for (int e = 1; e < HD; ++e) m = fmaxf(m, row[e]);
    float ssum = 0.f;
#pragma unroll
    for (int e = 0; e < HD; ++e) { row[e] = expf(row[e] - m); ssum += row[e]; }
    float is = 1.f / ssum;
#pragma unroll
    for (int e = 0; e < HD; ++e) attn[(long)bn * 576 + d * HD + e] = row[e] * is;
}

// ---------- out[d,p] = sum_e attn[d,e] * v[e,p] ----------
__global__ void attnapply_k(const float* __restrict__ attn, const float* __restrict__ v,
                            long vB, float* __restrict__ out, long outB) {
    int p = blockIdx.x * 256 + threadIdx.x;
    int bn = blockIdx.y;
    int b = bn >> 3, n = bn & 7;
    __shared__ float a[576];
    for (int i = threadIdx.x; i < 576; i += 256) a[i] = attn[(long)bn * 576 + i];
    __syncthreads();
    const float* vp = v + (long)b * vB + (long)(n * HD) * HW + p;
    float acc[HD];
#pragma unroll
    for (int d = 0; d < HD; ++d) acc[d] = 0.f;
    for (int e = 0; e < HD; ++e) {
        float vv = vp[(long)e * HW];
#pragma unroll
        for (int d = 0; d < HD; ++d) acc[d] += a[d * HD + e] * vv;
    }
    float* op = out + (long)b * outB + (long)(n * HD) * HW + p;
#pragma unroll
    for (int d = 0; d < HD; ++d) op[(long)d * HW] = acc[d];
}

// ---------- forward real row DFT: 128 real -> 65 complex, scaled 1/128 ----------
__global__ void fftrow_k(const float* __restrict__ x, float* __restrict__ o) {
    int y = blockIdx.x, c = blockIdx.y, b = blockIdx.z;
    int t = threadIdx.x;
    __shared__ float xs[128], twc[128], tws[128];
    {
        float s, co;
        sincosf(6.2831853071795864f * t / 128.f, &s, &co);
        twc[t] = co; tws[t] = s;
    }
    xs[t] = x[(((long)b * DIMC + c) * HH + y) * WW + t];
    __syncthreads();
    if (t < 65) {
        float re = 0.f, im = 0.f;
        for (int n = 0; n < 128; ++n) {
            int i = (t * n) & 127;
            float xv = xs[n];
            re += xv * twc[i];
            im -= xv * tws[i];
        }
        long base = (((long)b * 2 * DIMC + c) * HH + y) * FW + t;
        o[base] = re * (1.f / 128.f);
        o[base + PLANE] = im * (1.f / 128.f);
    }
}

// ---------- forward complex column DFT over y (128 pts) ----------
__global__ void fftcol_k(const float* __restrict__ in, float* __restrict__ o) {
    int kx = blockIdx.x, c = blockIdx.y, b = blockIdx.z;
    int t = threadIdx.x;
    __shared__ float xr[128], xi[128], twc[128], tws[128];
    {
        float s, co;
        sincosf(6.2831853071795864f * t / 128.f, &s, &co);
        twc[t] = co; tws[t] = s;
    }
    long base = ((long)b * 2 * DIMC + c) * HH * FW + kx;
    xr[t] = in[base + (long)t * FW];
    xi[t] = in[base + PLANE + (long)t * FW];
    __syncthreads();
    float re = 0.f, im = 0.f;
    for (int y2 = 0; y2 < 128; ++y2) {
        int i = (t * y2) & 127;
        float cc = twc[i], ss = tws[i];
        re += xr[y2] * cc + xi[y2] * ss;
        im += xi[y2] * cc - xr[y2] * ss;
    }
    o[base + (long)t * FW] = re;
    o[base + PLANE + (long)t * FW] = im;
}

// ---------- inverse complex column DFT (e^{+i}) ----------
__global__ void ifftcol_k(const float* __restrict__ in, float* __restrict__ o) {
    int kx = blockIdx.x, c = blockIdx.y, b = blockIdx.z;
    int t = threadIdx.x;
    __shared__ float xr[128], xi[128], twc[128], tws[128];
    {
        float s, co;
        sincosf(6.2831853071795864f * t / 128.f, &s, &co);
        twc[t] = co; tws[t] = s;
    }
    long base = ((long)b * 2 * DIMC + c) * HH * FW + kx;
    xr[t] = in[base + (long)t * FW];
    xi[t] = in[base + PLANE + (long)t * FW];
    __syncthreads();
    float re = 0.f, im = 0.f;
    for (int ky = 0; ky < 128; ++ky) {
        int i = (t * ky) & 127;
        float cc = twc[i], ss = tws[i];
        re += xr[ky] * cc - xi[ky] * ss;
        im += xr[ky] * ss + xi[ky] * cc;
    }
    o[base + (long)t * FW] = re;
    o[base + PLANE + (long)t * FW] = im;
}

// ---------- inverse real row DFT: 65 complex -> 128 real, scaled 1/128 ----------
__global__ void ifftrow_k(const float* __restrict__ in, float* __restrict__ o) {
    int y = blockIdx.x, c = blockIdx.y, b = blockIdx.z;
    int t = threadIdx.x;
    __shared__ float XR[65], XI[65], twc[128], tws[128];
    {
        float s, co;
        sincosf(6.2831853071795864f * t / 128.f, &s, &co);
        twc[t] = co; tws[t] = s;
    }
    long base = (((long)b * 2 * DIMC + c) * HH + y) * FW;
    if (t < 65) {
        XR[t] = in[base + t];
        XI[t] = in[base + PLANE + t];
    }
    __syncthreads();
    float acc = 0.f;
    for (int k = 1; k < 64; ++k) {
        int i = (k * t) & 127;
        acc += XR[k] * twc[i] - XI[k] * tws[i];
    }
    float v = XR[0] + ((t & 1) ? -XR[64] : XR[64]) + 2.f * acc;
    o[(((long)b * DIMC + c) * HH + y) * WW + t] = v * (1.f / 128.f);
}

// ---------- exact GELU in place ----------
__global__ void gelu_k(float* __restrict__ x, long n) {
    long i = (long)blockIdx.x * 256 + threadIdx.x;
    if (i < n) {
        float v = x[i];
        x[i] = 0.5f * v * (1.f + erff(v * 0.70710678118654752f));
    }
}

extern "C" void kernel_launch(void* const* d_in, const int* in_sizes, int n_in,
                              void* d_out, int out_size, void* d_ws, size_t ws_size,
                              hipStream_t stream) {
    const float* x        = (const float*)d_in[0];
    const float* w_qkv1   = (const float*)d_in[1];
    const float* w_qkv1dw = (const float*)d_in[2];
    const float* w_proj1  = (const float*)d_in[3];
    const float* w_fdfp1  = (const float*)d_in[4];
    const float* w_fdfp2  = (const float*)d_in[5];
    const float* w_kv2    = (const float*)d_in[6];
    const float* w_kv2dw  = (const float*)d_in[7];
    const float* w_proj2  = (const float*)d_in[8];
    const float* temp     = (const float*)d_in[9];
    float* out = (float*)d_out;
    float* ws  = (float*)d_ws;

    dim3 blk(256);

    // fused w_kv2 @ w_proj1
    fusew_k<<<384, 192, 0, stream>>>(w_kv2, w_proj1, ws + S_WF);

    // -------- stage 1: qkv = dw3(conv1x1(x)) in 3 channel chunks --------
    for (int ch = 0; ch < 3; ++ch) {
        conv1x1_k<<<dim3(HW / 256, 12, NB), blk, 0, stream>>>(
            x, (long)DIMC * HW, w_qkv1 + (long)ch * 192 * 192, 192,
            ws + OFF_A, (long)192 * HW, HW);
        dw3_k<<<dim3(HW / 256, 192, NB), blk, 0, stream>>>(
            ws + OFF_A, (long)192 * HW, w_qkv1dw + ch * 192 * 9,
            ws + (long)ch * 192 * HW, (long)576 * HW);
    }
    // norms of q1 (ch 0..191), k1 (ch 192..383)
    rownorm_k<<<768, blk, 0, stream>>>(ws, (long)576 * HW, ws + S_INVQ);
    rownorm_k<<<768, blk, 0, stream>>>(ws + (long)192 * HW, (long)576 * HW, ws + S_INVK);
    gram_k<<<dim3(32, 8), 576, 0, stream>>>(ws, (long)576 * HW,
                                            ws + (long)192 * HW, (long)576 * HW, ws + S_GP);
    softmax_k<<<32, 32, 0, stream>>>(ws + S_GP, ws + S_INVQ, ws + S_INVK, temp, ws + S_ATT);
    // out1 (attn output) -> A
    attnapply_k<<<dim3(HW / 256, 32), blk, 0, stream>>>(
        ws + S_ATT, ws + (long)384 * HW, (long)576 * HW, ws + OFF_A, (long)192 * HW);

    // -------- fdfp(x) -> q2 @ E (uses CB0..CB2, which B-region no longer needs) --------
    fftrow_k<<<dim3(HH, DIMC, NB), 128, 0, stream>>>(x, ws + OFF_CB0);
    fftcol_k<<<dim3(FW, DIMC, NB), 128, 0, stream>>>(ws + OFF_CB0, ws + OFF_CB1);
    conv1x1_k<<<dim3((FHW + 255) / 256, 24, NB), blk, 0, stream>>>(
        ws + OFF_CB1, (long)384 * FHW, w_fdfp1, 384, ws + OFF_CB2, (long)384 * FHW, FHW);
    gelu_k<<<(unsigned)(CBSZ / 256), blk, 0, stream>>>(ws + OFF_CB2, CBSZ);
    conv1x1_k<<<dim3((FHW + 255) / 256, 24, NB), blk, 0, stream>>>(
        ws + OFF_CB2, (long)384 * FHW, w_fdfp2, 384, ws + OFF_CB0, (long)384 * FHW, FHW);
    ifftcol_k<<<dim3(FW, DIMC, NB), 128, 0, stream>>>(ws + OFF_CB0, ws + OFF_CB1);
    ifftrow_k<<<dim3(HH, DIMC, NB), 128, 0, stream>>>(ws + OFF_CB1, ws + OFF_E);

    // -------- kv2 = dw3(conv1x1(out1, Wf)) --------
    conv1x1_k<<<dim3(HW / 256, 24, NB), blk, 0, stream>>>(
        ws + OFF_A, (long)192 * HW, ws + S_WF, 192, ws, (long)384 * HW, HW);
    dw3_k<<<dim3(HW / 256, 384, NB), blk, 0, stream>>>(
        ws, (long)384 * HW, w_kv2dw, ws + OFF_K2, (long)384 * HW);

    // -------- stage 2 attention --------
    rownorm_k<<<768, blk, 0, stream>>>(ws + OFF_E, (long)192 * HW, ws + S_INVQ);
    rownorm_k<<<768, blk, 0, stream>>>(ws + OFF_K2, (long)384 * HW, ws + S_INVK);
    gram_k<<<dim3(32, 8), 576, 0, stream>>>(ws + OFF_E, (long)192 * HW,
                                            ws + OFF_K2, (long)384 * HW, ws + S_GP);
    softmax_k<<<32, 32, 0, stream>>>(ws + S_GP, ws + S_INVQ, ws + S_INVK, temp, ws + S_ATT);
    // out2 pre-proj -> ws[0..12.58M)
    attnapply_k<<<dim3(HW / 256, 32), blk, 0, stream>>>(
        ws + S_ATT, ws + OFF_K2 + (long)192 * HW, (long)384 * HW, ws, (long)192 * HW);
    // final projection -> d_out
    conv1x1_k<<<dim3(HW / 256, 12, NB), blk, 0, stream>>>(
        ws, (long)192 * HW, w_proj2, 192, out, (long)192 * HW, HW);
}

// Round 2
// 2344.600 us; speedup vs baseline: 2.5021x; 2.5021x over previous
//
#include <hip/hip_runtime.h>
#include <math.h>

namespace {
constexpr int DIMC = 192;
constexpr int NB = 4;
constexpr int HH = 128, WW = 128;
constexpr int HW = HH * WW;              // 16384
constexpr int NH = 8, HD = 24;
constexpr int FW = 65;
constexpr int FHW = HH * FW;             // 8320
constexpr long PLANE = (long)DIMC * HH * FW;        // im-plane offset within batch
constexpr long CBSZ  = (long)NB * 2 * DIMC * FHW;   // floats per complex buffer
constexpr long OFF_CB0 = 0;
constexpr long OFF_CB1 = CBSZ;
constexpr long OFF_CB2 = 2 * CBSZ;
constexpr long OFF_A   = 3 * CBSZ;                       // chunk tmp / out1
constexpr long OFF_E   = OFF_A + (long)NB * DIMC * HW;   // q2 / out2 tmp
constexpr long OFF_S   = OFF_E + (long)NB * DIMC * HW;   // small
constexpr long OFF_K2  = (long)NB * 2 * DIMC * HW;       // kv2 dw out
constexpr long S_INVQ = OFF_S;
constexpr long S_INVK = OFF_S + 768;
constexpr long S_WF   = OFF_S + 2048;
constexpr long S_GP   = S_WF + (long)2 * DIMC * DIMC;
constexpr long S_ATT  = S_GP + (long)8 * 32 * 576;
}

// ---------- fused weight: Wf[o][c] = sum_m w_kv2[o][m] * w_proj1[m][c] ----------
__global__ void fusew_k(const float* __restrict__ wkv, const float* __restrict__ wproj,
                        float* __restrict__ wf) {
    int o = blockIdx.x;
    int c = threadIdx.x;
    float acc = 0.f;
    for (int m = 0; m < 192; ++m)
        acc += wkv[o * 192 + m] * wproj[m * 192 + c];
    wf[o * 192 + c] = acc;
}

// ---------- tiled 1x1 conv GEMM: out[b,o,p] = sum_c w[o,c] * in[b,c,p] ----------
// Block: 256 threads computes 64 o x 128 p. K streamed 16 at a time via LDS.
__global__ __launch_bounds__(256) void conv1x1_t(
        const float* __restrict__ in, long inBatch,
        const float* __restrict__ w, int Cin,
        float* __restrict__ out, long outBatch, int HWn) {
    __shared__ float Xs[16][128];
    __shared__ float Wsm[16][64];
    const int tid = threadIdx.x;
    const int tx = tid & 63;
    const int ty = tid >> 6;            // 0..3
    const int p0 = blockIdx.x * 128;
    const int o0 = blockIdx.y * 64;
    const int b = blockIdx.z;
    const float* ip = in + (long)b * inBatch + p0;
    const float* wp = w + (long)o0 * Cin;
    float acc[32];
#pragma unroll
    for (int j = 0; j < 32; ++j) acc[j] = 0.f;
    const int xr = tid >> 4;            // 0..15
    const int xc = (tid & 15) * 8;      // 0..120
    const int wo = tid & 63;
    const int wc = (tid >> 6) * 4;      // 0,4,8,12
    for (int c0 = 0; c0 < Cin; c0 += 16) {
        __syncthreads();
        const float* gx = ip + (long)(c0 + xr) * HWn + xc;
        float4 a0 = *(const float4*)gx;
        float4 a1 = *(const float4*)(gx + 4);
        *(float4*)&Xs[xr][xc] = a0;
        *(float4*)&Xs[xr][xc + 4] = a1;
        float4 wv = *(const float4*)(wp + (long)wo * Cin + c0 + wc);
        Wsm[wc][wo] = wv.x; Wsm[wc + 1][wo] = wv.y;
        Wsm[wc + 2][wo] = wv.z; Wsm[wc + 3][wo] = wv.w;
        __syncthreads();
#pragma unroll
        for (int cc = 0; cc < 16; ++cc) {
            float4 w0 = *(const float4*)&Wsm[cc][ty * 16];
            float4 w1 = *(const float4*)&Wsm[cc][ty * 16 + 4];
            float4 w2 = *(const float4*)&Wsm[cc][ty * 16 + 8];
            float4 w3 = *(const float4*)&Wsm[cc][ty * 16 + 12];
            float xa = Xs[cc][tx], xb = Xs[cc][tx + 64];
            acc[0]  += w0.x * xa; acc[1]  += w0.x * xb;
            acc[2]  += w0.y * xa; acc[3]  += w0.y * xb;
            acc[4]  += w0.z * xa; acc[5]  += w0.z * xb;
            acc[6]  += w0.w * xa; acc[7]  += w0.w * xb;
            acc[8]  += w1.x * xa; acc[9]  += w1.x * xb;
            acc[10] += w1.y * xa; acc[11] += w1.y * xb;
            acc[12] += w1.z * xa; acc[13] += w1.z * xb;
            acc[14] += w1.w * xa; acc[15] += w1.w * xb;
            acc[16] += w2.x * xa; acc[17] += w2.x * xb;
            acc[18] += w2.y * xa; acc[19] += w2.y * xb;
            acc[20] += w2.z * xa; acc[21] += w2.z * xb;
            acc[22] += w2.w * xa; acc[23] += w2.w * xb;
            acc[24] += w3.x * xa; acc[25] += w3.x * xb;
            acc[26] += w3.y * xa; acc[27] += w3.y * xb;
            acc[28] += w3.z * xa; acc[29] += w3.z * xb;
            acc[30] += w3.w * xa; acc[31] += w3.w * xb;
        }
    }
    float* op = out + (long)b * outBatch + (long)(o0 + ty * 16) * HWn + p0 + tx;
#pragma unroll
    for (int j = 0; j < 16; ++j) {
        op[0] = acc[2 * j]; op[64] = acc[2 * j + 1];
        op += HWn;
    }
}

// ---------- depthwise 3x3, pad 1 ----------
__global__ void dw3_k(const float* __restrict__ in, long inBatch,
                      const float* __restrict__ w9,
                      float* __restrict__ out, long outBatch) {
    int p = blockIdx.x * 256 + threadIdx.x;
    int c = blockIdx.y, b = blockIdx.z;
    int y = p >> 7, x = p & 127;
    const float* ip = in + (long)b * inBatch + (long)c * HW;
    const float* wp = w9 + c * 9;
    float acc = 0.f;
#pragma unroll
    for (int ky = 0; ky < 3; ++ky) {
        int yy = y + ky - 1;
        if (yy < 0 || yy >= HH) continue;
#pragma unroll
        for (int kx = 0; kx < 3; ++kx) {
            int xx = x + kx - 1;
            if (xx < 0 || xx >= WW) continue;
            acc += ip[yy * WW + xx] * wp[ky * 3 + kx];
        }
    }
    out[(long)b * outBatch + (long)c * HW + p] = acc;
}

// ---------- row L2 norm (inverse, clamped) ----------
__global__ void rownorm_k(const float* __restrict__ x, long batchStride,
                          float* __restrict__ inv) {
    int r = blockIdx.x;
    int b = r / 192, c = r % 192;
    const float* p = x + (long)b * batchStride + (long)c * HW;
    float s = 0.f;
    for (int i = threadIdx.x; i < HW; i += 256) { float v = p[i]; s += v * v; }
    __shared__ float red[256];
    red[threadIdx.x] = s;
    __syncthreads();
    for (int st = 128; st > 0; st >>= 1) {
        if (threadIdx.x < st) red[threadIdx.x] += red[threadIdx.x + st];
        __syncthreads();
    }
    if (threadIdx.x == 0) inv[r] = 1.f / fmaxf(sqrtf(red[0]), 1e-12f);
}

// ---------- Gram partials ----------
__global__ __launch_bounds__(576) void gram_k(const float* __restrict__ q, long qB,
                                              const float* __restrict__ k, long kB,
                                              float* __restrict__ gp) {
    int bn = blockIdx.x;
    int ls = blockIdx.y;
    int b = bn >> 3, n = bn & 7;
    const float* qp = q + (long)b * qB + (long)(n * HD) * HW;
    const float* kp = k + (long)b * kB + (long)(n * HD) * HW;
    __shared__ float qs[HD][65], ks[HD][65];
    int tid = threadIdx.x;
    int d = tid / HD, e = tid % HD;
    float acc = 0.f;
    int l0 = ls * 2048, l1 = l0 + 2048;
    for (int l = l0; l < l1; l += 64) {
        __syncthreads();
        for (int idx = tid; idx < HD * 64; idx += 576) {
            int r = idx >> 6, j = idx & 63;
            qs[r][j] = qp[(long)r * HW + l + j];
            ks[r][j] = kp[(long)r * HW + l + j];
        }
        __syncthreads();
#pragma unroll 16
        for (int j = 0; j < 64; ++j) acc += qs[d][j] * ks[e][j];
    }
    gp[((long)ls * 32 + bn) * 576 + tid] = acc;
}

// ---------- normalize + temperature + softmax ----------
__global__ void softmax_k(const float* __restrict__ gp, const float* __restrict__ invq,
                          const float* __restrict__ invk, const float* __restrict__ temp,
                          float* __restrict__ attn) {
    int bn = blockIdx.x;
    int b = bn >> 3, n = bn & 7;
    int d = threadIdx.x;
    if (d >= HD) return;
    float t = temp[n];
    float iq = invq[b * 192 + n * HD + d];
    float row[HD];
#pragma unroll
    for (int e = 0; e < HD; ++e) {
        float g = 0.f;
        for (int s = 0; s < 8; ++s) g += gp[((long)s * 32 + bn) * 576 + d * HD + e];
        row[e] = g * iq * invk[b * 192 + n * HD + e] * t;
    }
    float m = row[0];
#pragma unroll
    for (int e = 1; e < HD; ++e) m = fmaxf(m, row[e]);
    float ssum = 0.f;
#pragma unroll
    for (int e = 0; e < HD; ++e) { row[e] = expf(row[e] - m); ssum += row[e]; }
    float is = 1.f / ssum;
#pragma unroll
    for (int e = 0; e < HD; ++e) attn[(long)bn * 576 + d * HD + e] = row[e] * is;
}

// ---------- out[d,p] = sum_e attn[d,e] * v[e,p] ----------
__global__ void attnapply_k(const float* __restrict__ attn, const float* __restrict__ v,
                            long vB, float* __restrict__ out, long outB) {
    int p = blockIdx.x * 256 + threadIdx.x;
    int bn = blockIdx.y;
    int b = bn >> 3, n = bn & 7;
    __shared__ float a[576];
    for (int i = threadIdx.x; i < 576; i += 256) a[i] = attn[(long)bn * 576 + i];
    __syncthreads();
    const float* vp = v + (long)b * vB + (long)(n * HD) * HW + p;
    float acc[HD];
#pragma unroll
    for (int d = 0; d < HD; ++d) acc[d] = 0.f;
    for (int e = 0; e < HD; ++e) {
        float vv = vp[(long)e * HW];
#pragma unroll
        for (int d = 0; d < HD; ++d) acc[d] += a[d * HD + e] * vv;
    }
    float* op = out + (long)b * outB + (long)(n * HD) * HW + p;
#pragma unroll
    for (int d = 0; d < HD; ++d) op[(long)d * HW] = acc[d];
}

// ---------- forward real row DFT ----------
__global__ void fftrow_k(const float* __restrict__ x, float* __restrict__ o) {
    int y = blockIdx.x, c = blockIdx.y, b = blockIdx.z;
    int t = threadIdx.x;
    __shared__ float xs[128], twc[128], tws[128];
    {
        float s, co;
        sincosf(6.2831853071795864f * t / 128.f, &s, &co);
        twc[t] = co; tws[t] = s;
    }
    xs[t] = x[(((long)b * DIMC + c) * HH + y) * WW + t];
    __syncthreads();
    if (t < 65) {
        float re = 0.f, im = 0.f;
        for (int n = 0; n < 128; ++n) {
            int i = (t * n) & 127;
            float xv = xs[n];
            re += xv * twc[i];
            im -= xv * tws[i];
        }
        long base = (((long)b * 2 * DIMC + c) * HH + y) * FW + t;
        o[base] = re * (1.f / 128.f);
        o[base + PLANE] = im * (1.f / 128.f);
    }
}

// ---------- forward complex column DFT ----------
__global__ void fftcol_k(const float* __restrict__ in, float* __restrict__ o) {
    int kx = blockIdx.x, c = blockIdx.y, b = blockIdx.z;
    int t = threadIdx.x;
    __shared__ float xr[128], xi[128], twc[128], tws[128];
    {
        float s, co;
        sincosf(6.2831853071795864f * t / 128.f, &s, &co);
        twc[t] = co; tws[t] = s;
    }
    long base = ((long)b * 2 * DIMC + c) * HH * FW + kx;
    xr[t] = in[base + (long)t * FW];
    xi[t] = in[base + PLANE + (long)t * FW];
    __syncthreads();
    float re = 0.f, im = 0.f;
    for (int y2 = 0; y2 < 128; ++y2) {
        int i = (t * y2) & 127;
        float cc = twc[i], ss = tws[i];
        re += xr[y2] * cc + xi[y2] * ss;
        im += xi[y2] * cc - xr[y2] * ss;
    }
    o[base + (long)t * FW] = re;
    o[base + PLANE + (long)t * FW] = im;
}

// ---------- inverse complex column DFT ----------
__global__ void ifftcol_k(const float* __restrict__ in, float* __restrict__ o) {
    int kx = blockIdx.x, c = blockIdx.y, b = blockIdx.z;
    int t = threadIdx.x;
    __shared__ float xr[128], xi[128], twc[128], tws[128];
    {
        float s, co;
        sincosf(6.2831853071795864f * t / 128.f, &s, &co);
        twc[t] = co; tws[t] = s;
    }
    long base = ((long)b * 2 * DIMC + c) * HH * FW + kx;
    xr[t] = in[base + (long)t * FW];
    xi[t] = in[base + PLANE + (long)t * FW];
    __syncthreads();
    float re = 0.f, im = 0.f;
    for (int ky = 0; ky < 128; ++ky) {
        int i = (t * ky) & 127;
        float cc = twc[i], ss = tws[i];
        re += xr[ky] * cc - xi[ky] * ss;
        im += xr[ky] * ss + xi[ky] * cc;
    }
    o[base + (long)t * FW] = re;
    o[base + PLANE + (long)t * FW] = im;
}

// ---------- inverse real row DFT ----------
__global__ void ifftrow_k(const float* __restrict__ in, float* __restrict__ o) {
    int y = blockIdx.x, c = blockIdx.y, b = blockIdx.z;
    int t = threadIdx.x;
    __shared__ float XR[65], XI[65], twc[128], tws[128];
    {
        float s, co;
        sincosf(6.2831853071795864f * t / 128.f, &s, &co);
        twc[t] = co; tws[t] = s;
    }
    long base = (((long)b * 2 * DIMC + c) * HH + y) * FW;
    if (t < 65) {
        XR[t] = in[base + t];
        XI[t] = in[base + PLANE + t];
    }
    __syncthreads();
    float acc = 0.f;
    for (int k = 1; k < 64; ++k) {
        int i = (k * t) & 127;
        acc += XR[k] * twc[i] - XI[k] * tws[i];
    }
    float v = XR[0] + ((t & 1) ? -XR[64] : XR[64]) + 2.f * acc;
    o[(((long)b * DIMC + c) * HH + y) * WW + t] = v * (1.f / 128.f);
}

// ---------- exact GELU in place ----------
__global__ void gelu_k(float* __restrict__ x, long n) {
    long i = (long)blockIdx.x * 256 + threadIdx.x;
    if (i < n) {
        float v = x[i];
        x[i] = 0.5f * v * (1.f + erff(v * 0.70710678118654752f));
    }
}

extern "C" void kernel_launch(void* const* d_in, const int* in_sizes, int n_in,
                              void* d_out, int out_size, void* d_ws, size_t ws_size,
                              hipStream_t stream) {
    const float* x        = (const float*)d_in[0];
    const float* w_qkv1   = (const float*)d_in[1];
    const float* w_qkv1dw = (const float*)d_in[2];
    const float* w_proj1  = (const float*)d_in[3];
    const float* w_fdfp1  = (const float*)d_in[4];
    const float* w_fdfp2  = (const float*)d_in[5];
    const float* w_kv2    = (const float*)d_in[6];
    const float* w_kv2dw  = (const float*)d_in[7];
    const float* w_proj2  = (const float*)d_in[8];
    const float* temp     = (const float*)d_in[9];
    float* out = (float*)d_out;
    float* ws  = (float*)d_ws;

    dim3 blk(256);

    fusew_k<<<384, 192, 0, stream>>>(w_kv2, w_proj1, ws + S_WF);

    // -------- stage 1: qkv = dw3(conv1x1(x)) in 3 channel chunks --------
    for (int ch = 0; ch < 3; ++ch) {
        conv1x1_t<<<dim3(HW / 128, 3, NB), blk, 0, stream>>>(
            x, (long)DIMC * HW, w_qkv1 + (long)ch * 192 * 192, 192,
            ws + OFF_A, (long)192 * HW, HW);
        dw3_k<<<dim3(HW / 256, 192, NB), blk, 0, stream>>>(
            ws + OFF_A, (long)192 * HW, w_qkv1dw + ch * 192 * 9,
            ws + (long)ch * 192 * HW, (long)576 * HW);
    }
    rownorm_k<<<768, blk, 0, stream>>>(ws, (long)576 * HW, ws + S_INVQ);
    rownorm_k<<<768, blk, 0, stream>>>(ws + (long)192 * HW, (long)576 * HW, ws + S_INVK);
    gram_k<<<dim3(32, 8), 576, 0, stream>>>(ws, (long)576 * HW,
                                            ws + (long)192 * HW, (long)576 * HW, ws + S_GP);
    softmax_k<<<32, 32, 0, stream>>>(ws + S_GP, ws + S_INVQ, ws + S_INVK, temp, ws + S_ATT);
    attnapply_k<<<dim3(HW / 256, 32), blk, 0, stream>>>(
        ws + S_ATT, ws + (long)384 * HW, (long)576 * HW, ws + OFF_A, (long)192 * HW);

    // -------- fdfp(x) -> q2 @ E --------
    fftrow_k<<<dim3(HH, DIMC, NB), 128, 0, stream>>>(x, ws + OFF_CB0);
    fftcol_k<<<dim3(FW, DIMC, NB), 128, 0, stream>>>(ws + OFF_CB0, ws + OFF_CB1);
    conv1x1_t<<<dim3(FHW / 128, 6, NB), blk, 0, stream>>>(
        ws + OFF_CB1, (long)384 * FHW, w_fdfp1, 384, ws + OFF_CB2, (long)384 * FHW, FHW);
    gelu_k<<<(unsigned)(CBSZ / 256), blk, 0, stream>>>(ws + OFF_CB2, CBSZ);
    conv1x1_t<<<dim3(FHW / 128, 6, NB), blk, 0, stream>>>(
        ws + OFF_CB2, (long)384 * FHW, w_fdfp2, 384, ws + OFF_CB0, (long)384 * FHW, FHW);
    ifftcol_k<<<dim3(FW, DIMC, NB), 128, 0, stream>>>(ws + OFF_CB0, ws + OFF_CB1);
    ifftrow_k<<<dim3(HH, DIMC, NB), 128, 0, stream>>>(ws + OFF_CB1, ws + OFF_E);

    // -------- kv2 = dw3(conv1x1(out1, Wf)) --------
    conv1x1_t<<<dim3(HW / 128, 6, NB), blk, 0, stream>>>(
        ws + OFF_A, (long)192 * HW, ws + S_WF, 192, ws, (long)384 * HW, HW);
    dw3_k<<<dim3(HW / 256, 384, NB), blk, 0, stream>>>(
        ws, (long)384 * HW, w_kv2dw, ws + OFF_K2, (long)384 * HW);

    // -------- stage 2 attention --------
    rownorm_k<<<768, blk, 0, stream>>>(ws + OFF_E, (long)192 * HW, ws + S_INVQ);
    rownorm_k<<<768, blk, 0, stream>>>(ws + OFF_K2, (long)384 * HW, ws + S_INVK);
    gram_k<<<dim3(32, 8), 576, 0, stream>>>(ws + OFF_E, (long)192 * HW,
                                            ws + OFF_K2, (long)384 * HW, ws + S_GP);
    softmax_k<<<32, 32, 0, stream>>>(ws + S_GP, ws + S_INVQ, ws + S_INVK, temp, ws + S_ATT);
    attnapply_k<<<dim3(HW / 256, 32), blk, 0, stream>>>(
        ws + S_ATT, ws + OFF_K2 + (long)192 * HW, (long)384 * HW, ws, (long)192 * HW);
    conv1x1_t<<<dim3(HW / 128, 3, NB), blk, 0, stream>>>(
        ws, (long)192 * HW, w_proj2, 192, out, (long)192 * HW, HW);
}

// Round 3
// 1849.860 us; speedup vs baseline: 3.1713x; 1.2674x over previous
//
#include <hip/hip_runtime.h>
#include <math.h>

namespace {
constexpr int DIMC = 192;
constexpr int NB = 4;
constexpr int HH = 128, WW = 128;
constexpr int HW = HH * WW;              // 16384
constexpr int NH = 8, HD = 24;
constexpr int FP = 80;                   // padded kx width (65 valid)
// freq "transposed" layout L_T: [b][part*128+(y|ky)][c][kx80]
constexpr long LT_PART = 128L * 192 * FP;          // 1,966,080
constexpr long LT_B    = 2 * LT_PART;              // 3,932,160
constexpr long LT_ROW  = 192L * FP;                // 15360
// freq "channel" layout L_C: [b][part*192+c][ky][kx80]
constexpr long LC_CH   = 128L * FP;                // 10240
constexpr long LC_PART = 192L * LC_CH;             // 1,966,080
constexpr long LC_B    = 2 * LC_PART;              // 3,932,160
constexpr long XB  = 192L * HW;                    // 3,145,728 (x / q2 / out1 batch)
constexpr long CB0 = 0;
constexpr long CB1 = 15728640;
constexpr long CB2 = 31457280;
constexpr long OFF_T1 = 37748736;        // stage1 conv tmp / out1 (12,582,912)
constexpr long OFF_Q2 = 50331648;        // q2 (12,582,912)
constexpr long OFF_KT = 0;               // kv2 pre-dw tmp (25,165,824)
constexpr long OFF_KF = 25165824;        // kv2 final (25,165,824)
constexpr long OFF_O2 = 0;               // out2 tmp (12,582,912)
constexpr long SM_WF   = 62914560;       // 73,728
constexpr long SM_INVQ = 62988288;       // 768
constexpr long SM_INVK = 62989056;       // 768
constexpr long SM_GP   = 62989824;       // 147,456
constexpr long SM_ATT  = 63137280;       // 18,432
constexpr long SM_B1   = 63155712;       // 128*160
constexpr long SM_B2   = 63176192;       // 256*256
constexpr long SM_B3   = 63241728;       // 256*256
constexpr long SM_B4   = 63307264;       // 160*128
constexpr float PI2 = 6.283185307179586476f;
}

// ================= basis init =================
__global__ void initB1_k(float* __restrict__ B1) {       // [128 n][160 j]
    int idx = blockIdx.x * 256 + threadIdx.x;
    if (idx >= 128 * 160) return;
    int n = idx / 160, j = idx % 160;
    float v = 0.f;
    if (j < 65) {
        int i = (n * j) & 127;
        v = cosf(PI2 * i / 128.f) * (1.f / 128.f);
    } else if (j >= 80 && j < 145) {
        int jj = j - 80;
        int i = (n * jj) & 127;
        v = -sinf(PI2 * i / 128.f) * (1.f / 128.f);
    }
    B1[idx] = v;
}
__global__ void initB2_k(float* __restrict__ B2) {       // [256 m][256 cin]
    int idx = blockIdx.x * 256 + threadIdx.x;            // < 65536
    int m = idx >> 8, cin = idx & 255;
    int pd = m >> 7, ky = m & 127;
    int ps = cin >> 7, y = cin & 127;
    int i = (ky * y) & 127;
    float c, s; sincosf(PI2 * i / 128.f, &s, &c);
    float v = (pd == 0) ? (ps == 0 ? c : s) : (ps == 0 ? -s : c);
    B2[idx] = v;
}
__global__ void initB3_k(float* __restrict__ B3) {       // [256 m][256 cin]
    int idx = blockIdx.x * 256 + threadIdx.x;
    int m = idx >> 8, cin = idx & 255;
    int pd = m >> 7, y = m & 127;
    int ps = cin >> 7, ky = cin & 127;
    int i = (y * ky) & 127;
    float c, s; sincosf(PI2 * i / 128.f, &s, &c);
    float v = (pd == 0) ? (ps == 0 ? c : -s) : (ps == 0 ? s : c);
    B3[idx] = v;
}
__global__ void initB4_k(float* __restrict__ B4) {       // [160 k][128 n]
    int idx = blockIdx.x * 256 + threadIdx.x;
    if (idx >= 160 * 128) return;
    int k = idx / 128, n = idx % 128;
    float v = 0.f;
    if (k < 80) {
        int kx = k;
        if (kx == 0) v = 1.f / 128.f;
        else if (kx < 64) { int i = (kx * n) & 127; v = 2.f * cosf(PI2 * i / 128.f) / 128.f; }
        else if (kx == 64) { int i = (64 * n) & 127; v = cosf(PI2 * i / 128.f) / 128.f; }
    } else {
        int kx = k - 80;
        if (kx >= 1 && kx < 64) { int i = (kx * n) & 127; v = -2.f * sinf(PI2 * i / 128.f) / 128.f; }
    }
    B4[idx] = v;
}

// ---------- fused weight: Wf[o][c] = sum_m w_kv2[o][m] * w_proj1[m][c] ----------
__global__ void fusew_k(const float* __restrict__ wkv, const float* __restrict__ wproj,
                        float* __restrict__ wf) {
    int o = blockIdx.x;
    int c = threadIdx.x;
    float acc = 0.f;
    for (int m = 0; m < 192; ++m)
        acc += wkv[o * 192 + m] * wproj[m * 192 + c];
    wf[o * 192 + c] = acc;
}

// ================= K1: data x basis GEMM (contract fast axis) =================
// C[r][j] = sum_k A[r][k] * B[k][j] per (b,c) plane; 128 rows, NN=grid.y*32 cols.
__global__ __launch_bounds__(256) void k1_gemm(
    const float* __restrict__ A, const float* __restrict__ B, float* __restrict__ C,
    long aBatch, long aC, long aRow, int aSplit, long aHiOff, int KK, int bStride,
    long oBatch, long oC, long oRow, int oSplit, long oHiOff) {
    __shared__ float As[16][132];
    __shared__ float Bs[16][32];
    const int t = threadIdx.x;
    const long aBase = (long)blockIdx.z * aBatch + (long)blockIdx.x * aC;
    const long oBase = (long)blockIdx.z * oBatch + (long)blockIdx.x * oC;
    const int ct0 = blockIdx.y * 32;
    float acc[4][4];
#pragma unroll
    for (int i = 0; i < 4; ++i)
#pragma unroll
        for (int j = 0; j < 4; ++j) acc[i][j] = 0.f;
    const int rl = t >> 1;
    const int kp = (t & 1) * 8;
    const int bk = t >> 4;
    const int bc2 = (t & 15) * 2;
    const int rg = (t >> 3) * 4;
    const int cg = (t & 7) * 4;
    for (int k0 = 0; k0 < KK; k0 += 16) {
        __syncthreads();
        int kb = k0 + kp;
        long ak = (kb < aSplit) ? (long)kb : (long)(kb - aSplit) + aHiOff;
        const float* ga = A + aBase + (long)rl * aRow + ak;
        float4 v0 = *(const float4*)ga;
        float4 v1 = *(const float4*)(ga + 4);
        As[kp + 0][rl] = v0.x; As[kp + 1][rl] = v0.y;
        As[kp + 2][rl] = v0.z; As[kp + 3][rl] = v0.w;
        As[kp + 4][rl] = v1.x; As[kp + 5][rl] = v1.y;
        As[kp + 6][rl] = v1.z; As[kp + 7][rl] = v1.w;
        const float* gb = B + (long)(k0 + bk) * bStride + ct0 + bc2;
        Bs[bk][bc2] = gb[0]; Bs[bk][bc2 + 1] = gb[1];
        __syncthreads();
#pragma unroll
        for (int kk = 0; kk < 16; ++kk) {
            float4 av = *(const float4*)&As[kk][rg];
            float4 bv = *(const float4*)&Bs[kk][cg];
            acc[0][0] += av.x * bv.x; acc[0][1] += av.x * bv.y; acc[0][2] += av.x * bv.z; acc[0][3] += av.x * bv.w;
            acc[1][0] += av.y * bv.x; acc[1][1] += av.y * bv.y; acc[1][2] += av.y * bv.z; acc[1][3] += av.y * bv.w;
            acc[2][0] += av.z * bv.x; acc[2][1] += av.z * bv.y; acc[2][2] += av.z * bv.z; acc[2][3] += av.z * bv.w;
            acc[3][0] += av.w * bv.x; acc[3][1] += av.w * bv.y; acc[3][2] += av.w * bv.z; acc[3][3] += av.w * bv.w;
        }
    }
    int c4 = ct0 + cg;
    long cmap = (c4 < oSplit) ? (long)c4 : (long)(c4 - oSplit) + oHiOff;
#pragma unroll
    for (int i = 0; i < 4; ++i) {
        float* op = C + oBase + (long)(rg + i) * oRow + cmap;
        float4 v = make_float4(acc[i][0], acc[i][1], acc[i][2], acc[i][3]);
        *(float4*)op = v;
    }
}

// ================= K2: basis/weights x data GEMM (flexible strides) =================
// out[o][p] = sum_c w[o*Cin+c] * in[inOff(c)+p]; 64 o x 128 p per block.
__global__ __launch_bounds__(256) void k2_gemm(
    const float* __restrict__ in, long inBatch,
    const float* __restrict__ w, int Cin,
    float* __restrict__ out, long outBatch,
    int iShift, int iMask, long iHi, long iLo,
    int oShift, int oMask, long oHi, long oLo) {
    __shared__ float Xs[16][128];
    __shared__ float Wsm[16][64];
    const int tid = threadIdx.x;
    const int tx = tid & 63;
    const int ty = tid >> 6;
    const long p0 = (long)blockIdx.x * 128;
    const int o0 = blockIdx.y * 64;
    const float* ip = in + (long)blockIdx.z * inBatch + p0;
    const float* wp = w + (long)o0 * Cin;
    float acc[32];
#pragma unroll
    for (int j = 0; j < 32; ++j) acc[j] = 0.f;
    const int xr = tid >> 4;
    const int xc = (tid & 15) * 8;
    const int wo = tid & 63;
    const int wc = (tid >> 6) * 4;
    for (int c0 = 0; c0 < Cin; c0 += 16) {
        __syncthreads();
        int ci = c0 + xr;
        long ioff = (long)(ci >> iShift) * iHi + (long)(ci & iMask) * iLo;
        const float* gx = ip + ioff + xc;
        float4 a0 = *(const float4*)gx;
        float4 a1 = *(const float4*)(gx + 4);
        *(float4*)&Xs[xr][xc] = a0;
        *(float4*)&Xs[xr][xc + 4] = a1;
        float4 wv = *(const float4*)(wp + (long)wo * Cin + c0 + wc);
        Wsm[wc][wo] = wv.x; Wsm[wc + 1][wo] = wv.y;
        Wsm[wc + 2][wo] = wv.z; Wsm[wc + 3][wo] = wv.w;
        __syncthreads();
#pragma unroll
        for (int cc = 0; cc < 16; ++cc) {
            float4 w0 = *(const float4*)&Wsm[cc][ty * 16];
            float4 w1 = *(const float4*)&Wsm[cc][ty * 16 + 4];
            float4 w2 = *(const float4*)&Wsm[cc][ty * 16 + 8];
            float4 w3 = *(const float4*)&Wsm[cc][ty * 16 + 12];
            float xa = Xs[cc][tx], xb = Xs[cc][tx + 64];
            acc[0]  += w0.x * xa; acc[1]  += w0.x * xb;
            acc[2]  += w0.y * xa; acc[3]  += w0.y * xb;
            acc[4]  += w0.z * xa; acc[5]  += w0.z * xb;
            acc[6]  += w0.w * xa; acc[7]  += w0.w * xb;
            acc[8]  += w1.x * xa; acc[9]  += w1.x * xb;
            acc[10] += w1.y * xa; acc[11] += w1.y * xb;
            acc[12] += w1.z * xa; acc[13] += w1.z * xb;
            acc[14] += w1.w * xa; acc[15] += w1.w * xb;
            acc[16] += w2.x * xa; acc[17] += w2.x * xb;
            acc[18] += w2.y * xa; acc[19] += w2.y * xb;
            acc[20] += w2.z * xa; acc[21] += w2.z * xb;
            acc[22] += w2.w * xa; acc[23] += w2.w * xb;
            acc[24] += w3.x * xa; acc[25] += w3.x * xb;
            acc[26] += w3.y * xa; acc[27] += w3.y * xb;
            acc[28] += w3.z * xa; acc[29] += w3.z * xb;
            acc[30] += w3.w * xa; acc[31] += w3.w * xb;
        }
    }
    long bOff = (long)blockIdx.z * outBatch;
#pragma unroll
    for (int j = 0; j < 16; ++j) {
        int o = o0 + ty * 16 + j;
        long ooff = (long)(o >> oShift) * oHi + (long)(o & oMask) * oLo;
        out[bOff + ooff + p0 + tx] = acc[2 * j];
        out[bOff + ooff + p0 + tx + 64] = acc[2 * j + 1];
    }
}

// ================= transpose between L_T and L_C (ky <-> c) =================
__global__ void trs_k(const float* __restrict__ in, float* __restrict__ o,
                      long iKy, long iC, long oKy, long oC) {
    long ib = (long)blockIdx.z * LT_B + (long)blockIdx.y * LT_PART + (long)blockIdx.x * iC;
    long ob = (long)blockIdx.z * LT_B + (long)blockIdx.y * LT_PART + (long)blockIdx.x * oC;
    for (int idx = threadIdx.x; idx < 128 * FP; idx += 256) {
        int ky = idx / FP, kx = idx - ky * FP;
        o[ob + (long)ky * oKy + kx] = in[ib + (long)ky * iKy + kx];
    }
}

// ---------- depthwise 3x3, pad 1 ----------
__global__ void dw3_k(const float* __restrict__ in, long inBatch,
                      const float* __restrict__ w9,
                      float* __restrict__ out, long outBatch) {
    int p = blockIdx.x * 256 + threadIdx.x;
    int c = blockIdx.y, b = blockIdx.z;
    int y = p >> 7, x = p & 127;
    const float* ip = in + (long)b * inBatch + (long)c * HW;
    const float* wp = w9 + c * 9;
    float acc = 0.f;
#pragma unroll
    for (int ky = 0; ky < 3; ++ky) {
        int yy = y + ky - 1;
        if (yy < 0 || yy >= HH) continue;
#pragma unroll
        for (int kx = 0; kx < 3; ++kx) {
            int xx = x + kx - 1;
            if (xx < 0 || xx >= WW) continue;
            acc += ip[yy * WW + xx] * wp[ky * 3 + kx];
        }
    }
    out[(long)b * outBatch + (long)c * HW + p] = acc;
}

// ---------- row L2 norm (inverse, clamped) ----------
__global__ void rownorm_k(const float* __restrict__ x, long batchStride,
                          float* __restrict__ inv) {
    int r = blockIdx.x;
    int b = r / 192, c = r % 192;
    const float* p = x + (long)b * batchStride + (long)c * HW;
    float s = 0.f;
    for (int i = threadIdx.x; i < HW; i += 256) { float v = p[i]; s += v * v; }
    __shared__ float red[256];
    red[threadIdx.x] = s;
    __syncthreads();
    for (int st = 128; st > 0; st >>= 1) {
        if (threadIdx.x < st) red[threadIdx.x] += red[threadIdx.x + st];
        __syncthreads();
    }
    if (threadIdx.x == 0) inv[r] = 1.f / fmaxf(sqrtf(red[0]), 1e-12f);
}

// ---------- Gram partials ----------
__global__ __launch_bounds__(576) void gram_k(const float* __restrict__ q, long qB,
                                              const float* __restrict__ k, long kB,
                                              float* __restrict__ gp) {
    int bn = blockIdx.x;
    int ls = blockIdx.y;
    int b = bn >> 3, n = bn & 7;
    const float* qp = q + (long)b * qB + (long)(n * HD) * HW;
    const float* kp = k + (long)b * kB + (long)(n * HD) * HW;
    __shared__ float qs[HD][65], ks[HD][65];
    int tid = threadIdx.x;
    int d = tid / HD, e = tid % HD;
    float acc = 0.f;
    int l0 = ls * 2048, l1 = l0 + 2048;
    for (int l = l0; l < l1; l += 64) {
        __syncthreads();
        for (int idx = tid; idx < HD * 64; idx += 576) {
            int r = idx >> 6, j = idx & 63;
            qs[r][j] = qp[(long)r * HW + l + j];
            ks[r][j] = kp[(long)r * HW + l + j];
        }
        __syncthreads();
#pragma unroll 16
        for (int j = 0; j < 64; ++j) acc += qs[d][j] * ks[e][j];
    }
    gp[((long)ls * 32 + bn) * 576 + tid] = acc;
}

// ---------- normalize + temperature + softmax ----------
__global__ void softmax_k(const float* __restrict__ gp, const float* __restrict__ invq,
                          const float* __restrict__ invk, const float* __restrict__ temp,
                          float* __restrict__ attn) {
    int bn = blockIdx.x;
    int b = bn >> 3, n = bn & 7;
    int d = threadIdx.x;
    if (d >= HD) return;
    float t = temp[n];
    float iq = invq[b * 192 + n * HD + d];
    float row[HD];
#pragma unroll
    for (int e = 0; e < HD; ++e) {
        float g = 0.f;
        for (int s = 0; s < 8; ++s) g += gp[((long)s * 32 + bn) * 576 + d * HD + e];
        row[e] = g * iq * invk[b * 192 + n * HD + e] * t;
    }
    float m = row[0];
#pragma unroll
    for (int e = 1; e < HD; ++e) m = fmaxf(m, row[e]);
    float ssum = 0.f;
#pragma unroll
    for (int e = 0; e < HD; ++e) { row[e] = expf(row[e] - m); ssum += row[e]; }
    float is = 1.f / ssum;
#pragma unroll
    for (int e = 0; e < HD; ++e) attn[(long)bn * 576 + d * HD + e] = row[e] * is;
}

// ---------- out[d,p] = sum_e attn[d,e] * v[e,p] ----------
__global__ void attnapply_k(const float* __restrict__ attn, const float* __restrict__ v,
                            long vB, float* __restrict__ out, long outB) {
    int p = blockIdx.x * 256 + threadIdx.x;
    int bn = blockIdx.y;
    int b = bn >> 3, n = bn & 7;
    __shared__ float a[576];
    for (int i = threadIdx.x; i < 576; i += 256) a[i] = attn[(long)bn * 576 + i];
    __syncthreads();
    const float* vp = v + (long)b * vB + (long)(n * HD) * HW + p;
    float acc[HD];
#pragma unroll
    for (int d = 0; d < HD; ++d) acc[d] = 0.f;
    for (int e = 0; e < HD; ++e) {
        float vv = vp[(long)e * HW];
#pragma unroll
        for (int d = 0; d < HD; ++d) acc[d] += a[d * HD + e] * vv;
    }
    float* op = out + (long)b * outB + (long)(n * HD) * HW + p;
#pragma unroll
    for (int d = 0; d < HD; ++d) op[(long)d * HW] = acc[d];
}

// ---------- exact GELU in place ----------
__global__ void gelu_k(float* __restrict__ x, long n) {
    long i = (long)blockIdx.x * 256 + threadIdx.x;
    if (i < n) {
        float v = x[i];
        x[i] = 0.5f * v * (1.f + erff(v * 0.70710678118654752f));
    }
}

extern "C" void kernel_launch(void* const* d_in, const int* in_sizes, int n_in,
                              void* d_out, int out_size, void* d_ws, size_t ws_size,
                              hipStream_t stream) {
    const float* x        = (const float*)d_in[0];
    const float* w_qkv1   = (const float*)d_in[1];
    const float* w_qkv1dw = (const float*)d_in[2];
    const float* w_proj1  = (const float*)d_in[3];
    const float* w_fdfp1  = (const float*)d_in[4];
    const float* w_fdfp2  = (const float*)d_in[5];
    const float* w_kv2    = (const float*)d_in[6];
    const float* w_kv2dw  = (const float*)d_in[7];
    const float* w_proj2  = (const float*)d_in[8];
    const float* temp     = (const float*)d_in[9];
    float* out = (float*)d_out;
    float* ws  = (float*)d_ws;
    dim3 blk(256);

    // ---- init basis tables + fused weight ----
    initB1_k<<<80, blk, 0, stream>>>(ws + SM_B1);
    initB2_k<<<256, blk, 0, stream>>>(ws + SM_B2);
    initB3_k<<<256, blk, 0, stream>>>(ws + SM_B3);
    initB4_k<<<80, blk, 0, stream>>>(ws + SM_B4);
    fusew_k<<<384, 192, 0, stream>>>(w_kv2, w_proj1, ws + SM_WF);

    // ---- fdfp(x) -> q2 ----
    // row fwd DFT: x [b][c][y][n] -> CB0 (L_T, y-form)
    k1_gemm<<<dim3(192, 5, 4), blk, 0, stream>>>(
        x, ws + SM_B1, ws + CB0,
        XB, (long)HW, 128L, 100000, 0L, 128, 160,
        LT_B, (long)FP, LT_ROW, FP, LT_PART);
    // col fwd DFT: CB0 -> CB1 (L_T, ky-form)
    k2_gemm<<<dim3(120, 4, 4), blk, 0, stream>>>(
        ws + CB0, LT_B, ws + SM_B2, 256, ws + CB1, LT_B,
        7, 127, LT_PART, LT_ROW,
        7, 127, LT_PART, LT_ROW);
    // T1: CB1 (L_T ky) -> CB2 (L_C)
    trs_k<<<dim3(192, 2, 4), blk, 0, stream>>>(ws + CB1, ws + CB2,
                                               LT_ROW, (long)FP, (long)FP, LC_CH);
    // W1 channel conv: CB2 -> CB0
    k2_gemm<<<dim3(80, 6, 4), blk, 0, stream>>>(
        ws + CB2, LC_B, w_fdfp1, 384, ws + CB0, LC_B,
        0, 0, LC_CH, 0L,
        0, 0, LC_CH, 0L);
    gelu_k<<<61440, blk, 0, stream>>>(ws + CB0, 15728640L);
    // W2 channel conv: CB0 -> CB1
    k2_gemm<<<dim3(80, 6, 4), blk, 0, stream>>>(
        ws + CB0, LC_B, w_fdfp2, 384, ws + CB1, LC_B,
        0, 0, LC_CH, 0L,
        0, 0, LC_CH, 0L);
    // T2: CB1 (L_C) -> CB2 (L_T ky)
    trs_k<<<dim3(192, 2, 4), blk, 0, stream>>>(ws + CB1, ws + CB2,
                                               (long)FP, LC_CH, LT_ROW, (long)FP);
    // col inv DFT: CB2 -> CB0 (L_T y-form)
    k2_gemm<<<dim3(120, 4, 4), blk, 0, stream>>>(
        ws + CB2, LT_B, ws + SM_B3, 256, ws + CB0, LT_B,
        7, 127, LT_PART, LT_ROW,
        7, 127, LT_PART, LT_ROW);
    // row inv DFT: CB0 -> q2 [b][c][y][n]
    k1_gemm<<<dim3(192, 4, 4), blk, 0, stream>>>(
        ws + CB0, ws + SM_B4, ws + OFF_Q2,
        LT_B, (long)FP, LT_ROW, FP, LT_PART, 160, 128,
        XB, (long)HW, 128L, 100000, 0L);

    // ---- stage 1: qkv = dw3(conv1x1(x)) in 3 chunks -> qkv buf [b][576][HW] at ws[0..) ----
    for (int ch = 0; ch < 3; ++ch) {
        k2_gemm<<<dim3(128, 3, 4), blk, 0, stream>>>(
            x, XB, w_qkv1 + (long)ch * 192 * 192, 192, ws + OFF_T1, XB,
            0, 0, (long)HW, 0L,
            0, 0, (long)HW, 0L);
        dw3_k<<<dim3(64, 192, 4), blk, 0, stream>>>(
            ws + OFF_T1, XB, w_qkv1dw + ch * 192 * 9,
            ws + (long)ch * 192 * HW, (long)576 * HW);
    }
    rownorm_k<<<768, blk, 0, stream>>>(ws, (long)576 * HW, ws + SM_INVQ);
    rownorm_k<<<768, blk, 0, stream>>>(ws + (long)192 * HW, (long)576 * HW, ws + SM_INVK);
    gram_k<<<dim3(32, 8), 576, 0, stream>>>(ws, (long)576 * HW,
                                            ws + (long)192 * HW, (long)576 * HW, ws + SM_GP);
    softmax_k<<<32, 32, 0, stream>>>(ws + SM_GP, ws + SM_INVQ, ws + SM_INVK, temp, ws + SM_ATT);
    attnapply_k<<<dim3(64, 32), blk, 0, stream>>>(
        ws + SM_ATT, ws + (long)384 * HW, (long)576 * HW, ws + OFF_T1, XB);

    // ---- kv2 = dw3(conv1x1(out1, Wf)) ----
    k2_gemm<<<dim3(128, 6, 4), blk, 0, stream>>>(
        ws + OFF_T1, XB, ws + SM_WF, 192, ws + OFF_KT, (long)384 * HW,
        0, 0, (long)HW, 0L,
        0, 0, (long)HW, 0L);
    dw3_k<<<dim3(64, 384, 4), blk, 0, stream>>>(
        ws + OFF_KT, (long)384 * HW, w_kv2dw, ws + OFF_KF, (long)384 * HW);

    // ---- stage 2 attention ----
    rownorm_k<<<768, blk, 0, stream>>>(ws + OFF_Q2, XB, ws + SM_INVQ);
    rownorm_k<<<768, blk, 0, stream>>>(ws + OFF_KF, (long)384 * HW, ws + SM_INVK);
    gram_k<<<dim3(32, 8), 576, 0, stream>>>(ws + OFF_Q2, XB,
                                            ws + OFF_KF, (long)384 * HW, ws + SM_GP);
    softmax_k<<<32, 32, 0, stream>>>(ws + SM_GP, ws + SM_INVQ, ws + SM_INVK, temp, ws + SM_ATT);
    attnapply_k<<<dim3(64, 32), blk, 0, stream>>>(
        ws + SM_ATT, ws + OFF_KF + (long)192 * HW, (long)384 * HW, ws + OFF_O2, XB);
    k2_gemm<<<dim3(128, 3, 4), blk, 0, stream>>>(
        ws + OFF_O2, XB, w_proj2, 192, out, XB,
        0, 0, (long)HW, 0L,
        0, 0, (long)HW, 0L);
}

// Round 4
// 1116.393 us; speedup vs baseline: 5.2548x; 1.6570x over previous
//
#include <hip/hip_runtime.h>
#include <math.h>

typedef _Float16 half_t;
typedef half_t h8v __attribute__((ext_vector_type(8)));
typedef float f32x4 __attribute__((ext_vector_type(4)));

namespace {
constexpr int DIMC = 192;
constexpr int NB = 4;
constexpr int HH = 128, WW = 128;
constexpr int HW = HH * WW;              // 16384
constexpr int NH = 8, HD = 24;
constexpr int FP = 80;                   // padded kx width (65 valid)
constexpr long LT_PART = 128L * 192 * FP;          // 1,966,080
constexpr long LT_B    = 2 * LT_PART;              // 3,932,160
constexpr long LT_ROW  = 192L * FP;                // 15360
constexpr long XB  = 192L * HW;                    // 3,145,728
constexpr long CB0 = 0;
constexpr long CB1 = 15728640;
constexpr long CB2 = 31457280;
constexpr long OFF_T1 = 37748736;        // conv tmp / out1
constexpr long OFF_Q2 = 50331648;        // q2
constexpr long OFF_S  = 62914560;        // small region
constexpr long OFF_KT = 0;               // kv2 pre-dw tmp
constexpr long OFF_KF = 25165824;        // kv2 final
constexpr long OFF_O2 = 0;               // out2 tmp
constexpr long SM_INVQ = OFF_S;
constexpr long SM_INVK = OFF_S + 768;
constexpr long SM_ATT  = OFF_S + 2048;          // 18,432
constexpr long SM_GP   = OFF_S + 20480;         // 147,456
constexpr long H0      = OFF_S + 167936;        // fp16 pool (float units)
constexpr long H_WQKV = H0;                     // 110,592 h
constexpr long H_WF   = H0 + 55296;             // 73,728 h
constexpr long H_W1   = H0 + 92160;             // 147,456 h
constexpr long H_W2   = H0 + 165888;            // 147,456 h
constexpr long H_PRJ  = H0 + 239616;            // 36,864 h
constexpr long H_B2   = H0 + 258048;            // 65,536 h
constexpr long H_B3   = H0 + 290816;            // 65,536 h
constexpr long H_B1T  = H0 + 323584;            // 160x128 h
constexpr long H_B4T  = H0 + 333824;            // 128x160 h
constexpr float PI2 = 6.283185307179586476f;
}

// ================= init: fp16 weight/basis materialization =================
__global__ void cvt16_k(const float* __restrict__ in, half_t* __restrict__ o, int n) {
    int i = blockIdx.x * 256 + threadIdx.x;
    if (i < n) o[i] = (half_t)in[i];
}
__global__ void initB1t_k(half_t* __restrict__ B) {      // [160 j][128 k]
    int idx = blockIdx.x * 256 + threadIdx.x;
    if (idx >= 160 * 128) return;
    int j = idx / 128, k = idx % 128;
    float v = 0.f;
    if (j < 65) v = cosf(PI2 * ((k * j) & 127) / 128.f) * (1.f / 128.f);
    else if (j >= 80 && j < 145) v = -sinf(PI2 * ((k * (j - 80)) & 127) / 128.f) * (1.f / 128.f);
    B[idx] = (half_t)v;
}
__global__ void initB2h_k(half_t* __restrict__ B) {      // [256 m][256 c]
    int idx = blockIdx.x * 256 + threadIdx.x;
    int m = idx >> 8, cin = idx & 255;
    int pd = m >> 7, ky = m & 127;
    int ps = cin >> 7, y = cin & 127;
    float c, s; sincosf(PI2 * ((ky * y) & 127) / 128.f, &s, &c);
    float v = (pd == 0) ? (ps == 0 ? c : s) : (ps == 0 ? -s : c);
    B[idx] = (half_t)v;
}
__global__ void initB3h_k(half_t* __restrict__ B) {      // [256 m][256 c]
    int idx = blockIdx.x * 256 + threadIdx.x;
    int m = idx >> 8, cin = idx & 255;
    int pd = m >> 7, y = m & 127;
    int ps = cin >> 7, ky = cin & 127;
    float c, s; sincosf(PI2 * ((y * ky) & 127) / 128.f, &s, &c);
    float v = (pd == 0) ? (ps == 0 ? c : -s) : (ps == 0 ? s : c);
    B[idx] = (half_t)v;
}
__global__ void initB4t_k(half_t* __restrict__ B) {      // [128 j][160 k]
    int idx = blockIdx.x * 256 + threadIdx.x;
    if (idx >= 128 * 160) return;
    int j = idx / 160, k = idx % 160;
    float v = 0.f;
    if (k < 80) {
        if (k == 0) v = 1.f / 128.f;
        else if (k < 64) v = 2.f * cosf(PI2 * ((k * j) & 127) / 128.f) / 128.f;
        else if (k == 64) v = cosf(PI2 * ((64 * j) & 127) / 128.f) / 128.f;
    } else {
        int kx = k - 80;
        if (kx >= 1 && kx < 64) v = -2.f * sinf(PI2 * ((kx * j) & 127) / 128.f) / 128.f;
    }
    B[idx] = (half_t)v;
}
__global__ void fusew_k(const float* __restrict__ wkv, const float* __restrict__ wproj,
                        half_t* __restrict__ wf) {
    int o = blockIdx.x, c = threadIdx.x;
    float acc = 0.f;
    for (int m = 0; m < 192; ++m) acc += wkv[o * 192 + m] * wproj[m * 192 + c];
    wf[o * 192 + c] = (half_t)acc;
}

// ================= K2M: fp16-weights x fp32-data MFMA GEMM =================
// out[o][p] = sum_c W[o][c] * X[cmap(c)][p]; block tile 64 o x 256 p, 4 waves.
template<int PFOLD, int GELU>
__global__ __launch_bounds__(256) void k2m(
    const half_t* __restrict__ W16, int Cin,
    const float* __restrict__ X, long xBatch, int iSplit, long iLo, long iHi,
    float* __restrict__ out, long oBatch, int oSplit, long oLo, long oHi) {
    __shared__ __align__(16) half_t Wh[64 * 40];
    __shared__ __align__(16) half_t Xh[256 * 40];
    const int t = threadIdx.x;
    const int o0 = blockIdx.x * 64;
    const long p0 = (long)blockIdx.y * 256;
    const long xb = (long)blockIdx.z * xBatch;
    const long ob = (long)blockIdx.z * oBatch;
    const int lane = t & 63, wv = t >> 6;
    const int fr = lane & 15, fg = lane >> 4;
    const int so = t >> 2, scg = (t & 3) * 8;
    f32x4 acc[4][4];
#pragma unroll
    for (int m = 0; m < 4; ++m)
#pragma unroll
        for (int n = 0; n < 4; ++n) acc[m][n] = {0.f, 0.f, 0.f, 0.f};
    long pa;
    {
        long p = p0 + t;
        if (PFOLD) { long q = p / 80; pa = q * LT_ROW + (p - q * 80); } else pa = p;
    }
    for (int k0 = 0; k0 < Cin; k0 += 32) {
        __syncthreads();
        *(h8v*)&Wh[so * 40 + scg] =
            *(const h8v*)(W16 + (long)(o0 + so) * Cin + k0 + scg);
#pragma unroll
        for (int s = 0; s < 2; ++s) {
            int cb = k0 + s * 16;
            long rb = (cb < iSplit) ? (long)cb * iLo : (long)(cb - iSplit) * iLo + iHi;
            const float* g = X + xb + rb + pa;
            float v[16];
#pragma unroll
            for (int j = 0; j < 16; ++j) v[j] = g[(long)j * iLo];
            h8v h0, h1;
#pragma unroll
            for (int j = 0; j < 8; ++j) { h0[j] = (half_t)v[j]; h1[j] = (half_t)v[8 + j]; }
            *(h8v*)&Xh[t * 40 + s * 16] = h0;
            *(h8v*)&Xh[t * 40 + s * 16 + 8] = h1;
        }
        __syncthreads();
        h8v a[4], bb[4];
#pragma unroll
        for (int m = 0; m < 4; ++m) a[m] = *(const h8v*)&Wh[(m * 16 + fr) * 40 + fg * 8];
#pragma unroll
        for (int n = 0; n < 4; ++n) bb[n] = *(const h8v*)&Xh[(wv * 64 + n * 16 + fr) * 40 + fg * 8];
#pragma unroll
        for (int m = 0; m < 4; ++m)
#pragma unroll
            for (int n = 0; n < 4; ++n)
                acc[m][n] = __builtin_amdgcn_mfma_f32_16x16x32_f16(a[m], bb[n], acc[m][n], 0, 0, 0);
    }
    long pe[4];
#pragma unroll
    for (int n = 0; n < 4; ++n) {
        long p = p0 + wv * 64 + n * 16 + fr;
        if (PFOLD) { long q = p / 80; pe[n] = q * LT_ROW + (p - q * 80); } else pe[n] = p;
    }
#pragma unroll
    for (int m = 0; m < 4; ++m)
#pragma unroll
        for (int i = 0; i < 4; ++i) {
            int o = o0 + m * 16 + fg * 4 + i;
            long oadr = ob + ((o < oSplit) ? (long)o * oLo : (long)(o - oSplit) * oLo + oHi);
#pragma unroll
            for (int n = 0; n < 4; ++n) {
                float v = acc[m][n][i];
                if (GELU) v = 0.5f * v * (1.f + erff(v * 0.70710678118654752f));
                out[oadr + pe[n]] = v;
            }
        }
}

// ================= K1M: fp32-data x fp16-basis MFMA GEMM (k-contiguous A) ====
// C[r][j] = sum_k A[r][kmap(k)] * Bt[j][k]; one plane per block: 128 x (NF*32).
template<int NF>
__global__ __launch_bounds__(256) void k1m(
    const float* __restrict__ A, long aBatch, long aC, long aRow, int aSplit, long aHiOff, int K,
    const uint* __restrict__ Bt32,
    float* __restrict__ out, long oBatch, long oC, long oRow, int oSplit, long oHiOff) {
    __shared__ __align__(16) half_t Ah[128 * 40];
    __shared__ __align__(16) half_t Bh[160 * 40];
    const int t = threadIdx.x;
    const long ab = (long)blockIdx.z * aBatch + (long)blockIdx.x * aC;
    const long ob = (long)blockIdx.z * oBatch + (long)blockIdx.x * oC;
    const int N = NF * 32;
    const int lane = t & 63, wv = t >> 6;
    const int wm = wv >> 1, wn = wv & 1;
    const int fr = lane & 15, fg = lane >> 4;
    const int sr = t >> 1, shalf = t & 1;
    const int Kw = K >> 1;
    f32x4 acc[4][NF];
#pragma unroll
    for (int m = 0; m < 4; ++m)
#pragma unroll
        for (int n = 0; n < NF; ++n) acc[m][n] = {0.f, 0.f, 0.f, 0.f};
    for (int k0 = 0; k0 < K; k0 += 32) {
        __syncthreads();
        {
            int cb = k0 + shalf * 16;
            long rb = (cb < aSplit) ? (long)cb : (long)(cb - aSplit) + aHiOff;
            const float* g = A + ab + (long)sr * aRow + rb;
            float4 v0 = *(const float4*)g;
            float4 v1 = *(const float4*)(g + 4);
            float4 v2 = *(const float4*)(g + 8);
            float4 v3 = *(const float4*)(g + 12);
            h8v h0, h1;
            h0[0] = (half_t)v0.x; h0[1] = (half_t)v0.y; h0[2] = (half_t)v0.z; h0[3] = (half_t)v0.w;
            h0[4] = (half_t)v1.x; h0[5] = (half_t)v1.y; h0[6] = (half_t)v1.z; h0[7] = (half_t)v1.w;
            h1[0] = (half_t)v2.x; h1[1] = (half_t)v2.y; h1[2] = (half_t)v2.z; h1[3] = (half_t)v2.w;
            h1[4] = (half_t)v3.x; h1[5] = (half_t)v3.y; h1[6] = (half_t)v3.z; h1[7] = (half_t)v3.w;
            *(h8v*)&Ah[sr * 40 + shalf * 16] = h0;
            *(h8v*)&Ah[sr * 40 + shalf * 16 + 8] = h1;
        }
        for (int j = t; j < N * 16; j += 256) {
            int n = j >> 4, kw = j & 15;
            *(uint*)&Bh[n * 40 + kw * 2] = Bt32[(long)n * Kw + (k0 >> 1) + kw];
        }
        __syncthreads();
        h8v a[4], bb[NF];
#pragma unroll
        for (int m = 0; m < 4; ++m) a[m] = *(const h8v*)&Ah[(wm * 64 + m * 16 + fr) * 40 + fg * 8];
#pragma unroll
        for (int n = 0; n < NF; ++n) bb[n] = *(const h8v*)&Bh[(wn * NF * 16 + n * 16 + fr) * 40 + fg * 8];
#pragma unroll
        for (int m = 0; m < 4; ++m)
#pragma unroll
            for (int n = 0; n < NF; ++n)
                acc[m][n] = __builtin_amdgcn_mfma_f32_16x16x32_f16(a[m], bb[n], acc[m][n], 0, 0, 0);
    }
#pragma unroll
    for (int m = 0; m < 4; ++m)
#pragma unroll
        for (int i = 0; i < 4; ++i) {
            int r = wm * 64 + m * 16 + fg * 4 + i;
            float* orow = out + ob + (long)r * oRow;
#pragma unroll
            for (int n = 0; n < NF; ++n) {
                int j = wn * NF * 16 + n * 16 + fr;
                long jm = (j < oSplit) ? (long)j : (long)(j - oSplit) + oHiOff;
                orow[jm] = acc[m][n][i];
            }
        }
}

// ---------- depthwise 3x3, pad 1 ----------
__global__ void dw3_k(const float* __restrict__ in, long inBatch,
                      const float* __restrict__ w9,
                      float* __restrict__ out, long outBatch) {
    int p = blockIdx.x * 256 + threadIdx.x;
    int c = blockIdx.y, b = blockIdx.z;
    int y = p >> 7, x = p & 127;
    const float* ip = in + (long)b * inBatch + (long)c * HW;
    const float* wp = w9 + c * 9;
    float acc = 0.f;
#pragma unroll
    for (int ky = 0; ky < 3; ++ky) {
        int yy = y + ky - 1;
        if (yy < 0 || yy >= HH) continue;
#pragma unroll
        for (int kx = 0; kx < 3; ++kx) {
            int xx = x + kx - 1;
            if (xx < 0 || xx >= WW) continue;
            acc += ip[yy * WW + xx] * wp[ky * 3 + kx];
        }
    }
    out[(long)b * outBatch + (long)c * HW + p] = acc;
}

// ---------- row L2 norm (inverse, clamped) ----------
__global__ void rownorm_k(const float* __restrict__ x, long batchStride,
                          float* __restrict__ inv) {
    int r = blockIdx.x;
    int b = r / 192, c = r % 192;
    const float* p = x + (long)b * batchStride + (long)c * HW;
    float s = 0.f;
    for (int i = threadIdx.x; i < HW; i += 256) { float v = p[i]; s += v * v; }
    __shared__ float red[256];
    red[threadIdx.x] = s;
    __syncthreads();
    for (int st = 128; st > 0; st >>= 1) {
        if (threadIdx.x < st) red[threadIdx.x] += red[threadIdx.x + st];
        __syncthreads();
    }
    if (threadIdx.x == 0) inv[r] = 1.f / fmaxf(sqrtf(red[0]), 1e-12f);
}

// ---------- Gram partials ----------
__global__ __launch_bounds__(576) void gram_k(const float* __restrict__ q, long qB,
                                              const float* __restrict__ k, long kB,
                                              float* __restrict__ gp) {
    int bn = blockIdx.x;
    int ls = blockIdx.y;
    int b = bn >> 3, n = bn & 7;
    const float* qp = q + (long)b * qB + (long)(n * HD) * HW;
    const float* kp = k + (long)b * kB + (long)(n * HD) * HW;
    __shared__ float qs[HD][65], ks[HD][65];
    int tid = threadIdx.x;
    int d = tid / HD, e = tid % HD;
    float acc = 0.f;
    int l0 = ls * 2048, l1 = l0 + 2048;
    for (int l = l0; l < l1; l += 64) {
        __syncthreads();
        for (int idx = tid; idx < HD * 64; idx += 576) {
            int r = idx >> 6, j = idx & 63;
            qs[r][j] = qp[(long)r * HW + l + j];
            ks[r][j] = kp[(long)r * HW + l + j];
        }
        __syncthreads();
#pragma unroll 16
        for (int j = 0; j < 64; ++j) acc += qs[d][j] * ks[e][j];
    }
    gp[((long)ls * 32 + bn) * 576 + tid] = acc;
}

// ---------- normalize + temperature + softmax ----------
__global__ void softmax_k(const float* __restrict__ gp, const float* __restrict__ invq,
                          const float* __restrict__ invk, const float* __restrict__ temp,
                          float* __restrict__ attn) {
    int bn = blockIdx.x;
    int b = bn >> 3, n = bn & 7;
    int d = threadIdx.x;
    if (d >= HD) return;
    float t = temp[n];
    float iq = invq[b * 192 + n * HD + d];
    float row[HD];
#pragma unroll
    for (int e = 0; e < HD; ++e) {
        float g = 0.f;
        for (int s = 0; s < 8; ++s) g += gp[((long)s * 32 + bn) * 576 + d * HD + e];
        row[e] = g * iq * invk[b * 192 + n * HD + e] * t;
    }
    float m = row[0];
#pragma unroll
    for (int e = 1; e < HD; ++e) m = fmaxf(m, row[e]);
    float ssum = 0.f;
#pragma unroll
    for (int e = 0; e < HD; ++e) { row[e] = expf(row[e] - m); ssum += row[e]; }
    float is = 1.f / ssum;
#pragma unroll
    for (int e = 0; e < HD; ++e) attn[(long)bn * 576 + d * HD + e] = row[e] * is;
}

// ---------- out[d,p] = sum_e attn[d,e] * v[e,p] ----------
__global__ void attnapply_k(const float* __restrict__ attn, const float* __restrict__ v,
                            long vB, float* __restrict__ out, long outB) {
    int p = blockIdx.x * 256 + threadIdx.x;
    int bn = blockIdx.y;
    int b = bn >> 3, n = bn & 7;
    __shared__ float a[576];
    for (int i = threadIdx.x; i < 576; i += 256) a[i] = attn[(long)bn * 576 + i];
    __syncthreads();
    const float* vp = v + (long)b * vB + (long)(n * HD) * HW + p;
    float acc[HD];
#pragma unroll
    for (int d = 0; d < HD; ++d) acc[d] = 0.f;
    for (int e = 0; e < HD; ++e) {
        float vv = vp[(long)e * HW];
#pragma unroll
        for (int d = 0; d < HD; ++d) acc[d] += a[d * HD + e] * vv;
    }
    float* op = out + (long)b * outB + (long)(n * HD) * HW + p;
#pragma unroll
    for (int d = 0; d < HD; ++d) op[(long)d * HW] = acc[d];
}

extern "C" void kernel_launch(void* const* d_in, const int* in_sizes, int n_in,
                              void* d_out, int out_size, void* d_ws, size_t ws_size,
                              hipStream_t stream) {
    const float* x        = (const float*)d_in[0];
    const float* w_qkv1   = (const float*)d_in[1];
    const float* w_qkv1dw = (const float*)d_in[2];
    const float* w_proj1  = (const float*)d_in[3];
    const float* w_fdfp1  = (const float*)d_in[4];
    const float* w_fdfp2  = (const float*)d_in[5];
    const float* w_kv2    = (const float*)d_in[6];
    const float* w_kv2dw  = (const float*)d_in[7];
    const float* w_proj2  = (const float*)d_in[8];
    const float* temp     = (const float*)d_in[9];
    float* out = (float*)d_out;
    float* ws  = (float*)d_ws;
    dim3 blk(256);
    const int BIG = 1 << 20;

    // ---- init fp16 weights/bases ----
    cvt16_k<<<432, blk, 0, stream>>>(w_qkv1, (half_t*)(ws + H_WQKV), 110592);
    cvt16_k<<<576, blk, 0, stream>>>(w_fdfp1, (half_t*)(ws + H_W1), 147456);
    cvt16_k<<<576, blk, 0, stream>>>(w_fdfp2, (half_t*)(ws + H_W2), 147456);
    cvt16_k<<<144, blk, 0, stream>>>(w_proj2, (half_t*)(ws + H_PRJ), 36864);
    initB1t_k<<<80, blk, 0, stream>>>((half_t*)(ws + H_B1T));
    initB2h_k<<<256, blk, 0, stream>>>((half_t*)(ws + H_B2));
    initB3h_k<<<256, blk, 0, stream>>>((half_t*)(ws + H_B3));
    initB4t_k<<<80, blk, 0, stream>>>((half_t*)(ws + H_B4T));
    fusew_k<<<384, 192, 0, stream>>>(w_kv2, w_proj1, (half_t*)(ws + H_WF));

    // ---- fdfp(x) -> q2 ----
    // row fwd DFT: x -> CB0 (L_T y-form)
    k1m<5><<<dim3(192, 1, 4), blk, 0, stream>>>(
        x, XB, (long)HW, 128L, BIG, 0L, 128,
        (const uint*)(ws + H_B1T),
        ws + CB0, LT_B, (long)FP, LT_ROW, 80, LT_PART);
    // col fwd DFT: CB0 -> CB1
    k2m<0, 0><<<dim3(4, 60, 4), blk, 0, stream>>>(
        (const half_t*)(ws + H_B2), 256,
        ws + CB0, LT_B, 128, LT_ROW, LT_PART,
        ws + CB1, LT_B, 128, LT_ROW, LT_PART);
    // W1 + gelu: CB1 -> CB2
    k2m<1, 1><<<dim3(6, 40, 4), blk, 0, stream>>>(
        (const half_t*)(ws + H_W1), 384,
        ws + CB1, LT_B, 192, (long)FP, LT_PART,
        ws + CB2, LT_B, 192, (long)FP, LT_PART);
    // W2: CB2 -> CB0
    k2m<1, 0><<<dim3(6, 40, 4), blk, 0, stream>>>(
        (const half_t*)(ws + H_W2), 384,
        ws + CB2, LT_B, 192, (long)FP, LT_PART,
        ws + CB0, LT_B, 192, (long)FP, LT_PART);
    // col inv DFT: CB0 -> CB1
    k2m<0, 0><<<dim3(4, 60, 4), blk, 0, stream>>>(
        (const half_t*)(ws + H_B3), 256,
        ws + CB0, LT_B, 128, LT_ROW, LT_PART,
        ws + CB1, LT_B, 128, LT_ROW, LT_PART);
    // row inv DFT: CB1 -> q2
    k1m<4><<<dim3(192, 1, 4), blk, 0, stream>>>(
        ws + CB1, LT_B, (long)FP, LT_ROW, 80, LT_PART, 160,
        (const uint*)(ws + H_B4T),
        ws + OFF_Q2, XB, (long)HW, 128L, BIG, 0L);

    // ---- stage 1: qkv = dw3(conv1x1(x)) in 3 chunks -> [b][576][HW] at ws[0..) ----
    for (int ch = 0; ch < 3; ++ch) {
        k2m<0, 0><<<dim3(3, 64, 4), blk, 0, stream>>>(
            (const half_t*)(ws + H_WQKV) + (long)ch * 192 * 192, 192,
            x, XB, BIG, (long)HW, 0L,
            ws + OFF_T1, XB, BIG, (long)HW, 0L);
        dw3_k<<<dim3(64, 192, 4), blk, 0, stream>>>(
            ws + OFF_T1, XB, w_qkv1dw + ch * 192 * 9,
            ws + (long)ch * 192 * HW, (long)576 * HW);
    }
    rownorm_k<<<768, blk, 0, stream>>>(ws, (long)576 * HW, ws + SM_INVQ);
    rownorm_k<<<768, blk, 0, stream>>>(ws + (long)192 * HW, (long)576 * HW, ws + SM_INVK);
    gram_k<<<dim3(32, 8), 576, 0, stream>>>(ws, (long)576 * HW,
                                            ws + (long)192 * HW, (long)576 * HW, ws + SM_GP);
    softmax_k<<<32, 32, 0, stream>>>(ws + SM_GP, ws + SM_INVQ, ws + SM_INVK, temp, ws + SM_ATT);
    attnapply_k<<<dim3(64, 32), blk, 0, stream>>>(
        ws + SM_ATT, ws + (long)384 * HW, (long)576 * HW, ws + OFF_T1, XB);

    // ---- kv2 = dw3(conv1x1(out1, Wf)) ----
    k2m<0, 0><<<dim3(6, 64, 4), blk, 0, stream>>>(
        (const half_t*)(ws + H_WF), 192,
        ws + OFF_T1, XB, BIG, (long)HW, 0L,
        ws + OFF_KT, (long)384 * HW, BIG, (long)HW, 0L);
    dw3_k<<<dim3(64, 384, 4), blk, 0, stream>>>(
        ws + OFF_KT, (long)384 * HW, w_kv2dw, ws + OFF_KF, (long)384 * HW);

    // ---- stage 2 attention ----
    rownorm_k<<<768, blk, 0, stream>>>(ws + OFF_Q2, XB, ws + SM_INVQ);
    rownorm_k<<<768, blk, 0, stream>>>(ws + OFF_KF, (long)384 * HW, ws + SM_INVK);
    gram_k<<<dim3(32, 8), 576, 0, stream>>>(ws + OFF_Q2, XB,
                                            ws + OFF_KF, (long)384 * HW, ws + SM_GP);
    softmax_k<<<32, 32, 0, stream>>>(ws + SM_GP, ws + SM_INVQ, ws + SM_INVK, temp, ws + SM_ATT);
    attnapply_k<<<dim3(64, 32), blk, 0, stream>>>(
        ws + SM_ATT, ws + OFF_KF + (long)192 * HW, (long)384 * HW, ws + OFF_O2, XB);
    k2m<0, 0><<<dim3(3, 64, 4), blk, 0, stream>>>(
        (const half_t*)(ws + H_PRJ), 192,
        ws + OFF_O2, XB, BIG, (long)HW, 0L,
        out, XB, BIG, (long)HW, 0L);
}

// Round 5
// 809.278 us; speedup vs baseline: 7.2490x; 1.3795x over previous
//
#include <hip/hip_runtime.h>
#include <math.h>

typedef _Float16 half_t;
typedef half_t h8v __attribute__((ext_vector_type(8)));
typedef float f32x4 __attribute__((ext_vector_type(4)));

namespace {
constexpr int DIMC = 192;
constexpr int NB = 4;
constexpr int HH = 128, WW = 128;
constexpr int HW = HH * WW;              // 16384
constexpr int NH = 8, HD = 24;
constexpr int FP = 80;                   // padded kx width (65 valid)
constexpr long LT_PART = 128L * 192 * FP;          // 1,966,080
constexpr long LT_B    = 2 * LT_PART;              // 3,932,160
constexpr long LT_ROW  = 192L * FP;                // 15360
constexpr long XB  = 192L * HW;                    // 3,145,728
constexpr long CB0 = 0;
constexpr long CB1 = 15728640;
constexpr long CB2 = 31457280;
constexpr long OFF_T1 = 37748736;        // conv tmp / out1
constexpr long OFF_Q2 = 50331648;        // q2
constexpr long OFF_S  = 62914560;        // small region
constexpr long OFF_KT = 0;               // kv2 pre-dw tmp
constexpr long OFF_KF = 25165824;        // kv2 final
constexpr long OFF_O2 = 0;               // out2 tmp
constexpr long SM_INVQ1 = OFF_S;                // 768
constexpr long SM_INVK1 = OFF_S + 768;          // 768
constexpr long SM_INVQ2 = OFF_S + 1536;         // 768
constexpr long SM_INVK2 = OFF_S + 2304;         // 768
constexpr long SM_ATT   = OFF_S + 3072;         // 18,432
constexpr long SM_GP    = OFF_S + 21504;        // 147,456
constexpr long H0       = OFF_S + 168960;       // fp16 pool (float units)
constexpr long H_WQKV = H0;                     // 110,592 h
constexpr long H_WF   = H0 + 55296;             // 73,728 h
constexpr long H_W1   = H0 + 92160;             // 147,456 h
constexpr long H_W2   = H0 + 165888;            // 147,456 h
constexpr long H_PRJ  = H0 + 239616;            // 36,864 h
constexpr long H_B2   = H0 + 258048;            // 65,536 h
constexpr long H_B3   = H0 + 290816;            // 65,536 h
constexpr long H_B1T  = H0 + 323584;            // 160x128 h
constexpr long H_B4T  = H0 + 333824;            // 128x160 h
constexpr float PI2 = 6.283185307179586476f;
}

// ================= init: fp16 weight/basis materialization =================
__global__ void cvt16_k(const float* __restrict__ in, half_t* __restrict__ o, int n) {
    int i = blockIdx.x * 256 + threadIdx.x;
    if (i < n) o[i] = (half_t)in[i];
}
__global__ void initB1t_k(half_t* __restrict__ B) {      // [160 j][128 k]
    int idx = blockIdx.x * 256 + threadIdx.x;
    if (idx >= 160 * 128) return;
    int j = idx / 128, k = idx % 128;
    float v = 0.f;
    if (j < 65) v = cosf(PI2 * ((k * j) & 127) / 128.f) * (1.f / 128.f);
    else if (j >= 80 && j < 145) v = -sinf(PI2 * ((k * (j - 80)) & 127) / 128.f) * (1.f / 128.f);
    B[idx] = (half_t)v;
}
__global__ void initB2h_k(half_t* __restrict__ B) {      // [256 m][256 c]
    int idx = blockIdx.x * 256 + threadIdx.x;
    int m = idx >> 8, cin = idx & 255;
    int pd = m >> 7, ky = m & 127;
    int ps = cin >> 7, y = cin & 127;
    float c, s; sincosf(PI2 * ((ky * y) & 127) / 128.f, &s, &c);
    float v = (pd == 0) ? (ps == 0 ? c : s) : (ps == 0 ? -s : c);
    B[idx] = (half_t)v;
}
__global__ void initB3h_k(half_t* __restrict__ B) {      // [256 m][256 c]
    int idx = blockIdx.x * 256 + threadIdx.x;
    int m = idx >> 8, cin = idx & 255;
    int pd = m >> 7, y = m & 127;
    int ps = cin >> 7, ky = cin & 127;
    float c, s; sincosf(PI2 * ((y * ky) & 127) / 128.f, &s, &c);
    float v = (pd == 0) ? (ps == 0 ? c : -s) : (ps == 0 ? s : c);
    B[idx] = (half_t)v;
}
__global__ void initB4t_k(half_t* __restrict__ B) {      // [128 j][160 k]
    int idx = blockIdx.x * 256 + threadIdx.x;
    if (idx >= 128 * 160) return;
    int j = idx / 160, k = idx % 160;
    float v = 0.f;
    if (k < 80) {
        if (k == 0) v = 1.f / 128.f;
        else if (k < 64) v = 2.f * cosf(PI2 * ((k * j) & 127) / 128.f) / 128.f;
        else if (k == 64) v = cosf(PI2 * ((64 * j) & 127) / 128.f) / 128.f;
    } else {
        int kx = k - 80;
        if (kx >= 1 && kx < 64) v = -2.f * sinf(PI2 * ((kx * j) & 127) / 128.f) / 128.f;
    }
    B[idx] = (half_t)v;
}
__global__ void fusew_k(const float* __restrict__ wkv, const float* __restrict__ wproj,
                        half_t* __restrict__ wf) {
    int o = blockIdx.x, c = threadIdx.x;
    float acc = 0.f;
    for (int m = 0; m < 192; ++m) acc += wkv[o * 192 + m] * wproj[m * 192 + c];
    wf[o * 192 + c] = (half_t)acc;
}

// ================= K2M: fp16-weights x fp32-data MFMA GEMM =================
template<int PFOLD, int GELU>
__global__ __launch_bounds__(256) void k2m(
    const half_t* __restrict__ W16, int Cin,
    const float* __restrict__ X, long xBatch, int iSplit, long iLo, long iHi,
    float* __restrict__ out, long oBatch, int oSplit, long oLo, long oHi) {
    __shared__ __align__(16) half_t Wh[64 * 40];
    __shared__ __align__(16) half_t Xh[256 * 40];
    const int t = threadIdx.x;
    const int o0 = blockIdx.x * 64;
    const long p0 = (long)blockIdx.y * 256;
    const long xb = (long)blockIdx.z * xBatch;
    const long ob = (long)blockIdx.z * oBatch;
    const int lane = t & 63, wv = t >> 6;
    const int fr = lane & 15, fg = lane >> 4;
    const int so = t >> 2, scg = (t & 3) * 8;
    f32x4 acc[4][4];
#pragma unroll
    for (int m = 0; m < 4; ++m)
#pragma unroll
        for (int n = 0; n < 4; ++n) acc[m][n] = {0.f, 0.f, 0.f, 0.f};
    long pa;
    {
        long p = p0 + t;
        if (PFOLD) { long q = p / 80; pa = q * LT_ROW + (p - q * 80); } else pa = p;
    }
    for (int k0 = 0; k0 < Cin; k0 += 32) {
        __syncthreads();
        *(h8v*)&Wh[so * 40 + scg] =
            *(const h8v*)(W16 + (long)(o0 + so) * Cin + k0 + scg);
#pragma unroll
        for (int s = 0; s < 2; ++s) {
            int cb = k0 + s * 16;
            long rb = (cb < iSplit) ? (long)cb * iLo : (long)(cb - iSplit) * iLo + iHi;
            const float* g = X + xb + rb + pa;
            float v[16];
#pragma unroll
            for (int j = 0; j < 16; ++j) v[j] = g[(long)j * iLo];
            h8v h0, h1;
#pragma unroll
            for (int j = 0; j < 8; ++j) { h0[j] = (half_t)v[j]; h1[j] = (half_t)v[8 + j]; }
            *(h8v*)&Xh[t * 40 + s * 16] = h0;
            *(h8v*)&Xh[t * 40 + s * 16 + 8] = h1;
        }
        __syncthreads();
        h8v a[4], bb[4];
#pragma unroll
        for (int m = 0; m < 4; ++m) a[m] = *(const h8v*)&Wh[(m * 16 + fr) * 40 + fg * 8];
#pragma unroll
        for (int n = 0; n < 4; ++n) bb[n] = *(const h8v*)&Xh[(wv * 64 + n * 16 + fr) * 40 + fg * 8];
#pragma unroll
        for (int m = 0; m < 4; ++m)
#pragma unroll
            for (int n = 0; n < 4; ++n)
                acc[m][n] = __builtin_amdgcn_mfma_f32_16x16x32_f16(a[m], bb[n], acc[m][n], 0, 0, 0);
    }
    long pe[4];
#pragma unroll
    for (int n = 0; n < 4; ++n) {
        long p = p0 + wv * 64 + n * 16 + fr;
        if (PFOLD) { long q = p / 80; pe[n] = q * LT_ROW + (p - q * 80); } else pe[n] = p;
    }
#pragma unroll
    for (int m = 0; m < 4; ++m)
#pragma unroll
        for (int i = 0; i < 4; ++i) {
            int o = o0 + m * 16 + fg * 4 + i;
            long oadr = ob + ((o < oSplit) ? (long)o * oLo : (long)(o - oSplit) * oLo + oHi);
#pragma unroll
            for (int n = 0; n < 4; ++n) {
                float v = acc[m][n][i];
                if (GELU) v = 0.5f * v * (1.f + erff(v * 0.70710678118654752f));
                out[oadr + pe[n]] = v;
            }
        }
}

// ================= K1M: fp32-data x fp16-basis MFMA GEMM (k-contiguous A) ====
// Optionally fuses the plane L2-norm reduction (block == one (b,c) plane).
template<int NF, int NORM>
__global__ __launch_bounds__(256) void k1m(
    const float* __restrict__ A, long aBatch, long aC, long aRow, int aSplit, long aHiOff, int K,
    const uint* __restrict__ Bt32,
    float* __restrict__ out, long oBatch, long oC, long oRow, int oSplit, long oHiOff,
    float* __restrict__ inv) {
    __shared__ __align__(16) half_t Ah[128 * 40];
    __shared__ __align__(16) half_t Bh[160 * 40];
    const int t = threadIdx.x;
    const long ab = (long)blockIdx.z * aBatch + (long)blockIdx.x * aC;
    const long ob = (long)blockIdx.z * oBatch + (long)blockIdx.x * oC;
    const int N = NF * 32;
    const int lane = t & 63, wv = t >> 6;
    const int wm = wv >> 1, wn = wv & 1;
    const int fr = lane & 15, fg = lane >> 4;
    const int sr = t >> 1, shalf = t & 1;
    const int Kw = K >> 1;
    f32x4 acc[4][NF];
#pragma unroll
    for (int m = 0; m < 4; ++m)
#pragma unroll
        for (int n = 0; n < NF; ++n) acc[m][n] = {0.f, 0.f, 0.f, 0.f};
    for (int k0 = 0; k0 < K; k0 += 32) {
        __syncthreads();
        {
            int cb = k0 + shalf * 16;
            long rb = (cb < aSplit) ? (long)cb : (long)(cb - aSplit) + aHiOff;
            const float* g = A + ab + (long)sr * aRow + rb;
            float4 v0 = *(const float4*)g;
            float4 v1 = *(const float4*)(g + 4);
            float4 v2 = *(const float4*)(g + 8);
            float4 v3 = *(const float4*)(g + 12);
            h8v h0, h1;
            h0[0] = (half_t)v0.x; h0[1] = (half_t)v0.y; h0[2] = (half_t)v0.z; h0[3] = (half_t)v0.w;
            h0[4] = (half_t)v1.x; h0[5] = (half_t)v1.y; h0[6] = (half_t)v1.z; h0[7] = (half_t)v1.w;
            h1[0] = (half_t)v2.x; h1[1] = (half_t)v2.y; h1[2] = (half_t)v2.z; h1[3] = (half_t)v2.w;
            h1[4] = (half_t)v3.x; h1[5] = (half_t)v3.y; h1[6] = (half_t)v3.z; h1[7] = (half_t)v3.w;
            *(h8v*)&Ah[sr * 40 + shalf * 16] = h0;
            *(h8v*)&Ah[sr * 40 + shalf * 16 + 8] = h1;
        }
        for (int j = t; j < N * 16; j += 256) {
            int n = j >> 4, kw = j & 15;
            *(uint*)&Bh[n * 40 + kw * 2] = Bt32[(long)n * Kw + (k0 >> 1) + kw];
        }
        __syncthreads();
        h8v a[4], bb[NF];
#pragma unroll
        for (int m = 0; m < 4; ++m) a[m] = *(const h8v*)&Ah[(wm * 64 + m * 16 + fr) * 40 + fg * 8];
#pragma unroll
        for (int n = 0; n < NF; ++n) bb[n] = *(const h8v*)&Bh[(wn * NF * 16 + n * 16 + fr) * 40 + fg * 8];
#pragma unroll
        for (int m = 0; m < 4; ++m)
#pragma unroll
            for (int n = 0; n < NF; ++n)
                acc[m][n] = __builtin_amdgcn_mfma_f32_16x16x32_f16(a[m], bb[n], acc[m][n], 0, 0, 0);
    }
#pragma unroll
    for (int m = 0; m < 4; ++m)
#pragma unroll
        for (int i = 0; i < 4; ++i) {
            int r = wm * 64 + m * 16 + fg * 4 + i;
            float* orow = out + ob + (long)r * oRow;
#pragma unroll
            for (int n = 0; n < NF; ++n) {
                int j = wn * NF * 16 + n * 16 + fr;
                long jm = (j < oSplit) ? (long)j : (long)(j - oSplit) + oHiOff;
                orow[jm] = acc[m][n][i];
            }
        }
    if (NORM) {
        float ss = 0.f;
#pragma unroll
        for (int m = 0; m < 4; ++m)
#pragma unroll
            for (int n = 0; n < NF; ++n)
#pragma unroll
                for (int i = 0; i < 4; ++i) ss += acc[m][n][i] * acc[m][n][i];
        __syncthreads();
        float* red = (float*)Ah;
        red[t] = ss;
        __syncthreads();
        for (int st = 128; st > 0; st >>= 1) {
            if (t < st) red[t] += red[t + st];
            __syncthreads();
        }
        if (t == 0) inv[(long)blockIdx.z * 192 + blockIdx.x] = 1.f / fmaxf(sqrtf(red[0]), 1e-12f);
    }
}

// ---------- depthwise 3x3, pad 1: one block per (channel, batch) plane ----------
// Thread: 4 consecutive cols x 16-row stripe, rolling 3-row register window.
// Optionally fuses plane sum-of-squares -> inv (channels < normCnt).
__global__ __launch_bounds__(256) void dw3_k(
    const float* __restrict__ in, long inBatch,
    const float* __restrict__ w9,
    float* __restrict__ out, long outBatch,
    int normCnt, float* __restrict__ inv) {
    const int c = blockIdx.x, b = blockIdx.y;
    const int t = threadIdx.x;
    const float* ip = in + (long)b * inBatch + (long)c * HW;
    float* op = out + (long)b * outBatch + (long)c * HW;
    const float* wp = w9 + c * 9;
    const float w0 = wp[0], w1 = wp[1], w2 = wp[2];
    const float w3 = wp[3], w4 = wp[4], w5 = wp[5];
    const float w6 = wp[6], w7 = wp[7], w8 = wp[8];
    const int tx = t & 31;
    const int x0 = tx * 4;
    const int y0 = (t >> 5) * 16;
    const bool lx = (tx > 0), rx = (tx < 31);
    float Ar[6], Br[6], Cr[6];
#define LOADROW(Y, R) do { \
        const float* _p = ip + (Y) * 128 + x0; \
        float4 _v = *(const float4*)_p; \
        R[1] = _v.x; R[2] = _v.y; R[3] = _v.z; R[4] = _v.w; \
        R[0] = lx ? _p[-1] : 0.f; \
        R[5] = rx ? _p[4] : 0.f; } while (0)
    if (y0 == 0) { Ar[0]=Ar[1]=Ar[2]=Ar[3]=Ar[4]=Ar[5]=0.f; }
    else LOADROW(y0 - 1, Ar);
    LOADROW(y0, Br);
    float ss = 0.f;
#pragma unroll
    for (int i = 0; i < 16; ++i) {
        int y = y0 + i;
        if (y + 1 < 128) { LOADROW(y + 1, Cr); }
        else { Cr[0]=Cr[1]=Cr[2]=Cr[3]=Cr[4]=Cr[5]=0.f; }
        float o0 = Ar[0]*w0 + Ar[1]*w1 + Ar[2]*w2
                 + Br[0]*w3 + Br[1]*w4 + Br[2]*w5
                 + Cr[0]*w6 + Cr[1]*w7 + Cr[2]*w8;
        float o1 = Ar[1]*w0 + Ar[2]*w1 + Ar[3]*w2
                 + Br[1]*w3 + Br[2]*w4 + Br[3]*w5
                 + Cr[1]*w6 + Cr[2]*w7 + Cr[3]*w8;
        float o2 = Ar[2]*w0 + Ar[3]*w1 + Ar[4]*w2
                 + Br[2]*w3 + Br[3]*w4 + Br[4]*w5
                 + Cr[2]*w6 + Cr[3]*w7 + Cr[4]*w8;
        float o3 = Ar[3]*w0 + Ar[4]*w1 + Ar[5]*w2
                 + Br[3]*w3 + Br[4]*w4 + Br[5]*w5
                 + Cr[3]*w6 + Cr[4]*w7 + Cr[5]*w8;
        *(float4*)(op + y * 128 + x0) = make_float4(o0, o1, o2, o3);
        ss += o0*o0 + o1*o1 + o2*o2 + o3*o3;
#pragma unroll
        for (int j = 0; j < 6; ++j) { Ar[j] = Br[j]; Br[j] = Cr[j]; }
    }
#undef LOADROW
    if (normCnt > 0 && c < normCnt) {
        __shared__ float red[256];
        red[t] = ss;
        __syncthreads();
        for (int st = 128; st > 0; st >>= 1) {
            if (t < st) red[t] += red[t + st];
            __syncthreads();
        }
        if (t == 0) inv[(long)b * 192 + c] = 1.f / fmaxf(sqrtf(red[0]), 1e-12f);
    }
}

// ---------- Gram partials ----------
__global__ __launch_bounds__(576) void gram_k(const float* __restrict__ q, long qB,
                                              const float* __restrict__ k, long kB,
                                              float* __restrict__ gp) {
    int bn = blockIdx.x;
    int ls = blockIdx.y;
    int b = bn >> 3, n = bn & 7;
    const float* qp = q + (long)b * qB + (long)(n * HD) * HW;
    const float* kp = k + (long)b * kB + (long)(n * HD) * HW;
    __shared__ float qs[HD][65], ks[HD][65];
    int tid = threadIdx.x;
    int d = tid / HD, e = tid % HD;
    float acc = 0.f;
    int l0 = ls * 2048, l1 = l0 + 2048;
    for (int l = l0; l < l1; l += 64) {
        __syncthreads();
        for (int idx = tid; idx < HD * 64; idx += 576) {
            int r = idx >> 6, j = idx & 63;
            qs[r][j] = qp[(long)r * HW + l + j];
            ks[r][j] = kp[(long)r * HW + l + j];
        }
        __syncthreads();
#pragma unroll 16
        for (int j = 0; j < 64; ++j) acc += qs[d][j] * ks[e][j];
    }
    gp[((long)ls * 32 + bn) * 576 + tid] = acc;
}

// ---------- normalize + temperature + softmax ----------
__global__ void softmax_k(const float* __restrict__ gp, const float* __restrict__ invq,
                          const float* __restrict__ invk, const float* __restrict__ temp,
                          float* __restrict__ attn) {
    int bn = blockIdx.x;
    int b = bn >> 3, n = bn & 7;
    int d = threadIdx.x;
    if (d >= HD) return;
    float t = temp[n];
    float iq = invq[b * 192 + n * HD + d];
    float row[HD];
#pragma unroll
    for (int e = 0; e < HD; ++e) {
        float g = 0.f;
        for (int s = 0; s < 8; ++s) g += gp[((long)s * 32 + bn) * 576 + d * HD + e];
        row[e] = g * iq * invk[b * 192 + n * HD + e] * t;
    }
    float m = row[0];
#pragma unroll
    for (int e = 1; e < HD; ++e) m = fmaxf(m, row[e]);
    float ssum = 0.f;
#pragma unroll
    for (int e = 0; e < HD; ++e) { row[e] = expf(row[e] - m); ssum += row[e]; }
    float is = 1.f / ssum;
#pragma unroll
    for (int e = 0; e < HD; ++e) attn[(long)bn * 576 + d * HD + e] = row[e] * is;
}

// ---------- out[d,p] = sum_e attn[d,e] * v[e,p] ----------
__global__ void attnapply_k(const float* __restrict__ attn, const float* __restrict__ v,
                            long vB, float* __restrict__ out, long outB) {
    int p = blockIdx.x * 256 + threadIdx.x;
    int bn = blockIdx.y;
    int b = bn >> 3, n = bn & 7;
    __shared__ float a[576];
    for (int i = threadIdx.x; i < 576; i += 256) a[i] = attn[(long)bn * 576 + i];
    __syncthreads();
    const float* vp = v + (long)b * vB + (long)(n * HD) * HW + p;
    float acc[HD];
#pragma unroll
    for (int d = 0; d < HD; ++d) acc[d] = 0.f;
    for (int e = 0; e < HD; ++e) {
        float vv = vp[(long)e * HW];
#pragma unroll
        for (int d = 0; d < HD; ++d) acc[d] += a[d * HD + e] * vv;
    }
    float* op = out + (long)b * outB + (long)(n * HD) * HW + p;
#pragma unroll
    for (int d = 0; d < HD; ++d) op[(long)d * HW] = acc[d];
}

extern "C" void kernel_launch(void* const* d_in, const int* in_sizes, int n_in,
                              void* d_out, int out_size, void* d_ws, size_t ws_size,
                              hipStream_t stream) {
    const float* x        = (const float*)d_in[0];
    const float* w_qkv1   = (const float*)d_in[1];
    const float* w_qkv1dw = (const float*)d_in[2];
    const float* w_proj1  = (const float*)d_in[3];
    const float* w_fdfp1  = (const float*)d_in[4];
    const float* w_fdfp2  = (const float*)d_in[5];
    const float* w_kv2    = (const float*)d_in[6];
    const float* w_kv2dw  = (const float*)d_in[7];
    const float* w_proj2  = (const float*)d_in[8];
    const float* temp     = (const float*)d_in[9];
    float* out = (float*)d_out;
    float* ws  = (float*)d_ws;
    dim3 blk(256);
    const int BIG = 1 << 20;

    // ---- init fp16 weights/bases ----
    cvt16_k<<<432, blk, 0, stream>>>(w_qkv1, (half_t*)(ws + H_WQKV), 110592);
    cvt16_k<<<576, blk, 0, stream>>>(w_fdfp1, (half_t*)(ws + H_W1), 147456);
    cvt16_k<<<576, blk, 0, stream>>>(w_fdfp2, (half_t*)(ws + H_W2), 147456);
    cvt16_k<<<144, blk, 0, stream>>>(w_proj2, (half_t*)(ws + H_PRJ), 36864);
    initB1t_k<<<80, blk, 0, stream>>>((half_t*)(ws + H_B1T));
    initB2h_k<<<256, blk, 0, stream>>>((half_t*)(ws + H_B2));
    initB3h_k<<<256, blk, 0, stream>>>((half_t*)(ws + H_B3));
    initB4t_k<<<80, blk, 0, stream>>>((half_t*)(ws + H_B4T));
    fusew_k<<<384, 192, 0, stream>>>(w_kv2, w_proj1, (half_t*)(ws + H_WF));

    // ---- fdfp(x) -> q2 (+ fused q2 norms) ----
    k1m<5, 0><<<dim3(192, 1, 4), blk, 0, stream>>>(
        x, XB, (long)HW, 128L, BIG, 0L, 128,
        (const uint*)(ws + H_B1T),
        ws + CB0, LT_B, (long)FP, LT_ROW, 80, LT_PART, nullptr);
    k2m<0, 0><<<dim3(4, 60, 4), blk, 0, stream>>>(
        (const half_t*)(ws + H_B2), 256,
        ws + CB0, LT_B, 128, LT_ROW, LT_PART,
        ws + CB1, LT_B, 128, LT_ROW, LT_PART);
    k2m<1, 1><<<dim3(6, 40, 4), blk, 0, stream>>>(
        (const half_t*)(ws + H_W1), 384,
        ws + CB1, LT_B, 192, (long)FP, LT_PART,
        ws + CB2, LT_B, 192, (long)FP, LT_PART);
    k2m<1, 0><<<dim3(6, 40, 4), blk, 0, stream>>>(
        (const half_t*)(ws + H_W2), 384,
        ws + CB2, LT_B, 192, (long)FP, LT_PART,
        ws + CB0, LT_B, 192, (long)FP, LT_PART);
    k2m<0, 0><<<dim3(4, 60, 4), blk, 0, stream>>>(
        (const half_t*)(ws + H_B3), 256,
        ws + CB0, LT_B, 128, LT_ROW, LT_PART,
        ws + CB1, LT_B, 128, LT_ROW, LT_PART);
    k1m<4, 1><<<dim3(192, 1, 4), blk, 0, stream>>>(
        ws + CB1, LT_B, (long)FP, LT_ROW, 80, LT_PART, 160,
        (const uint*)(ws + H_B4T),
        ws + OFF_Q2, XB, (long)HW, 128L, BIG, 0L, ws + SM_INVQ2);

    // ---- stage 1: qkv = dw3(conv1x1(x)) in 3 chunks (+ fused q1/k1 norms) ----
    for (int ch = 0; ch < 3; ++ch) {
        k2m<0, 0><<<dim3(3, 64, 4), blk, 0, stream>>>(
            (const half_t*)(ws + H_WQKV) + (long)ch * 192 * 192, 192,
            x, XB, BIG, (long)HW, 0L,
            ws + OFF_T1, XB, BIG, (long)HW, 0L);
        dw3_k<<<dim3(192, 4), blk, 0, stream>>>(
            ws + OFF_T1, XB, w_qkv1dw + ch * 192 * 9,
            ws + (long)ch * 192 * HW, (long)576 * HW,
            ch == 2 ? 0 : 192,
            ch == 0 ? ws + SM_INVQ1 : ws + SM_INVK1);
    }
    gram_k<<<dim3(32, 8), 576, 0, stream>>>(ws, (long)576 * HW,
                                            ws + (long)192 * HW, (long)576 * HW, ws + SM_GP);
    softmax_k<<<32, 32, 0, stream>>>(ws + SM_GP, ws + SM_INVQ1, ws + SM_INVK1, temp, ws + SM_ATT);
    attnapply_k<<<dim3(64, 32), blk, 0, stream>>>(
        ws + SM_ATT, ws + (long)384 * HW, (long)576 * HW, ws + OFF_T1, XB);

    // ---- kv2 = dw3(conv1x1(out1, Wf)) (+ fused k2 norms) ----
    k2m<0, 0><<<dim3(6, 64, 4), blk, 0, stream>>>(
        (const half_t*)(ws + H_WF), 192,
        ws + OFF_T1, XB, BIG, (long)HW, 0L,
        ws + OFF_KT, (long)384 * HW, BIG, (long)HW, 0L);
    dw3_k<<<dim3(384, 4), blk, 0, stream>>>(
        ws + OFF_KT, (long)384 * HW, w_kv2dw, ws + OFF_KF, (long)384 * HW,
        192, ws + SM_INVK2);

    // ---- stage 2 attention ----
    gram_k<<<dim3(32, 8), 576, 0, stream>>>(ws + OFF_Q2, XB,
                                            ws + OFF_KF, (long)384 * HW, ws + SM_GP);
    softmax_k<<<32, 32, 0, stream>>>(ws + SM_GP, ws + SM_INVQ2, ws + SM_INVK2, temp, ws + SM_ATT);
    attnapply_k<<<dim3(64, 32), blk, 0, stream>>>(
        ws + SM_ATT, ws + OFF_KF + (long)192 * HW, (long)384 * HW, ws + OFF_O2, XB);
    k2m<0, 0><<<dim3(3, 64, 4), blk, 0, stream>>>(
        (const half_t*)(ws + H_PRJ), 192,
        ws + OFF_O2, XB, BIG, (long)HW, 0L,
        out, XB, BIG, (long)HW, 0L);
}

// Round 9
// 808.738 us; speedup vs baseline: 7.2538x; 1.0007x over previous
//
#include <hip/hip_runtime.h>
#include <math.h>

typedef _Float16 half_t;
typedef half_t h8v __attribute__((ext_vector_type(8)));
typedef float f32x4 __attribute__((ext_vector_type(4)));

namespace {
constexpr int DIMC = 192;
constexpr int NB = 4;
constexpr int HH = 128, WW = 128;
constexpr int HW = HH * WW;              // 16384
constexpr int NH = 8, HD = 24;
constexpr int FP = 80;                   // padded kx width (65 valid)
constexpr long LT_PART = 128L * 192 * FP;          // 1,966,080
constexpr long LT_B    = 2 * LT_PART;              // 3,932,160
constexpr long LT_ROW  = 192L * FP;                // 15360
constexpr long XB  = 192L * HW;                    // 3,145,728
constexpr long CB0 = 0;
constexpr long CB1 = 15728640;
constexpr long CB2 = 31457280;
constexpr long OFF_T1 = 37748736;        // conv tmp / out1
constexpr long OFF_Q2 = 50331648;        // q2
constexpr long OFF_S  = 62914560;        // small region
constexpr long OFF_KT = 0;               // kv2 pre-dw tmp
constexpr long OFF_KF = 25165824;        // kv2 final
constexpr long OFF_O2 = 0;               // out2 tmp
constexpr long SM_INVQ1 = OFF_S;                // 768
constexpr long SM_INVK1 = OFF_S + 768;          // 768
constexpr long SM_INVQ2 = OFF_S + 1536;         // 768
constexpr long SM_INVK2 = OFF_S + 2304;         // 768
constexpr long SM_ATT   = OFF_S + 3072;         // 18,432
constexpr long SM_GP    = OFF_S + 21504;        // 147,456
constexpr long H0       = OFF_S + 168960;       // fp16 pool (float units)
constexpr long H_WQKV = H0;                     // 110,592 h
constexpr long H_WF   = H0 + 55296;             // 73,728 h
constexpr long H_W1   = H0 + 92160;             // 147,456 h
constexpr long H_W2   = H0 + 165888;            // 147,456 h
constexpr long H_PRJ  = H0 + 239616;            // 36,864 h
constexpr long H_B2   = H0 + 258048;            // 65,536 h
constexpr long H_B3   = H0 + 290816;            // 65,536 h
constexpr long H_B1T  = H0 + 323584;            // 160x128 h
constexpr long H_B4T  = H0 + 333824;            // 128x160 h
constexpr float PI2 = 6.283185307179586476f;
}

// ================= init: fp16 weight/basis materialization =================
__global__ void cvt16_k(const float* __restrict__ in, half_t* __restrict__ o, int n) {
    int i = blockIdx.x * 256 + threadIdx.x;
    if (i < n) o[i] = (half_t)in[i];
}
__global__ void initB1t_k(half_t* __restrict__ B) {      // [160 j][128 k]
    int idx = blockIdx.x * 256 + threadIdx.x;
    if (idx >= 160 * 128) return;
    int j = idx / 128, k = idx % 128;
    float v = 0.f;
    if (j < 65) v = cosf(PI2 * ((k * j) & 127) / 128.f) * (1.f / 128.f);
    else if (j >= 80 && j < 145) v = -sinf(PI2 * ((k * (j - 80)) & 127) / 128.f) * (1.f / 128.f);
    B[idx] = (half_t)v;
}
__global__ void initB2h_k(half_t* __restrict__ B) {      // [256 m][256 c]
    int idx = blockIdx.x * 256 + threadIdx.x;
    int m = idx >> 8, cin = idx & 255;
    int pd = m >> 7, ky = m & 127;
    int ps = cin >> 7, y = cin & 127;
    float c, s; sincosf(PI2 * ((ky * y) & 127) / 128.f, &s, &c);
    float v = (pd == 0) ? (ps == 0 ? c : s) : (ps == 0 ? -s : c);
    B[idx] = (half_t)v;
}
__global__ void initB3h_k(half_t* __restrict__ B) {      // [256 m][256 c]
    int idx = blockIdx.x * 256 + threadIdx.x;
    int m = idx >> 8, cin = idx & 255;
    int pd = m >> 7, y = m & 127;
    int ps = cin >> 7, ky = cin & 127;
    float c, s; sincosf(PI2 * ((y * ky) & 127) / 128.f, &s, &c);
    float v = (pd == 0) ? (ps == 0 ? c : -s) : (ps == 0 ? s : c);
    B[idx] = (half_t)v;
}
__global__ void initB4t_k(half_t* __restrict__ B) {      // [128 j][160 k]
    int idx = blockIdx.x * 256 + threadIdx.x;
    if (idx >= 128 * 160) return;
    int j = idx / 160, k = idx % 160;
    float v = 0.f;
    if (k < 80) {
        if (k == 0) v = 1.f / 128.f;
        else if (k < 64) v = 2.f * cosf(PI2 * ((k * j) & 127) / 128.f) / 128.f;
        else if (k == 64) v = cosf(PI2 * ((64 * j) & 127) / 128.f) / 128.f;
    } else {
        int kx = k - 80;
        if (kx >= 1 && kx < 64) v = -2.f * sinf(PI2 * ((kx * j) & 127) / 128.f) / 128.f;
    }
    B[idx] = (half_t)v;
}
__global__ void fusew_k(const float* __restrict__ wkv, const float* __restrict__ wproj,
                        half_t* __restrict__ wf) {
    int o = blockIdx.x, c = threadIdx.x;
    float acc = 0.f;
    for (int m = 0; m < 192; ++m) acc += wkv[o * 192 + m] * wproj[m * 192 + c];
    wf[o * 192 + c] = (half_t)acc;
}

// ================= K2M: fp16-weights x fp32-data MFMA GEMM =================
template<int PFOLD, int GELU>
__global__ __launch_bounds__(256) void k2m(
    const half_t* __restrict__ W16, int Cin,
    const float* __restrict__ X, long xBatch, int iSplit, long iLo, long iHi,
    float* __restrict__ out, long oBatch, int oSplit, long oLo, long oHi) {
    __shared__ __align__(16) half_t Wh[64 * 40];
    __shared__ __align__(16) half_t Xh[256 * 40];
    const int t = threadIdx.x;
    const int o0 = blockIdx.x * 64;
    const long p0 = (long)blockIdx.y * 256;
    const long xb = (long)blockIdx.z * xBatch;
    const long ob = (long)blockIdx.z * oBatch;
    const int lane = t & 63, wv = t >> 6;
    const int fr = lane & 15, fg = lane >> 4;
    const int so = t >> 2, scg = (t & 3) * 8;
    f32x4 acc[4][4];
#pragma unroll
    for (int m = 0; m < 4; ++m)
#pragma unroll
        for (int n = 0; n < 4; ++n) acc[m][n] = {0.f, 0.f, 0.f, 0.f};
    long pa;
    {
        long p = p0 + t;
        if (PFOLD) { long q = p / 80; pa = q * LT_ROW + (p - q * 80); } else pa = p;
    }
    for (int k0 = 0; k0 < Cin; k0 += 32) {
        __syncthreads();
        *(h8v*)&Wh[so * 40 + scg] =
            *(const h8v*)(W16 + (long)(o0 + so) * Cin + k0 + scg);
#pragma unroll
        for (int s = 0; s < 2; ++s) {
            int cb = k0 + s * 16;
            long rb = (cb < iSplit) ? (long)cb * iLo : (long)(cb - iSplit) * iLo + iHi;
            const float* g = X + xb + rb + pa;
            float v[16];
#pragma unroll
            for (int j = 0; j < 16; ++j) v[j] = g[(long)j * iLo];
            h8v h0, h1;
#pragma unroll
            for (int j = 0; j < 8; ++j) { h0[j] = (half_t)v[j]; h1[j] = (half_t)v[8 + j]; }
            *(h8v*)&Xh[t * 40 + s * 16] = h0;
            *(h8v*)&Xh[t * 40 + s * 16 + 8] = h1;
        }
        __syncthreads();
        h8v a[4], bb[4];
#pragma unroll
        for (int m = 0; m < 4; ++m) a[m] = *(const h8v*)&Wh[(m * 16 + fr) * 40 + fg * 8];
#pragma unroll
        for (int n = 0; n < 4; ++n) bb[n] = *(const h8v*)&Xh[(wv * 64 + n * 16 + fr) * 40 + fg * 8];
#pragma unroll
        for (int m = 0; m < 4; ++m)
#pragma unroll
            for (int n = 0; n < 4; ++n)
                acc[m][n] = __builtin_amdgcn_mfma_f32_16x16x32_f16(a[m], bb[n], acc[m][n], 0, 0, 0);
    }
    long pe[4];
#pragma unroll
    for (int n = 0; n < 4; ++n) {
        long p = p0 + wv * 64 + n * 16 + fr;
        if (PFOLD) { long q = p / 80; pe[n] = q * LT_ROW + (p - q * 80); } else pe[n] = p;
    }
#pragma unroll
    for (int m = 0; m < 4; ++m)
#pragma unroll
        for (int i = 0; i < 4; ++i) {
            int o = o0 + m * 16 + fg * 4 + i;
            long oadr = ob + ((o < oSplit) ? (long)o * oLo : (long)(o - oSplit) * oLo + oHi);
#pragma unroll
            for (int n = 0; n < 4; ++n) {
                float v = acc[m][n][i];
                if (GELU) v = 0.5f * v * (1.f + erff(v * 0.70710678118654752f));
                out[oadr + pe[n]] = v;
            }
        }
}

// ================= K1M: fp32-data x fp16-basis MFMA GEMM (k-contiguous A) ====
template<int NF, int NORM>
__global__ __launch_bounds__(256) void k1m(
    const float* __restrict__ A, long aBatch, long aC, long aRow, int aSplit, long aHiOff, int K,
    const uint* __restrict__ Bt32,
    float* __restrict__ out, long oBatch, long oC, long oRow, int oSplit, long oHiOff,
    float* __restrict__ inv) {
    __shared__ __align__(16) half_t Ah[128 * 40];
    __shared__ __align__(16) half_t Bh[160 * 40];
    const int t = threadIdx.x;
    const long ab = (long)blockIdx.z * aBatch + (long)blockIdx.x * aC;
    const long ob = (long)blockIdx.z * oBatch + (long)blockIdx.x * oC;
    const int N = NF * 32;
    const int lane = t & 63, wv = t >> 6;
    const int wm = wv >> 1, wn = wv & 1;
    const int fr = lane & 15, fg = lane >> 4;
    const int sr = t >> 1, shalf = t & 1;
    const int Kw = K >> 1;
    f32x4 acc[4][NF];
#pragma unroll
    for (int m = 0; m < 4; ++m)
#pragma unroll
        for (int n = 0; n < NF; ++n) acc[m][n] = {0.f, 0.f, 0.f, 0.f};
    for (int k0 = 0; k0 < K; k0 += 32) {
        __syncthreads();
        {
            int cb = k0 + shalf * 16;
            long rb = (cb < aSplit) ? (long)cb : (long)(cb - aSplit) + aHiOff;
            const float* g = A + ab + (long)sr * aRow + rb;
            float4 v0 = *(const float4*)g;
            float4 v1 = *(const float4*)(g + 4);
            float4 v2 = *(const float4*)(g + 8);
            float4 v3 = *(const float4*)(g + 12);
            h8v h0, h1;
            h0[0] = (half_t)v0.x; h0[1] = (half_t)v0.y; h0[2] = (half_t)v0.z; h0[3] = (half_t)v0.w;
            h0[4] = (half_t)v1.x; h0[5] = (half_t)v1.y; h0[6] = (half_t)v1.z; h0[7] = (half_t)v1.w;
            h1[0] = (half_t)v2.x; h1[1] = (half_t)v2.y; h1[2] = (half_t)v2.z; h1[3] = (half_t)v2.w;
            h1[4] = (half_t)v3.x; h1[5] = (half_t)v3.y; h1[6] = (half_t)v3.z; h1[7] = (half_t)v3.w;
            *(h8v*)&Ah[sr * 40 + shalf * 16] = h0;
            *(h8v*)&Ah[sr * 40 + shalf * 16 + 8] = h1;
        }
        for (int j = t; j < N * 16; j += 256) {
            int n = j >> 4, kw = j & 15;
            *(uint*)&Bh[n * 40 + kw * 2] = Bt32[(long)n * Kw + (k0 >> 1) + kw];
        }
        __syncthreads();
        h8v a[4], bb[NF];
#pragma unroll
        for (int m = 0; m < 4; ++m) a[m] = *(const h8v*)&Ah[(wm * 64 + m * 16 + fr) * 40 + fg * 8];
#pragma unroll
        for (int n = 0; n < NF; ++n) bb[n] = *(const h8v*)&Bh[(wn * NF * 16 + n * 16 + fr) * 40 + fg * 8];
#pragma unroll
        for (int m = 0; m < 4; ++m)
#pragma unroll
            for (int n = 0; n < NF; ++n)
                acc[m][n] = __builtin_amdgcn_mfma_f32_16x16x32_f16(a[m], bb[n], acc[m][n], 0, 0, 0);
    }
#pragma unroll
    for (int m = 0; m < 4; ++m)
#pragma unroll
        for (int i = 0; i < 4; ++i) {
            int r = wm * 64 + m * 16 + fg * 4 + i;
            float* orow = out + ob + (long)r * oRow;
#pragma unroll
            for (int n = 0; n < NF; ++n) {
                int j = wn * NF * 16 + n * 16 + fr;
                long jm = (j < oSplit) ? (long)j : (long)(j - oSplit) + oHiOff;
                orow[jm] = acc[m][n][i];
            }
        }
    if (NORM) {
        float ss = 0.f;
#pragma unroll
        for (int m = 0; m < 4; ++m)
#pragma unroll
            for (int n = 0; n < NF; ++n)
#pragma unroll
                for (int i = 0; i < 4; ++i) ss += acc[m][n][i] * acc[m][n][i];
        __syncthreads();
        float* red = (float*)Ah;
        red[t] = ss;
        __syncthreads();
        for (int st = 128; st > 0; st >>= 1) {
            if (t < st) red[t] += red[t + st];
            __syncthreads();
        }
        if (t == 0) inv[(long)blockIdx.z * 192 + blockIdx.x] = 1.f / fmaxf(sqrtf(red[0]), 1e-12f);
    }
}

// ---------- depthwise 3x3, pad 1: one block per (channel, batch) plane ----------
__global__ __launch_bounds__(256) void dw3_k(
    const float* __restrict__ in, long inBatch,
    const float* __restrict__ w9,
    float* __restrict__ out, long outBatch,
    int normCnt, float* __restrict__ inv) {
    const int c = blockIdx.x, b = blockIdx.y;
    const int t = threadIdx.x;
    const float* ip = in + (long)b * inBatch + (long)c * HW;
    float* op = out + (long)b * outBatch + (long)c * HW;
    const float* wp = w9 + c * 9;
    const float w0 = wp[0], w1 = wp[1], w2 = wp[2];
    const float w3 = wp[3], w4 = wp[4], w5 = wp[5];
    const float w6 = wp[6], w7 = wp[7], w8 = wp[8];
    const int tx = t & 31;
    const int x0 = tx * 4;
    const int y0 = (t >> 5) * 16;
    const bool lx = (tx > 0), rx = (tx < 31);
    float Ar[6], Br[6], Cr[6];
#define LOADROW(Y, R) do { \
        const float* _p = ip + (Y) * 128 + x0; \
        float4 _v = *(const float4*)_p; \
        R[1] = _v.x; R[2] = _v.y; R[3] = _v.z; R[4] = _v.w; \
        R[0] = lx ? _p[-1] : 0.f; \
        R[5] = rx ? _p[4] : 0.f; } while (0)
    if (y0 == 0) { Ar[0]=Ar[1]=Ar[2]=Ar[3]=Ar[4]=Ar[5]=0.f; }
    else LOADROW(y0 - 1, Ar);
    LOADROW(y0, Br);
    float ss = 0.f;
#pragma unroll
    for (int i = 0; i < 16; ++i) {
        int y = y0 + i;
        if (y + 1 < 128) { LOADROW(y + 1, Cr); }
        else { Cr[0]=Cr[1]=Cr[2]=Cr[3]=Cr[4]=Cr[5]=0.f; }
        float o0 = Ar[0]*w0 + Ar[1]*w1 + Ar[2]*w2
                 + Br[0]*w3 + Br[1]*w4 + Br[2]*w5
                 + Cr[0]*w6 + Cr[1]*w7 + Cr[2]*w8;
        float o1 = Ar[1]*w0 + Ar[2]*w1 + Ar[3]*w2
                 + Br[1]*w3 + Br[2]*w4 + Br[3]*w5
                 + Cr[1]*w6 + Cr[2]*w7 + Cr[3]*w8;
        float o2 = Ar[2]*w0 + Ar[3]*w1 + Ar[4]*w2
                 + Br[2]*w3 + Br[3]*w4 + Br[4]*w5
                 + Cr[2]*w6 + Cr[3]*w7 + Cr[4]*w8;
        float o3 = Ar[3]*w0 + Ar[4]*w1 + Ar[5]*w2
                 + Br[3]*w3 + Br[4]*w4 + Br[5]*w5
                 + Cr[3]*w6 + Cr[4]*w7 + Cr[5]*w8;
        *(float4*)(op + y * 128 + x0) = make_float4(o0, o1, o2, o3);
        ss += o0*o0 + o1*o1 + o2*o2 + o3*o3;
#pragma unroll
        for (int j = 0; j < 6; ++j) { Ar[j] = Br[j]; Br[j] = Cr[j]; }
    }
#undef LOADROW
    if (normCnt > 0 && c < normCnt) {
        __shared__ float red[256];
        red[t] = ss;
        __syncthreads();
        for (int st = 128; st > 0; st >>= 1) {
            if (t < st) red[t] += red[t + st];
            __syncthreads();
        }
        if (t == 0) inv[(long)b * 192 + c] = 1.f / fmaxf(sqrtf(red[0]), 1e-12f);
    }
}

// ---------- Gram partials (fp32, 8 l-slices — known-good r5 version) ----------
__global__ __launch_bounds__(576) void gram_k(const float* __restrict__ q, long qB,
                                              const float* __restrict__ k, long kB,
                                              float* __restrict__ gp) {
    int bn = blockIdx.x;
    int ls = blockIdx.y;
    int b = bn >> 3, n = bn & 7;
    const float* qp = q + (long)b * qB + (long)(n * HD) * HW;
    const float* kp = k + (long)b * kB + (long)(n * HD) * HW;
    __shared__ float qs[HD][65], ks[HD][65];
    int tid = threadIdx.x;
    int d = tid / HD, e = tid % HD;
    float acc = 0.f;
    int l0 = ls * 2048, l1 = l0 + 2048;
    for (int l = l0; l < l1; l += 64) {
        __syncthreads();
        for (int idx = tid; idx < HD * 64; idx += 576) {
            int r = idx >> 6, j = idx & 63;
            qs[r][j] = qp[(long)r * HW + l + j];
            ks[r][j] = kp[(long)r * HW + l + j];
        }
        __syncthreads();
#pragma unroll 16
        for (int j = 0; j < 64; ++j) acc += qs[d][j] * ks[e][j];
    }
    gp[((long)ls * 32 + bn) * 576 + tid] = acc;
}

// ---------- normalize + temperature + softmax (known-good r5 version) ----------
__global__ void softmax_k(const float* __restrict__ gp, const float* __restrict__ invq,
                          const float* __restrict__ invk, const float* __restrict__ temp,
                          float* __restrict__ attn) {
    int bn = blockIdx.x;
    int b = bn >> 3, n = bn & 7;
    int d = threadIdx.x;
    if (d >= HD) return;
    float t = temp[n];
    float iq = invq[b * 192 + n * HD + d];
    float row[HD];
#pragma unroll
    for (int e = 0; e < HD; ++e) {
        float g = 0.f;
        for (int s = 0; s < 8; ++s) g += gp[((long)s * 32 + bn) * 576 + d * HD + e];
        row[e] = g * iq * invk[b * 192 + n * HD + e] * t;
    }
    float m = row[0];
#pragma unroll
    for (int e = 1; e < HD; ++e) m = fmaxf(m, row[e]);
    float ssum = 0.f;
#pragma unroll
    for (int e = 0; e < HD; ++e) { row[e] = expf(row[e] - m); ssum += row[e]; }
    float is = 1.f / ssum;
#pragma unroll
    for (int e = 0; e < HD; ++e) attn[(long)bn * 576 + d * HD + e] = row[e] * is;
}

// ---------- out[d,p] = sum_e attn[d,e] * v[e,p] ----------
__global__ void attnapply_k(const float* __restrict__ attn, const float* __restrict__ v,
                            long vB, float* __restrict__ out, long outB) {
    int p = blockIdx.x * 256 + threadIdx.x;
    int bn = blockIdx.y;
    int b = bn >> 3, n = bn & 7;
    __shared__ float a[576];
    for (int i = threadIdx.x; i < 576; i += 256) a[i] = attn[(long)bn * 576 + i];
    __syncthreads();
    const float* vp = v + (long)b * vB + (long)(n * HD) * HW + p;
    float acc[HD];
#pragma unroll
    for (int d = 0; d < HD; ++d) acc[d] = 0.f;
    for (int e = 0; e < HD; ++e) {
        float vv = vp[(long)e * HW];
#pragma unroll
        for (int d = 0; d < HD; ++d) acc[d] += a[d * HD + e] * vv;
    }
    float* op = out + (long)b * outB + (long)(n * HD) * HW + p;
#pragma unroll
    for (int d = 0; d < HD; ++d) op[(long)d * HW] = acc[d];
}

extern "C" void kernel_launch(void* const* d_in, const int* in_sizes, int n_in,
                              void* d_out, int out_size, void* d_ws, size_t ws_size,
                              hipStream_t stream) {
    const float* x        = (const float*)d_in[0];
    const float* w_qkv1   = (const float*)d_in[1];
    const float* w_qkv1dw = (const float*)d_in[2];
    const float* w_proj1  = (const float*)d_in[3];
    const float* w_fdfp1  = (const float*)d_in[4];
    const float* w_fdfp2  = (const float*)d_in[5];
    const float* w_kv2    = (const float*)d_in[6];
    const float* w_kv2dw  = (const float*)d_in[7];
    const float* w_proj2  = (const float*)d_in[8];
    const float* temp     = (const float*)d_in[9];
    float* out = (float*)d_out;
    float* ws  = (float*)d_ws;
    dim3 blk(256);
    const int BIG = 1 << 20;

    // ---- init fp16 weights/bases ----
    cvt16_k<<<432, blk, 0, stream>>>(w_qkv1, (half_t*)(ws + H_WQKV), 110592);
    cvt16_k<<<576, blk, 0, stream>>>(w_fdfp1, (half_t*)(ws + H_W1), 147456);
    cvt16_k<<<576, blk, 0, stream>>>(w_fdfp2, (half_t*)(ws + H_W2), 147456);
    cvt16_k<<<144, blk, 0, stream>>>(w_proj2, (half_t*)(ws + H_PRJ), 36864);
    initB1t_k<<<80, blk, 0, stream>>>((half_t*)(ws + H_B1T));
    initB2h_k<<<256, blk, 0, stream>>>((half_t*)(ws + H_B2));
    initB3h_k<<<256, blk, 0, stream>>>((half_t*)(ws + H_B3));
    initB4t_k<<<80, blk, 0, stream>>>((half_t*)(ws + H_B4T));
    fusew_k<<<384, 192, 0, stream>>>(w_kv2, w_proj1, (half_t*)(ws + H_WF));

    // ---- fdfp(x) -> q2 (+ fused q2 norms) ----
    k1m<5, 0><<<dim3(192, 1, 4), blk, 0, stream>>>(
        x, XB, (long)HW, 128L, BIG, 0L, 128,
        (const uint*)(ws + H_B1T),
        ws + CB0, LT_B, (long)FP, LT_ROW, 80, LT_PART, nullptr);
    k2m<0, 0><<<dim3(4, 60, 4), blk, 0, stream>>>(
        (const half_t*)(ws + H_B2), 256,
        ws + CB0, LT_B, 128, LT_ROW, LT_PART,
        ws + CB1, LT_B, 128, LT_ROW, LT_PART);
    k2m<1, 1><<<dim3(6, 40, 4), blk, 0, stream>>>(
        (const half_t*)(ws + H_W1), 384,
        ws + CB1, LT_B, 192, (long)FP, LT_PART,
        ws + CB2, LT_B, 192, (long)FP, LT_PART);
    k2m<1, 0><<<dim3(6, 40, 4), blk, 0, stream>>>(
        (const half_t*)(ws + H_W2), 384,
        ws + CB2, LT_B, 192, (long)FP, LT_PART,
        ws + CB0, LT_B, 192, (long)FP, LT_PART);
    k2m<0, 0><<<dim3(4, 60, 4), blk, 0, stream>>>(
        (const half_t*)(ws + H_B3), 256,
        ws + CB0, LT_B, 128, LT_ROW, LT_PART,
        ws + CB1, LT_B, 128, LT_ROW, LT_PART);
    k1m<4, 1><<<dim3(192, 1, 4), blk, 0, stream>>>(
        ws + CB1, LT_B, (long)FP, LT_ROW, 80, LT_PART, 160,
        (const uint*)(ws + H_B4T),
        ws + OFF_Q2, XB, (long)HW, 128L, BIG, 0L, ws + SM_INVQ2);

    // ---- stage 1: qkv = dw3(conv1x1(x)) in 3 chunks (+ fused q1/k1 norms) ----
    for (int ch = 0; ch < 3; ++ch) {
        k2m<0, 0><<<dim3(3, 64, 4), blk, 0, stream>>>(
            (const half_t*)(ws + H_WQKV) + (long)ch * 192 * 192, 192,
            x, XB, BIG, (long)HW, 0L,
            ws + OFF_T1, XB, BIG, (long)HW, 0L);
        dw3_k<<<dim3(192, 4), blk, 0, stream>>>(
            ws + OFF_T1, XB, w_qkv1dw + ch * 192 * 9,
            ws + (long)ch * 192 * HW, (long)576 * HW,
            ch == 2 ? 0 : 192,
            ch == 0 ? ws + SM_INVQ1 : ws + SM_INVK1);
    }
    gram_k<<<dim3(32, 8), 576, 0, stream>>>(ws, (long)576 * HW,
                                            ws + (long)192 * HW, (long)576 * HW, ws + SM_GP);
    softmax_k<<<32, 32, 0, stream>>>(ws + SM_GP, ws + SM_INVQ1, ws + SM_INVK1, temp, ws + SM_ATT);
    attnapply_k<<<dim3(64, 32), blk, 0, stream>>>(
        ws + SM_ATT, ws + (long)384 * HW, (long)576 * HW, ws + OFF_T1, XB);

    // ---- kv2 = dw3(conv1x1(out1, Wf)) (+ fused k2 norms) ----
    k2m<0, 0><<<dim3(6, 64, 4), blk, 0, stream>>>(
        (const half_t*)(ws + H_WF), 192,
        ws + OFF_T1, XB, BIG, (long)HW, 0L,
        ws + OFF_KT, (long)384 * HW, BIG, (long)HW, 0L);
    dw3_k<<<dim3(384, 4), blk, 0, stream>>>(
        ws + OFF_KT, (long)384 * HW, w_kv2dw, ws + OFF_KF, (long)384 * HW,
        192, ws + SM_INVK2);

    // ---- stage 2 attention ----
    gram_k<<<dim3(32, 8), 576, 0, stream>>>(ws + OFF_Q2, XB,
                                            ws + OFF_KF, (long)384 * HW, ws + SM_GP);
    softmax_k<<<32, 32, 0, stream>>>(ws + SM_GP, ws + SM_INVQ2, ws + SM_INVK2, temp, ws + SM_ATT);
    attnapply_k<<<dim3(64, 32), blk, 0, stream>>>(
        ws + SM_ATT, ws + OFF_KF + (long)192 * HW, (long)384 * HW, ws + OFF_O2, XB);
    k2m<0, 0><<<dim3(3, 64, 4), blk, 0, stream>>>(
        (const half_t*)(ws + H_PRJ), 192,
        ws + OFF_O2, XB, BIG, (long)HW, 0L,
        out, XB, BIG, (long)HW, 0L);
}

// Round 10
// 716.674 us; speedup vs baseline: 8.1856x; 1.1285x over previous
//
#include <hip/hip_runtime.h>
#include <math.h>

typedef _Float16 half_t;
typedef half_t h8v __attribute__((ext_vector_type(8)));
typedef float f32x4 __attribute__((ext_vector_type(4)));

namespace {
constexpr int DIMC = 192;
constexpr int NB = 4;
constexpr int HH = 128, WW = 128;
constexpr int HW = HH * WW;              // 16384
constexpr int NH = 8, HD = 24;
constexpr int FP = 80;                   // padded kx width (65 valid)
constexpr long LT_PART = 128L * 192 * FP;          // 1,966,080
constexpr long LT_B    = 2 * LT_PART;              // 3,932,160
constexpr long LT_ROW  = 192L * FP;                // 15360
constexpr long XB  = 192L * HW;                    // 3,145,728
constexpr long CB0 = 0;
constexpr long CB1 = 15728640;
constexpr long CB2 = 31457280;
constexpr long OFF_T1 = 37748736;        // conv tmp / out1 / stage-1 gram partials
constexpr long OFF_Q2 = 50331648;        // q2
constexpr long OFF_S  = 62914560;        // small region
constexpr long OFF_KT = 0;               // kv2 pre-dw tmp / stage-2 gram partials
constexpr long OFF_KF = 25165824;        // kv2 final  [25.1M..50.3M) — NOTE: overlaps OFF_T1!
constexpr long OFF_O2 = 0;               // out2 tmp
constexpr int  GSL = 64;                 // gram l-slices (256 l each)
constexpr long SM_INVQ1 = OFF_S;                // 768
constexpr long SM_INVK1 = OFF_S + 768;          // 768
constexpr long SM_INVQ2 = OFF_S + 1536;         // 768
constexpr long SM_INVK2 = OFF_S + 2304;         // 768
constexpr long SM_ATT   = OFF_S + 3072;         // 18,432
constexpr long H0       = OFF_S + 168960;       // fp16 pool (float units)
constexpr long H_WQKV = H0;                     // 110,592 h
constexpr long H_WF   = H0 + 55296;             // 73,728 h
constexpr long H_W1   = H0 + 92160;             // 147,456 h
constexpr long H_W2   = H0 + 165888;            // 147,456 h
constexpr long H_PRJ  = H0 + 239616;            // 36,864 h
constexpr long H_B2   = H0 + 258048;            // 65,536 h
constexpr long H_B3   = H0 + 290816;            // 65,536 h
constexpr long H_B1T  = H0 + 323584;            // 160x128 h
constexpr long H_B4T  = H0 + 333824;            // 128x160 h
constexpr float PI2 = 6.283185307179586476f;
}

// ================= init: fp16 weight/basis materialization =================
__global__ void cvt16_k(const float* __restrict__ in, half_t* __restrict__ o, int n) {
    int i = blockIdx.x * 256 + threadIdx.x;
    if (i < n) o[i] = (half_t)in[i];
}
__global__ void initB1t_k(half_t* __restrict__ B) {      // [160 j][128 k]
    int idx = blockIdx.x * 256 + threadIdx.x;
    if (idx >= 160 * 128) return;
    int j = idx / 128, k = idx % 128;
    float v = 0.f;
    if (j < 65) v = cosf(PI2 * ((k * j) & 127) / 128.f) * (1.f / 128.f);
    else if (j >= 80 && j < 145) v = -sinf(PI2 * ((k * (j - 80)) & 127) / 128.f) * (1.f / 128.f);
    B[idx] = (half_t)v;
}
__global__ void initB2h_k(half_t* __restrict__ B) {      // [256 m][256 c]
    int idx = blockIdx.x * 256 + threadIdx.x;
    int m = idx >> 8, cin = idx & 255;
    int pd = m >> 7, ky = m & 127;
    int ps = cin >> 7, y = cin & 127;
    float c, s; sincosf(PI2 * ((ky * y) & 127) / 128.f, &s, &c);
    float v = (pd == 0) ? (ps == 0 ? c : s) : (ps == 0 ? -s : c);
    B[idx] = (half_t)v;
}
__global__ void initB3h_k(half_t* __restrict__ B) {      // [256 m][256 c]
    int idx = blockIdx.x * 256 + threadIdx.x;
    int m = idx >> 8, cin = idx & 255;
    int pd = m >> 7, y = m & 127;
    int ps = cin >> 7, ky = cin & 127;
    float c, s; sincosf(PI2 * ((y * ky) & 127) / 128.f, &s, &c);
    float v = (pd == 0) ? (ps == 0 ? c : -s) : (ps == 0 ? s : c);
    B[idx] = (half_t)v;
}
__global__ void initB4t_k(half_t* __restrict__ B) {      // [128 j][160 k]
    int idx = blockIdx.x * 256 + threadIdx.x;
    if (idx >= 128 * 160) return;
    int j = idx / 160, k = idx % 160;
    float v = 0.f;
    if (k < 80) {
        if (k == 0) v = 1.f / 128.f;
        else if (k < 64) v = 2.f * cosf(PI2 * ((k * j) & 127) / 128.f) / 128.f;
        else if (k == 64) v = cosf(PI2 * ((64 * j) & 127) / 128.f) / 128.f;
    } else {
        int kx = k - 80;
        if (kx >= 1 && kx < 64) v = -2.f * sinf(PI2 * ((kx * j) & 127) / 128.f) / 128.f;
    }
    B[idx] = (half_t)v;
}
__global__ void fusew_k(const float* __restrict__ wkv, const float* __restrict__ wproj,
                        half_t* __restrict__ wf) {
    int o = blockIdx.x, c = threadIdx.x;
    float acc = 0.f;
    for (int m = 0; m < 192; ++m) acc += wkv[o * 192 + m] * wproj[m * 192 + c];
    wf[o * 192 + c] = (half_t)acc;
}

// ================= K2M: fp16-weights x fp32-data MFMA GEMM =================
template<int PFOLD, int GELU>
__global__ __launch_bounds__(256) void k2m(
    const half_t* __restrict__ W16, int Cin,
    const float* __restrict__ X, long xBatch, int iSplit, long iLo, long iHi,
    float* __restrict__ out, long oBatch, int oSplit, long oLo, long oHi) {
    __shared__ __align__(16) half_t Wh[64 * 40];
    __shared__ __align__(16) half_t Xh[256 * 40];
    const int t = threadIdx.x;
    const int o0 = blockIdx.x * 64;
    const long p0 = (long)blockIdx.y * 256;
    const long xb = (long)blockIdx.z * xBatch;
    const long ob = (long)blockIdx.z * oBatch;
    const int lane = t & 63, wv = t >> 6;
    const int fr = lane & 15, fg = lane >> 4;
    const int so = t >> 2, scg = (t & 3) * 8;
    f32x4 acc[4][4];
#pragma unroll
    for (int m = 0; m < 4; ++m)
#pragma unroll
        for (int n = 0; n < 4; ++n) acc[m][n] = {0.f, 0.f, 0.f, 0.f};
    long pa;
    {
        long p = p0 + t;
        if (PFOLD) { long q = p / 80; pa = q * LT_ROW + (p - q * 80); } else pa = p;
    }
    for (int k0 = 0; k0 < Cin; k0 += 32) {
        __syncthreads();
        *(h8v*)&Wh[so * 40 + scg] =
            *(const h8v*)(W16 + (long)(o0 + so) * Cin + k0 + scg);
#pragma unroll
        for (int s = 0; s < 2; ++s) {
            int cb = k0 + s * 16;
            long rb = (cb < iSplit) ? (long)cb * iLo : (long)(cb - iSplit) * iLo + iHi;
            const float* g = X + xb + rb + pa;
            float v[16];
#pragma unroll
            for (int j = 0; j < 16; ++j) v[j] = g[(long)j * iLo];
            h8v h0, h1;
#pragma unroll
            for (int j = 0; j < 8; ++j) { h0[j] = (half_t)v[j]; h1[j] = (half_t)v[8 + j]; }
            *(h8v*)&Xh[t * 40 + s * 16] = h0;
            *(h8v*)&Xh[t * 40 + s * 16 + 8] = h1;
        }
        __syncthreads();
        h8v a[4], bb[4];
#pragma unroll
        for (int m = 0; m < 4; ++m) a[m] = *(const h8v*)&Wh[(m * 16 + fr) * 40 + fg * 8];
#pragma unroll
        for (int n = 0; n < 4; ++n) bb[n] = *(const h8v*)&Xh[(wv * 64 + n * 16 + fr) * 40 + fg * 8];
#pragma unroll
        for (int m = 0; m < 4; ++m)
#pragma unroll
            for (int n = 0; n < 4; ++n)
                acc[m][n] = __builtin_amdgcn_mfma_f32_16x16x32_f16(a[m], bb[n], acc[m][n], 0, 0, 0);
    }
    long pe[4];
#pragma unroll
    for (int n = 0; n < 4; ++n) {
        long p = p0 + wv * 64 + n * 16 + fr;
        if (PFOLD) { long q = p / 80; pe[n] = q * LT_ROW + (p - q * 80); } else pe[n] = p;
    }
#pragma unroll
    for (int m = 0; m < 4; ++m)
#pragma unroll
        for (int i = 0; i < 4; ++i) {
            int o = o0 + m * 16 + fg * 4 + i;
            long oadr = ob + ((o < oSplit) ? (long)o * oLo : (long)(o - oSplit) * oLo + oHi);
#pragma unroll
            for (int n = 0; n < 4; ++n) {
                float v = acc[m][n][i];
                if (GELU) v = 0.5f * v * (1.f + erff(v * 0.70710678118654752f));
                out[oadr + pe[n]] = v;
            }
        }
}

// ================= K1M: fp32-data x fp16-basis MFMA GEMM (k-contiguous A) ====
template<int NF, int NORM>
__global__ __launch_bounds__(256) void k1m(
    const float* __restrict__ A, long aBatch, long aC, long aRow, int aSplit, long aHiOff, int K,
    const uint* __restrict__ Bt32,
    float* __restrict__ out, long oBatch, long oC, long oRow, int oSplit, long oHiOff,
    float* __restrict__ inv) {
    __shared__ __align__(16) half_t Ah[128 * 40];
    __shared__ __align__(16) half_t Bh[160 * 40];
    const int t = threadIdx.x;
    const long ab = (long)blockIdx.z * aBatch + (long)blockIdx.x * aC;
    const long ob = (long)blockIdx.z * oBatch + (long)blockIdx.x * oC;
    const int N = NF * 32;
    const int lane = t & 63, wv = t >> 6;
    const int wm = wv >> 1, wn = wv & 1;
    const int fr = lane & 15, fg = lane >> 4;
    const int sr = t >> 1, shalf = t & 1;
    const int Kw = K >> 1;
    f32x4 acc[4][NF];
#pragma unroll
    for (int m = 0; m < 4; ++m)
#pragma unroll
        for (int n = 0; n < NF; ++n) acc[m][n] = {0.f, 0.f, 0.f, 0.f};
    for (int k0 = 0; k0 < K; k0 += 32) {
        __syncthreads();
        {
            int cb = k0 + shalf * 16;
            long rb = (cb < aSplit) ? (long)cb : (long)(cb - aSplit) + aHiOff;
            const float* g = A + ab + (long)sr * aRow + rb;
            float4 v0 = *(const float4*)g;
            float4 v1 = *(const float4*)(g + 4);
            float4 v2 = *(const float4*)(g + 8);
            float4 v3 = *(const float4*)(g + 12);
            h8v h0, h1;
            h0[0] = (half_t)v0.x; h0[1] = (half_t)v0.y; h0[2] = (half_t)v0.z; h0[3] = (half_t)v0.w;
            h0[4] = (half_t)v1.x; h0[5] = (half_t)v1.y; h0[6] = (half_t)v1.z; h0[7] = (half_t)v1.w;
            h1[0] = (half_t)v2.x; h1[1] = (half_t)v2.y; h1[2] = (half_t)v2.z; h1[3] = (half_t)v2.w;
            h1[4] = (half_t)v3.x; h1[5] = (half_t)v3.y; h1[6] = (half_t)v3.z; h1[7] = (half_t)v3.w;
            *(h8v*)&Ah[sr * 40 + shalf * 16] = h0;
            *(h8v*)&Ah[sr * 40 + shalf * 16 + 8] = h1;
        }
        for (int j = t; j < N * 16; j += 256) {
            int n = j >> 4, kw = j & 15;
            *(uint*)&Bh[n * 40 + kw * 2] = Bt32[(long)n * Kw + (k0 >> 1) + kw];
        }
        __syncthreads();
        h8v a[4], bb[NF];
#pragma unroll
        for (int m = 0; m < 4; ++m) a[m] = *(const h8v*)&Ah[(wm * 64 + m * 16 + fr) * 40 + fg * 8];
#pragma unroll
        for (int n = 0; n < NF; ++n) bb[n] = *(const h8v*)&Bh[(wn * NF * 16 + n * 16 + fr) * 40 + fg * 8];
#pragma unroll
        for (int m = 0; m < 4; ++m)
#pragma unroll
            for (int n = 0; n < NF; ++n)
                acc[m][n] = __builtin_amdgcn_mfma_f32_16x16x32_f16(a[m], bb[n], acc[m][n], 0, 0, 0);
    }
#pragma unroll
    for (int m = 0; m < 4; ++m)
#pragma unroll
        for (int i = 0; i < 4; ++i) {
            int r = wm * 64 + m * 16 + fg * 4 + i;
            float* orow = out + ob + (long)r * oRow;
#pragma unroll
            for (int n = 0; n < NF; ++n) {
                int j = wn * NF * 16 + n * 16 + fr;
                long jm = (j < oSplit) ? (long)j : (long)(j - oSplit) + oHiOff;
                orow[jm] = acc[m][n][i];
            }
        }
    if (NORM) {
        float ss = 0.f;
#pragma unroll
        for (int m = 0; m < 4; ++m)
#pragma unroll
            for (int n = 0; n < NF; ++n)
#pragma unroll
                for (int i = 0; i < 4; ++i) ss += acc[m][n][i] * acc[m][n][i];
        __syncthreads();
        float* red = (float*)Ah;
        red[t] = ss;
        __syncthreads();
        for (int st = 128; st > 0; st >>= 1) {
            if (t < st) red[t] += red[t + st];
            __syncthreads();
        }
        if (t == 0) inv[(long)blockIdx.z * 192 + blockIdx.x] = 1.f / fmaxf(sqrtf(red[0]), 1e-12f);
    }
}

// ---------- depthwise 3x3, pad 1: one block per (channel, batch) plane ----------
__global__ __launch_bounds__(256) void dw3_k(
    const float* __restrict__ in, long inBatch,
    const float* __restrict__ w9,
    float* __restrict__ out, long outBatch,
    int normCnt, float* __restrict__ inv) {
    const int c = blockIdx.x, b = blockIdx.y;
    const int t = threadIdx.x;
    const float* ip = in + (long)b * inBatch + (long)c * HW;
    float* op = out + (long)b * outBatch + (long)c * HW;
    const float* wp = w9 + c * 9;
    const float w0 = wp[0], w1 = wp[1], w2 = wp[2];
    const float w3 = wp[3], w4 = wp[4], w5 = wp[5];
    const float w6 = wp[6], w7 = wp[7], w8 = wp[8];
    const int tx = t & 31;
    const int x0 = tx * 4;
    const int y0 = (t >> 5) * 16;
    const bool lx = (tx > 0), rx = (tx < 31);
    float Ar[6], Br[6], Cr[6];
#define LOADROW(Y, R) do { \
        const float* _p = ip + (Y) * 128 + x0; \
        float4 _v = *(const float4*)_p; \
        R[1] = _v.x; R[2] = _v.y; R[3] = _v.z; R[4] = _v.w; \
        R[0] = lx ? _p[-1] : 0.f; \
        R[5] = rx ? _p[4] : 0.f; } while (0)
    if (y0 == 0) { Ar[0]=Ar[1]=Ar[2]=Ar[3]=Ar[4]=Ar[5]=0.f; }
    else LOADROW(y0 - 1, Ar);
    LOADROW(y0, Br);
    float ss = 0.f;
#pragma unroll
    for (int i = 0; i < 16; ++i) {
        int y = y0 + i;
        if (y + 1 < 128) { LOADROW(y + 1, Cr); }
        else { Cr[0]=Cr[1]=Cr[2]=Cr[3]=Cr[4]=Cr[5]=0.f; }
        float o0 = Ar[0]*w0 + Ar[1]*w1 + Ar[2]*w2
                 + Br[0]*w3 + Br[1]*w4 + Br[2]*w5
                 + Cr[0]*w6 + Cr[1]*w7 + Cr[2]*w8;
        float o1 = Ar[1]*w0 + Ar[2]*w1 + Ar[3]*w2
                 + Br[1]*w3 + Br[2]*w4 + Br[3]*w5
                 + Cr[1]*w6 + Cr[2]*w7 + Cr[3]*w8;
        float o2 = Ar[2]*w0 + Ar[3]*w1 + Ar[4]*w2
                 + Br[2]*w3 + Br[3]*w4 + Br[4]*w5
                 + Cr[2]*w6 + Cr[3]*w7 + Cr[4]*w8;
        float o3 = Ar[3]*w0 + Ar[4]*w1 + Ar[5]*w2
                 + Br[3]*w3 + Br[4]*w4 + Br[5]*w5
                 + Cr[3]*w6 + Cr[4]*w7 + Cr[5]*w8;
        *(float4*)(op + y * 128 + x0) = make_float4(o0, o1, o2, o3);
        ss += o0*o0 + o1*o1 + o2*o2 + o3*o3;
#pragma unroll
        for (int j = 0; j < 6; ++j) { Ar[j] = Br[j]; Br[j] = Cr[j]; }
    }
#undef LOADROW
    if (normCnt > 0 && c < normCnt) {
        __shared__ float red[256];
        red[t] = ss;
        __syncthreads();
        for (int st = 128; st > 0; st >>= 1) {
            if (t < st) red[t] += red[t + st];
            __syncthreads();
        }
        if (t == 0) inv[(long)b * 192 + c] = 1.f / fmaxf(sqrtf(red[0]), 1e-12f);
    }
}

// ================= fp32 Gram, slice-parallel =================
// Partial G[d][e] over a 256-l slice. grid (32 bn, GSL ls), 576 threads.
// gp layout: [bn][d*24+e][GSL]. Caller must pass a gp buffer that is DEAD
// w.r.t. q, k, and the downstream V read (r6-r8 lesson: OFF_T1 aliased kv2).
__global__ __launch_bounds__(576) void gramf_k(
    const float* __restrict__ q, long qB,
    const float* __restrict__ k, long kB,
    float* __restrict__ gp) {
    __shared__ float qs[HD][260];
    __shared__ float ks[HD][260];
    const int bn = blockIdx.x, ls = blockIdx.y;
    const int b = bn >> 3, n = bn & 7;
    const int t = threadIdx.x;
    const int l0 = ls * 256;
    const float* qp = q + (long)b * qB + (long)(n * HD) * HW + l0;
    const float* kp = k + (long)b * kB + (long)(n * HD) * HW + l0;
    for (int idx = t; idx < HD * 64; idx += 576) {      // 64 float4 per row
        int row = idx >> 6, c4 = (idx & 63) * 4;
        *(float4*)&qs[row][c4] = *(const float4*)(qp + (long)row * HW + c4);
        *(float4*)&ks[row][c4] = *(const float4*)(kp + (long)row * HW + c4);
    }
    __syncthreads();
    const int d = t / 24, e = t - d * 24;               // t < 576
    float acc = 0.f;
#pragma unroll 8
    for (int j = 0; j < 256; j += 4) {
        float4 a = *(const float4*)&qs[d][j];
        float4 bb = *(const float4*)&ks[e][j];
        acc += a.x * bb.x + a.y * bb.y + a.z * bb.z + a.w * bb.w;
    }
    gp[((long)bn * 576 + t) * GSL + ls] = acc;
}

// ---------- slice-sum + normalize + temperature + softmax ----------
__global__ __launch_bounds__(256) void softmax_k(
    const float* __restrict__ gp, const float* __restrict__ invq,
    const float* __restrict__ invk, const float* __restrict__ temp,
    float* __restrict__ attn) {
    int bn = blockIdx.x;
    int b = bn >> 3, n = bn & 7;
    int t = threadIdx.x;
    __shared__ float sums[576];
    for (int idx = t; idx < 576; idx += 256) {
        const float* g = gp + ((long)bn * 576 + idx) * GSL;
        float s = 0.f;
        for (int i = 0; i < GSL; i += 4) {
            float4 v = *(const float4*)(g + i);
            s += v.x + v.y + v.z + v.w;
        }
        sums[idx] = s;
    }
    __syncthreads();
    int d = t;
    if (d >= HD) return;
    float tt = temp[n];
    float iq = invq[b * 192 + n * HD + d];
    float row[HD];
#pragma unroll
    for (int e = 0; e < HD; ++e)
        row[e] = sums[d * HD + e] * iq * invk[b * 192 + n * HD + e] * tt;
    float m = row[0];
#pragma unroll
    for (int e = 1; e < HD; ++e) m = fmaxf(m, row[e]);
    float ssum = 0.f;
#pragma unroll
    for (int e = 0; e < HD; ++e) { row[e] = expf(row[e] - m); ssum += row[e]; }
    float is = 1.f / ssum;
#pragma unroll
    for (int e = 0; e < HD; ++e) attn[(long)bn * 576 + d * HD + e] = row[e] * is;
}

// ---------- out[d,p] = sum_e attn[d,e] * v[e,p] ----------
__global__ void attnapply_k(const float* __restrict__ attn, const float* __restrict__ v,
                            long vB, float* __restrict__ out, long outB) {
    int p = blockIdx.x * 256 + threadIdx.x;
    int bn = blockIdx.y;
    int b = bn >> 3, n = bn & 7;
    __shared__ float a[576];
    for (int i = threadIdx.x; i < 576; i += 256) a[i] = attn[(long)bn * 576 + i];
    __syncthreads();
    const float* vp = v + (long)b * vB + (long)(n * HD) * HW + p;
    float acc[HD];
#pragma unroll
    for (int d = 0; d < HD; ++d) acc[d] = 0.f;
    for (int e = 0; e < HD; ++e) {
        float vv = vp[(long)e * HW];
#pragma unroll
        for (int d = 0; d < HD; ++d) acc[d] += a[d * HD + e] * vv;
    }
    float* op = out + (long)b * outB + (long)(n * HD) * HW + p;
#pragma unroll
    for (int d = 0; d < HD; ++d) op[(long)d * HW] = acc[d];
}

extern "C" void kernel_launch(void* const* d_in, const int* in_sizes, int n_in,
                              void* d_out, int out_size, void* d_ws, size_t ws_size,
                              hipStream_t stream) {
    const float* x        = (const float*)d_in[0];
    const float* w_qkv1   = (const float*)d_in[1];
    const float* w_qkv1dw = (const float*)d_in[2];
    const float* w_proj1  = (const float*)d_in[3];
    const float* w_fdfp1  = (const float*)d_in[4];
    const float* w_fdfp2  = (const float*)d_in[5];
    const float* w_kv2    = (const float*)d_in[6];
    const float* w_kv2dw  = (const float*)d_in[7];
    const float* w_proj2  = (const float*)d_in[8];
    const float* temp     = (const float*)d_in[9];
    float* out = (float*)d_out;
    float* ws  = (float*)d_ws;
    dim3 blk(256);
    const int BIG = 1 << 20;

    // ---- init fp16 weights/bases ----
    cvt16_k<<<432, blk, 0, stream>>>(w_qkv1, (half_t*)(ws + H_WQKV), 110592);
    cvt16_k<<<576, blk, 0, stream>>>(w_fdfp1, (half_t*)(ws + H_W1), 147456);
    cvt16_k<<<576, blk, 0, stream>>>(w_fdfp2, (half_t*)(ws + H_W2), 147456);
    cvt16_k<<<144, blk, 0, stream>>>(w_proj2, (half_t*)(ws + H_PRJ), 36864);
    initB1t_k<<<80, blk, 0, stream>>>((half_t*)(ws + H_B1T));
    initB2h_k<<<256, blk, 0, stream>>>((half_t*)(ws + H_B2));
    initB3h_k<<<256, blk, 0, stream>>>((half_t*)(ws + H_B3));
    initB4t_k<<<80, blk, 0, stream>>>((half_t*)(ws + H_B4T));
    fusew_k<<<384, 192, 0, stream>>>(w_kv2, w_proj1, (half_t*)(ws + H_WF));

    // ---- fdfp(x) -> q2 (+ fused q2 norms) ----
    k1m<5, 0><<<dim3(192, 1, 4), blk, 0, stream>>>(
        x, XB, (long)HW, 128L, BIG, 0L, 128,
        (const uint*)(ws + H_B1T),
        ws + CB0, LT_B, (long)FP, LT_ROW, 80, LT_PART, nullptr);
    k2m<0, 0><<<dim3(4, 60, 4), blk, 0, stream>>>(
        (const half_t*)(ws + H_B2), 256,
        ws + CB0, LT_B, 128, LT_ROW, LT_PART,
        ws + CB1, LT_B, 128, LT_ROW, LT_PART);
    k2m<1, 1><<<dim3(6, 40, 4), blk, 0, stream>>>(
        (const half_t*)(ws + H_W1), 384,
        ws + CB1, LT_B, 192, (long)FP, LT_PART,
        ws + CB2, LT_B, 192, (long)FP, LT_PART);
    k2m<1, 0><<<dim3(6, 40, 4), blk, 0, stream>>>(
        (const half_t*)(ws + H_W2), 384,
        ws + CB2, LT_B, 192, (long)FP, LT_PART,
        ws + CB0, LT_B, 192, (long)FP, LT_PART);
    k2m<0, 0><<<dim3(4, 60, 4), blk, 0, stream>>>(
        (const half_t*)(ws + H_B3), 256,
        ws + CB0, LT_B, 128, LT_ROW, LT_PART,
        ws + CB1, LT_B, 128, LT_ROW, LT_PART);
    k1m<4, 1><<<dim3(192, 1, 4), blk, 0, stream>>>(
        ws + CB1, LT_B, (long)FP, LT_ROW, 80, LT_PART, 160,
        (const uint*)(ws + H_B4T),
        ws + OFF_Q2, XB, (long)HW, 128L, BIG, 0L, ws + SM_INVQ2);

    // ---- stage 1: qkv = dw3(conv1x1(x)) in 3 chunks (+ fused q1/k1 norms) ----
    for (int ch = 0; ch < 3; ++ch) {
        k2m<0, 0><<<dim3(3, 64, 4), blk, 0, stream>>>(
            (const half_t*)(ws + H_WQKV) + (long)ch * 192 * 192, 192,
            x, XB, BIG, (long)HW, 0L,
            ws + OFF_T1, XB, BIG, (long)HW, 0L);
        dw3_k<<<dim3(192, 4), blk, 0, stream>>>(
            ws + OFF_T1, XB, w_qkv1dw + ch * 192 * 9,
            ws + (long)ch * 192 * HW, (long)576 * HW,
            ch == 2 ? 0 : 192,
            ch == 0 ? ws + SM_INVQ1 : ws + SM_INVK1);
    }
    // stage-1 partials at OFF_T1: qkv [0..37.7M) live, OFF_T1 [37.7M..] free.
    gramf_k<<<dim3(32, GSL), 576, 0, stream>>>(
        ws, (long)576 * HW, ws + (long)192 * HW, (long)576 * HW, ws + OFF_T1);
    softmax_k<<<32, blk, 0, stream>>>(ws + OFF_T1, ws + SM_INVQ1, ws + SM_INVK1, temp, ws + SM_ATT);
    attnapply_k<<<dim3(64, 32), blk, 0, stream>>>(
        ws + SM_ATT, ws + (long)384 * HW, (long)576 * HW, ws + OFF_T1, XB);

    // ---- kv2 = dw3(conv1x1(out1, Wf)) (+ fused k2 norms) ----
    k2m<0, 0><<<dim3(6, 64, 4), blk, 0, stream>>>(
        (const half_t*)(ws + H_WF), 192,
        ws + OFF_T1, XB, BIG, (long)HW, 0L,
        ws + OFF_KT, (long)384 * HW, BIG, (long)HW, 0L);
    dw3_k<<<dim3(384, 4), blk, 0, stream>>>(
        ws + OFF_KT, (long)384 * HW, w_kv2dw, ws + OFF_KF, (long)384 * HW,
        192, ws + SM_INVK2);

    // ---- stage 2 attention ----
    // partials at ws[0..1.18M): kv2 pre-dw tmp region, dead after dw3.
    // (NOT OFF_T1 — that aliases kv2 batch 2, the r6-r8 corruption.)
    gramf_k<<<dim3(32, GSL), 576, 0, stream>>>(
        ws + OFF_Q2, XB, ws + OFF_KF, (long)384 * HW, ws + OFF_KT);
    softmax_k<<<32, blk, 0, stream>>>(ws + OFF_KT, ws + SM_INVQ2, ws + SM_INVK2, temp, ws + SM_ATT);
    attnapply_k<<<dim3(64, 32), blk, 0, stream>>>(
        ws + SM_ATT, ws + OFF_KF + (long)192 * HW, (long)384 * HW, ws + OFF_O2, XB);
    k2m<0, 0><<<dim3(3, 64, 4), blk, 0, stream>>>(
        (const half_t*)(ws + H_PRJ), 192,
        ws + OFF_O2, XB, BIG, (long)HW, 0L,
        out, XB, BIG, (long)HW, 0L);
}

// Round 11
// 672.930 us; speedup vs baseline: 8.7177x; 1.0650x over previous
//
#include <hip/hip_runtime.h>
#include <math.h>

typedef _Float16 half_t;
typedef half_t h8v __attribute__((ext_vector_type(8)));
typedef half_t h4v __attribute__((ext_vector_type(4)));
typedef float f32x4 __attribute__((ext_vector_type(4)));

namespace {
constexpr int DIMC = 192;
constexpr int NB = 4;
constexpr int HH = 128, WW = 128;
constexpr int HW = HH * WW;              // 16384
constexpr int NH = 8, HD = 24;
constexpr int FP = 80;                   // padded kx width (65 valid)
constexpr long LT_PART = 128L * 192 * FP;          // 1,966,080
constexpr long LT_B    = 2 * LT_PART;              // 3,932,160
constexpr long LT_ROW  = 192L * FP;                // 15360
constexpr long XB  = 192L * HW;                    // 3,145,728
constexpr long CB0 = 0;
constexpr long CB1 = 15728640;
constexpr long CB2 = 31457280;           // (now unused by fused FFN)
constexpr long OFF_T1 = 37748736;        // conv tmp / out1 / stage-1 gram partials
constexpr long OFF_Q2 = 50331648;        // q2
constexpr long OFF_S  = 62914560;        // small region
constexpr long OFF_KT = 0;               // kv2 pre-dw tmp / stage-2 gram partials
constexpr long OFF_KF = 25165824;        // kv2 final  [25.1M..50.3M) — overlaps OFF_T1!
constexpr long OFF_O2 = 0;               // out2 tmp
constexpr int  GSL = 64;                 // gram l-slices (256 l each)
constexpr long SM_INVQ1 = OFF_S;                // 768
constexpr long SM_INVK1 = OFF_S + 768;          // 768
constexpr long SM_INVQ2 = OFF_S + 1536;         // 768
constexpr long SM_INVK2 = OFF_S + 2304;         // 768
constexpr long SM_ATT   = OFF_S + 3072;         // 18,432
constexpr long H0       = OFF_S + 168960;       // fp16 pool (float units)
constexpr long H_WQKV = H0;                     // 110,592 h
constexpr long H_WF   = H0 + 55296;             // 73,728 h
constexpr long H_W1   = H0 + 92160;             // 147,456 h
constexpr long H_W2   = H0 + 165888;            // 147,456 h
constexpr long H_PRJ  = H0 + 239616;            // 36,864 h
constexpr long H_B2   = H0 + 258048;            // 65,536 h
constexpr long H_B3   = H0 + 290816;            // 65,536 h
constexpr long H_B1T  = H0 + 323584;            // 160x128 h
constexpr long H_B4T  = H0 + 333824;            // 128x160 h
constexpr float PI2 = 6.283185307179586476f;
}

// ================= init: fp16 weight/basis materialization =================
__global__ void cvt16_k(const float* __restrict__ in, half_t* __restrict__ o, int n) {
    int i = blockIdx.x * 256 + threadIdx.x;
    if (i < n) o[i] = (half_t)in[i];
}
__global__ void initB1t_k(half_t* __restrict__ B) {      // [160 j][128 k]
    int idx = blockIdx.x * 256 + threadIdx.x;
    if (idx >= 160 * 128) return;
    int j = idx / 128, k = idx % 128;
    float v = 0.f;
    if (j < 65) v = cosf(PI2 * ((k * j) & 127) / 128.f) * (1.f / 128.f);
    else if (j >= 80 && j < 145) v = -sinf(PI2 * ((k * (j - 80)) & 127) / 128.f) * (1.f / 128.f);
    B[idx] = (half_t)v;
}
__global__ void initB2h_k(half_t* __restrict__ B) {      // [256 m][256 c]
    int idx = blockIdx.x * 256 + threadIdx.x;
    int m = idx >> 8, cin = idx & 255;
    int pd = m >> 7, ky = m & 127;
    int ps = cin >> 7, y = cin & 127;
    float c, s; sincosf(PI2 * ((ky * y) & 127) / 128.f, &s, &c);
    float v = (pd == 0) ? (ps == 0 ? c : s) : (ps == 0 ? -s : c);
    B[idx] = (half_t)v;
}
__global__ void initB3h_k(half_t* __restrict__ B) {      // [256 m][256 c]
    int idx = blockIdx.x * 256 + threadIdx.x;
    int m = idx >> 8, cin = idx & 255;
    int pd = m >> 7, y = m & 127;
    int ps = cin >> 7, ky = cin & 127;
    float c, s; sincosf(PI2 * ((y * ky) & 127) / 128.f, &s, &c);
    float v = (pd == 0) ? (ps == 0 ? c : -s) : (ps == 0 ? s : c);
    B[idx] = (half_t)v;
}
__global__ void initB4t_k(half_t* __restrict__ B) {      // [128 j][160 k]
    int idx = blockIdx.x * 256 + threadIdx.x;
    if (idx >= 128 * 160) return;
    int j = idx / 160, k = idx % 160;
    float v = 0.f;
    if (k < 80) {
        if (k == 0) v = 1.f / 128.f;
        else if (k < 64) v = 2.f * cosf(PI2 * ((k * j) & 127) / 128.f) / 128.f;
        else if (k == 64) v = cosf(PI2 * ((64 * j) & 127) / 128.f) / 128.f;
    } else {
        int kx = k - 80;
        if (kx >= 1 && kx < 64) v = -2.f * sinf(PI2 * ((kx * j) & 127) / 128.f) / 128.f;
    }
    B[idx] = (half_t)v;
}
__global__ void fusew_k(const float* __restrict__ wkv, const float* __restrict__ wproj,
                        half_t* __restrict__ wf) {
    int o = blockIdx.x, c = threadIdx.x;
    float acc = 0.f;
    for (int m = 0; m < 192; ++m) acc += wkv[o * 192 + m] * wproj[m * 192 + c];
    wf[o * 192 + c] = (half_t)acc;
}

// ================= K2M: fp16-weights x fp32-data MFMA GEMM =================
template<int PFOLD, int GELU>
__global__ __launch_bounds__(256) void k2m(
    const half_t* __restrict__ W16, int Cin,
    const float* __restrict__ X, long xBatch, int iSplit, long iLo, long iHi,
    float* __restrict__ out, long oBatch, int oSplit, long oLo, long oHi) {
    __shared__ __align__(16) half_t Wh[64 * 40];
    __shared__ __align__(16) half_t Xh[256 * 40];
    const int t = threadIdx.x;
    const int o0 = blockIdx.x * 64;
    const long p0 = (long)blockIdx.y * 256;
    const long xb = (long)blockIdx.z * xBatch;
    const long ob = (long)blockIdx.z * oBatch;
    const int lane = t & 63, wv = t >> 6;
    const int fr = lane & 15, fg = lane >> 4;
    const int so = t >> 2, scg = (t & 3) * 8;
    f32x4 acc[4][4];
#pragma unroll
    for (int m = 0; m < 4; ++m)
#pragma unroll
        for (int n = 0; n < 4; ++n) acc[m][n] = {0.f, 0.f, 0.f, 0.f};
    long pa;
    {
        long p = p0 + t;
        if (PFOLD) { long q = p / 80; pa = q * LT_ROW + (p - q * 80); } else pa = p;
    }
    for (int k0 = 0; k0 < Cin; k0 += 32) {
        __syncthreads();
        *(h8v*)&Wh[so * 40 + scg] =
            *(const h8v*)(W16 + (long)(o0 + so) * Cin + k0 + scg);
#pragma unroll
        for (int s = 0; s < 2; ++s) {
            int cb = k0 + s * 16;
            long rb = (cb < iSplit) ? (long)cb * iLo : (long)(cb - iSplit) * iLo + iHi;
            const float* g = X + xb + rb + pa;
            float v[16];
#pragma unroll
            for (int j = 0; j < 16; ++j) v[j] = g[(long)j * iLo];
            h8v h0, h1;
#pragma unroll
            for (int j = 0; j < 8; ++j) { h0[j] = (half_t)v[j]; h1[j] = (half_t)v[8 + j]; }
            *(h8v*)&Xh[t * 40 + s * 16] = h0;
            *(h8v*)&Xh[t * 40 + s * 16 + 8] = h1;
        }
        __syncthreads();
        h8v a[4], bb[4];
#pragma unroll
        for (int m = 0; m < 4; ++m) a[m] = *(const h8v*)&Wh[(m * 16 + fr) * 40 + fg * 8];
#pragma unroll
        for (int n = 0; n < 4; ++n) bb[n] = *(const h8v*)&Xh[(wv * 64 + n * 16 + fr) * 40 + fg * 8];
#pragma unroll
        for (int m = 0; m < 4; ++m)
#pragma unroll
            for (int n = 0; n < 4; ++n)
                acc[m][n] = __builtin_amdgcn_mfma_f32_16x16x32_f16(a[m], bb[n], acc[m][n], 0, 0, 0);
    }
    long pe[4];
#pragma unroll
    for (int n = 0; n < 4; ++n) {
        long p = p0 + wv * 64 + n * 16 + fr;
        if (PFOLD) { long q = p / 80; pe[n] = q * LT_ROW + (p - q * 80); } else pe[n] = p;
    }
#pragma unroll
    for (int m = 0; m < 4; ++m)
#pragma unroll
        for (int i = 0; i < 4; ++i) {
            int o = o0 + m * 16 + fg * 4 + i;
            long oadr = ob + ((o < oSplit) ? (long)o * oLo : (long)(o - oSplit) * oLo + oHi);
#pragma unroll
            for (int n = 0; n < 4; ++n) {
                float v = acc[m][n][i];
                if (GELU) v = 0.5f * v * (1.f + erff(v * 0.70710678118654752f));
                out[oadr + pe[n]] = v;
            }
        }
}

// ================= KFF: fused W1 -> GELU -> W2 over a 64-p slab ==============
// Block: 512 threads (8 waves). Wave w owns outputs [w*48, w*48+48) x 64 p.
// X streamed fp16 via LDS; Y (post-gelu) parked fp16 in LDS; Z written direct.
// Channel map (in AND out): c<192 -> c*80, else (c-192)*80 + LT_PART.
// p map: q=(p0+p)/80 -> q*LT_ROW + (p0+p-q*80).
__global__ __launch_bounds__(512) void kff(
    const half_t* __restrict__ W1, const half_t* __restrict__ W2,
    const float* __restrict__ X, float* __restrict__ out) {
    __shared__ __align__(16) half_t Wh[384 * 40];   // 30720 B
    __shared__ __align__(16) half_t Xh[64 * 40];    //  5120 B
    __shared__ __align__(16) half_t Yh[64 * 392];   // 50176 B
    const int t = threadIdx.x;
    const long p0 = (long)blockIdx.x * 64;
    const long xb = (long)blockIdx.y * LT_B;
    const int lane = t & 63, wv = t >> 6;           // 0..7
    const int fr = lane & 15, fg = lane >> 4;
    // X staging indices: thread loads p = t&63, k-group (t>>6)*4 .. +3
    const int sp = t & 63;
    const int skb = (t >> 6) * 4;
    long pa;
    { long p = p0 + sp; long q = p / 80; pa = q * LT_ROW + (p - q * 80); }
    f32x4 acc[3][4];
#pragma unroll
    for (int m = 0; m < 3; ++m)
#pragma unroll
        for (int n = 0; n < 4; ++n) acc[m][n] = {0.f, 0.f, 0.f, 0.f};

    // -------- stage 1: Y = W1 @ X --------
    for (int k0 = 0; k0 < 384; k0 += 32) {
        __syncthreads();
        // W1 chunk: 384 o x 32 k -> Wh[o][k], 1536 h8v tasks / 512 threads = 3
#pragma unroll
        for (int r = 0; r < 3; ++r) {
            int task = t + r * 512;
            int o = task >> 2, kg = (task & 3) * 8;
            *(h8v*)&Wh[o * 40 + kg] = *(const h8v*)(W1 + (long)o * 384 + k0 + kg);
        }
        // X chunk: 64 p x 32 k
        {
            int c0 = k0 + skb;
            long rb = (c0 < 192) ? (long)c0 * 80 : (long)(c0 - 192) * 80 + LT_PART;
            const float* g = X + xb + rb + pa;
            h4v h;
#pragma unroll
            for (int j = 0; j < 4; ++j) h[j] = (half_t)g[(long)j * 80];
            *(h4v*)&Xh[sp * 40 + skb] = h;
        }
        __syncthreads();
        h8v a[3], bb[4];
#pragma unroll
        for (int m = 0; m < 3; ++m) a[m] = *(const h8v*)&Wh[(wv * 48 + m * 16 + fr) * 40 + fg * 8];
#pragma unroll
        for (int n = 0; n < 4; ++n) bb[n] = *(const h8v*)&Xh[(n * 16 + fr) * 40 + fg * 8];
#pragma unroll
        for (int m = 0; m < 3; ++m)
#pragma unroll
            for (int n = 0; n < 4; ++n)
                acc[m][n] = __builtin_amdgcn_mfma_f32_16x16x32_f16(a[m], bb[n], acc[m][n], 0, 0, 0);
    }
    // gelu + park Y in LDS as [p][c] fp16 (same quantization point as unfused path)
#pragma unroll
    for (int m = 0; m < 3; ++m)
#pragma unroll
        for (int n = 0; n < 4; ++n) {
            int o4 = wv * 48 + m * 16 + fg * 4;
            int p = n * 16 + fr;
            h4v h;
#pragma unroll
            for (int i = 0; i < 4; ++i) {
                float v = acc[m][n][i];
                v = 0.5f * v * (1.f + erff(v * 0.70710678118654752f));
                h[i] = (half_t)v;
            }
            *(h4v*)&Yh[p * 392 + o4] = h;
        }
#pragma unroll
    for (int m = 0; m < 3; ++m)
#pragma unroll
        for (int n = 0; n < 4; ++n) acc[m][n] = {0.f, 0.f, 0.f, 0.f};

    // -------- stage 2: Z = W2 @ Y --------
    for (int k0 = 0; k0 < 384; k0 += 32) {
        __syncthreads();
#pragma unroll
        for (int r = 0; r < 3; ++r) {
            int task = t + r * 512;
            int o = task >> 2, kg = (task & 3) * 8;
            *(h8v*)&Wh[o * 40 + kg] = *(const h8v*)(W2 + (long)o * 384 + k0 + kg);
        }
        __syncthreads();
        h8v a[3], bb[4];
#pragma unroll
        for (int m = 0; m < 3; ++m) a[m] = *(const h8v*)&Wh[(wv * 48 + m * 16 + fr) * 40 + fg * 8];
#pragma unroll
        for (int n = 0; n < 4; ++n) bb[n] = *(const h8v*)&Yh[(n * 16 + fr) * 392 + k0 + fg * 8];
#pragma unroll
        for (int m = 0; m < 3; ++m)
#pragma unroll
            for (int n = 0; n < 4; ++n)
                acc[m][n] = __builtin_amdgcn_mfma_f32_16x16x32_f16(a[m], bb[n], acc[m][n], 0, 0, 0);
    }
    // epilogue: Z -> global (folded layout)
    long pe[4];
#pragma unroll
    for (int n = 0; n < 4; ++n) {
        long p = p0 + n * 16 + fr;
        long q = p / 80; pe[n] = q * LT_ROW + (p - q * 80);
    }
#pragma unroll
    for (int m = 0; m < 3; ++m)
#pragma unroll
        for (int i = 0; i < 4; ++i) {
            int o = wv * 48 + m * 16 + fg * 4 + i;
            long oadr = xb + ((o < 192) ? (long)o * 80 : (long)(o - 192) * 80 + LT_PART);
#pragma unroll
            for (int n = 0; n < 4; ++n) out[oadr + pe[n]] = acc[m][n][i];
        }
}

// ================= K1M: fp32-data x fp16-basis MFMA GEMM (k-contiguous A) ====
template<int NF, int NORM>
__global__ __launch_bounds__(256) void k1m(
    const float* __restrict__ A, long aBatch, long aC, long aRow, int aSplit, long aHiOff, int K,
    const uint* __restrict__ Bt32,
    float* __restrict__ out, long oBatch, long oC, long oRow, int oSplit, long oHiOff,
    float* __restrict__ inv) {
    __shared__ __align__(16) half_t Ah[128 * 40];
    __shared__ __align__(16) half_t Bh[160 * 40];
    const int t = threadIdx.x;
    const long ab = (long)blockIdx.z * aBatch + (long)blockIdx.x * aC;
    const long ob = (long)blockIdx.z * oBatch + (long)blockIdx.x * oC;
    const int N = NF * 32;
    const int lane = t & 63, wv = t >> 6;
    const int wm = wv >> 1, wn = wv & 1;
    const int fr = lane & 15, fg = lane >> 4;
    const int sr = t >> 1, shalf = t & 1;
    const int Kw = K >> 1;
    f32x4 acc[4][NF];
#pragma unroll
    for (int m = 0; m < 4; ++m)
#pragma unroll
        for (int n = 0; n < NF; ++n) acc[m][n] = {0.f, 0.f, 0.f, 0.f};
    for (int k0 = 0; k0 < K; k0 += 32) {
        __syncthreads();
        {
            int cb = k0 + shalf * 16;
            long rb = (cb < aSplit) ? (long)cb : (long)(cb - aSplit) + aHiOff;
            const float* g = A + ab + (long)sr * aRow + rb;
            float4 v0 = *(const float4*)g;
            float4 v1 = *(const float4*)(g + 4);
            float4 v2 = *(const float4*)(g + 8);
            float4 v3 = *(const float4*)(g + 12);
            h8v h0, h1;
            h0[0] = (half_t)v0.x; h0[1] = (half_t)v0.y; h0[2] = (half_t)v0.z; h0[3] = (half_t)v0.w;
            h0[4] = (half_t)v1.x; h0[5] = (half_t)v1.y; h0[6] = (half_t)v1.z; h0[7] = (half_t)v1.w;
            h1[0] = (half_t)v2.x; h1[1] = (half_t)v2.y; h1[2] = (half_t)v2.z; h1[3] = (half_t)v2.w;
            h1[4] = (half_t)v3.x; h1[5] = (half_t)v3.y; h1[6] = (half_t)v3.z; h1[7] = (half_t)v3.w;
            *(h8v*)&Ah[sr * 40 + shalf * 16] = h0;
            *(h8v*)&Ah[sr * 40 + shalf * 16 + 8] = h1;
        }
        for (int j = t; j < N * 16; j += 256) {
            int n = j >> 4, kw = j & 15;
            *(uint*)&Bh[n * 40 + kw * 2] = Bt32[(long)n * Kw + (k0 >> 1) + kw];
        }
        __syncthreads();
        h8v a[4], bb[NF];
#pragma unroll
        for (int m = 0; m < 4; ++m) a[m] = *(const h8v*)&Ah[(wm * 64 + m * 16 + fr) * 40 + fg * 8];
#pragma unroll
        for (int n = 0; n < NF; ++n) bb[n] = *(const h8v*)&Bh[(wn * NF * 16 + n * 16 + fr) * 40 + fg * 8];
#pragma unroll
        for (int m = 0; m < 4; ++m)
#pragma unroll
            for (int n = 0; n < NF; ++n)
                acc[m][n] = __builtin_amdgcn_mfma_f32_16x16x32_f16(a[m], bb[n], acc[m][n], 0, 0, 0);
    }
#pragma unroll
    for (int m = 0; m < 4; ++m)
#pragma unroll
        for (int i = 0; i < 4; ++i) {
            int r = wm * 64 + m * 16 + fg * 4 + i;
            float* orow = out + ob + (long)r * oRow;
#pragma unroll
            for (int n = 0; n < NF; ++n) {
                int j = wn * NF * 16 + n * 16 + fr;
                long jm = (j < oSplit) ? (long)j : (long)(j - oSplit) + oHiOff;
                orow[jm] = acc[m][n][i];
            }
        }
    if (NORM) {
        float ss = 0.f;
#pragma unroll
        for (int m = 0; m < 4; ++m)
#pragma unroll
            for (int n = 0; n < NF; ++n)
#pragma unroll
                for (int i = 0; i < 4; ++i) ss += acc[m][n][i] * acc[m][n][i];
        __syncthreads();
        float* red = (float*)Ah;
        red[t] = ss;
        __syncthreads();
        for (int st = 128; st > 0; st >>= 1) {
            if (t < st) red[t] += red[t + st];
            __syncthreads();
        }
        if (t == 0) inv[(long)blockIdx.z * 192 + blockIdx.x] = 1.f / fmaxf(sqrtf(red[0]), 1e-12f);
    }
}

// ---------- depthwise 3x3, pad 1: one block per (channel, batch) plane ----------
__global__ __launch_bounds__(256) void dw3_k(
    const float* __restrict__ in, long inBatch,
    const float* __restrict__ w9,
    float* __restrict__ out, long outBatch,
    int normCnt, float* __restrict__ inv) {
    const int c = blockIdx.x, b = blockIdx.y;
    const int t = threadIdx.x;
    const float* ip = in + (long)b * inBatch + (long)c * HW;
    float* op = out + (long)b * outBatch + (long)c * HW;
    const float* wp = w9 + c * 9;
    const float w0 = wp[0], w1 = wp[1], w2 = wp[2];
    const float w3 = wp[3], w4 = wp[4], w5 = wp[5];
    const float w6 = wp[6], w7 = wp[7], w8 = wp[8];
    const int tx = t & 31;
    const int x0 = tx * 4;
    const int y0 = (t >> 5) * 16;
    const bool lx = (tx > 0), rx = (tx < 31);
    float Ar[6], Br[6], Cr[6];
#define LOADROW(Y, R) do { \
        const float* _p = ip + (Y) * 128 + x0; \
        float4 _v = *(const float4*)_p; \
        R[1] = _v.x; R[2] = _v.y; R[3] = _v.z; R[4] = _v.w; \
        R[0] = lx ? _p[-1] : 0.f; \
        R[5] = rx ? _p[4] : 0.f; } while (0)
    if (y0 == 0) { Ar[0]=Ar[1]=Ar[2]=Ar[3]=Ar[4]=Ar[5]=0.f; }
    else LOADROW(y0 - 1, Ar);
    LOADROW(y0, Br);
    float ss = 0.f;
#pragma unroll
    for (int i = 0; i < 16; ++i) {
        int y = y0 + i;
        if (y + 1 < 128) { LOADROW(y + 1, Cr); }
        else { Cr[0]=Cr[1]=Cr[2]=Cr[3]=Cr[4]=Cr[5]=0.f; }
        float o0 = Ar[0]*w0 + Ar[1]*w1 + Ar[2]*w2
                 + Br[0]*w3 + Br[1]*w4 + Br[2]*w5
                 + Cr[0]*w6 + Cr[1]*w7 + Cr[2]*w8;
        float o1 = Ar[1]*w0 + Ar[2]*w1 + Ar[3]*w2
                 + Br[1]*w3 + Br[2]*w4 + Br[3]*w5
                 + Cr[1]*w6 + Cr[2]*w7 + Cr[3]*w8;
        float o2 = Ar[2]*w0 + Ar[3]*w1 + Ar[4]*w2
                 + Br[2]*w3 + Br[3]*w4 + Br[4]*w5
                 + Cr[2]*w6 + Cr[3]*w7 + Cr[4]*w8;
        float o3 = Ar[3]*w0 + Ar[4]*w1 + Ar[5]*w2
                 + Br[3]*w3 + Br[4]*w4 + Br[5]*w5
                 + Cr[3]*w6 + Cr[4]*w7 + Cr[5]*w8;
        *(float4*)(op + y * 128 + x0) = make_float4(o0, o1, o2, o3);
        ss += o0*o0 + o1*o1 + o2*o2 + o3*o3;
#pragma unroll
        for (int j = 0; j < 6; ++j) { Ar[j] = Br[j]; Br[j] = Cr[j]; }
    }
#undef LOADROW
    if (normCnt > 0 && c < normCnt) {
        __shared__ float red[256];
        red[t] = ss;
        __syncthreads();
        for (int st = 128; st > 0; st >>= 1) {
            if (t < st) red[t] += red[t + st];
            __syncthreads();
        }
        if (t == 0) inv[(long)b * 192 + c] = 1.f / fmaxf(sqrtf(red[0]), 1e-12f);
    }
}

// ================= fp32 Gram, slice-parallel =================
__global__ __launch_bounds__(576) void gramf_k(
    const float* __restrict__ q, long qB,
    const float* __restrict__ k, long kB,
    float* __restrict__ gp) {
    __shared__ float qs[HD][260];
    __shared__ float ks[HD][260];
    const int bn = blockIdx.x, ls = blockIdx.y;
    const int b = bn >> 3, n = bn & 7;
    const int t = threadIdx.x;
    const int l0 = ls * 256;
    const float* qp = q + (long)b * qB + (long)(n * HD) * HW + l0;
    const float* kp = k + (long)b * kB + (long)(n * HD) * HW + l0;
    for (int idx = t; idx < HD * 64; idx += 576) {
        int row = idx >> 6, c4 = (idx & 63) * 4;
        *(float4*)&qs[row][c4] = *(const float4*)(qp + (long)row * HW + c4);
        *(float4*)&ks[row][c4] = *(const float4*)(kp + (long)row * HW + c4);
    }
    __syncthreads();
    const int d = t / 24, e = t - d * 24;
    float acc = 0.f;
#pragma unroll 8
    for (int j = 0; j < 256; j += 4) {
        float4 a = *(const float4*)&qs[d][j];
        float4 bb = *(const float4*)&ks[e][j];
        acc += a.x * bb.x + a.y * bb.y + a.z * bb.z + a.w * bb.w;
    }
    gp[((long)bn * 576 + t) * GSL + ls] = acc;
}

// ---------- slice-sum + normalize + temperature + softmax ----------
__global__ __launch_bounds__(256) void softmax_k(
    const float* __restrict__ gp, const float* __restrict__ invq,
    const float* __restrict__ invk, const float* __restrict__ temp,
    float* __restrict__ attn) {
    int bn = blockIdx.x;
    int b = bn >> 3, n = bn & 7;
    int t = threadIdx.x;
    __shared__ float sums[576];
    for (int idx = t; idx < 576; idx += 256) {
        const float* g = gp + ((long)bn * 576 + idx) * GSL;
        float s = 0.f;
        for (int i = 0; i < GSL; i += 4) {
            float4 v = *(const float4*)(g + i);
            s += v.x + v.y + v.z + v.w;
        }
        sums[idx] = s;
    }
    __syncthreads();
    int d = t;
    if (d >= HD) return;
    float tt = temp[n];
    float iq = invq[b * 192 + n * HD + d];
    float row[HD];
#pragma unroll
    for (int e = 0; e < HD; ++e)
        row[e] = sums[d * HD + e] * iq * invk[b * 192 + n * HD + e] * tt;
    float m = row[0];
#pragma unroll
    for (int e = 1; e < HD; ++e) m = fmaxf(m, row[e]);
    float ssum = 0.f;
#pragma unroll
    for (int e = 0; e < HD; ++e) { row[e] = expf(row[e] - m); ssum += row[e]; }
    float is = 1.f / ssum;
#pragma unroll
    for (int e = 0; e < HD; ++e) attn[(long)bn * 576 + d * HD + e] = row[e] * is;
}

// ---------- out[d,p] = sum_e attn[d,e] * v[e,p] ----------
__global__ void attnapply_k(const float* __restrict__ attn, const float* __restrict__ v,
                            long vB, float* __restrict__ out, long outB) {
    int p = blockIdx.x * 256 + threadIdx.x;
    int bn = blockIdx.y;
    int b = bn >> 3, n = bn & 7;
    __shared__ float a[576];
    for (int i = threadIdx.x; i < 576; i += 256) a[i] = attn[(long)bn * 576 + i];
    __syncthreads();
    const float* vp = v + (long)b * vB + (long)(n * HD) * HW + p;
    float acc[HD];
#pragma unroll
    for (int d = 0; d < HD; ++d) acc[d] = 0.f;
    for (int e = 0; e < HD; ++e) {
        float vv = vp[(long)e * HW];
#pragma unroll
        for (int d = 0; d < HD; ++d) acc[d] += a[d * HD + e] * vv;
    }
    float* op = out + (long)b * outB + (long)(n * HD) * HW + p;
#pragma unroll
    for (int d = 0; d < HD; ++d) op[(long)d * HW] = acc[d];
}

extern "C" void kernel_launch(void* const* d_in, const int* in_sizes, int n_in,
                              void* d_out, int out_size, void* d_ws, size_t ws_size,
                              hipStream_t stream) {
    const float* x        = (const float*)d_in[0];
    const float* w_qkv1   = (const float*)d_in[1];
    const float* w_qkv1dw = (const float*)d_in[2];
    const float* w_proj1  = (const float*)d_in[3];
    const float* w_fdfp1  = (const float*)d_in[4];
    const float* w_fdfp2  = (const float*)d_in[5];
    const float* w_kv2    = (const float*)d_in[6];
    const float* w_kv2dw  = (const float*)d_in[7];
    const float* w_proj2  = (const float*)d_in[8];
    const float* temp     = (const float*)d_in[9];
    float* out = (float*)d_out;
    float* ws  = (float*)d_ws;
    dim3 blk(256);
    const int BIG = 1 << 20;

    // ---- init fp16 weights/bases ----
    cvt16_k<<<432, blk, 0, stream>>>(w_qkv1, (half_t*)(ws + H_WQKV), 110592);
    cvt16_k<<<576, blk, 0, stream>>>(w_fdfp1, (half_t*)(ws + H_W1), 147456);
    cvt16_k<<<576, blk, 0, stream>>>(w_fdfp2, (half_t*)(ws + H_W2), 147456);
    cvt16_k<<<144, blk, 0, stream>>>(w_proj2, (half_t*)(ws + H_PRJ), 36864);
    initB1t_k<<<80, blk, 0, stream>>>((half_t*)(ws + H_B1T));
    initB2h_k<<<256, blk, 0, stream>>>((half_t*)(ws + H_B2));
    initB3h_k<<<256, blk, 0, stream>>>((half_t*)(ws + H_B3));
    initB4t_k<<<80, blk, 0, stream>>>((half_t*)(ws + H_B4T));
    fusew_k<<<384, 192, 0, stream>>>(w_kv2, w_proj1, (half_t*)(ws + H_WF));

    // ---- fdfp(x) -> q2 (+ fused q2 norms) ----
    k1m<5, 0><<<dim3(192, 1, 4), blk, 0, stream>>>(
        x, XB, (long)HW, 128L, BIG, 0L, 128,
        (const uint*)(ws + H_B1T),
        ws + CB0, LT_B, (long)FP, LT_ROW, 80, LT_PART, nullptr);
    k2m<0, 0><<<dim3(4, 60, 4), blk, 0, stream>>>(
        (const half_t*)(ws + H_B2), 256,
        ws + CB0, LT_B, 128, LT_ROW, LT_PART,
        ws + CB1, LT_B, 128, LT_ROW, LT_PART);
    // fused W1 -> gelu -> W2: CB1 -> CB0
    kff<<<dim3(160, 4), 512, 0, stream>>>(
        (const half_t*)(ws + H_W1), (const half_t*)(ws + H_W2),
        ws + CB1, ws + CB0);
    k2m<0, 0><<<dim3(4, 60, 4), blk, 0, stream>>>(
        (const half_t*)(ws + H_B3), 256,
        ws + CB0, LT_B, 128, LT_ROW, LT_PART,
        ws + CB1, LT_B, 128, LT_ROW, LT_PART);
    k1m<4, 1><<<dim3(192, 1, 4), blk, 0, stream>>>(
        ws + CB1, LT_B, (long)FP, LT_ROW, 80, LT_PART, 160,
        (const uint*)(ws + H_B4T),
        ws + OFF_Q2, XB, (long)HW, 128L, BIG, 0L, ws + SM_INVQ2);

    // ---- stage 1: qkv = dw3(conv1x1(x)) in 3 chunks (+ fused q1/k1 norms) ----
    for (int ch = 0; ch < 3; ++ch) {
        k2m<0, 0><<<dim3(3, 64, 4), blk, 0, stream>>>(
            (const half_t*)(ws + H_WQKV) + (long)ch * 192 * 192, 192,
            x, XB, BIG, (long)HW, 0L,
            ws + OFF_T1, XB, BIG, (long)HW, 0L);
        dw3_k<<<dim3(192, 4), blk, 0, stream>>>(
            ws + OFF_T1, XB, w_qkv1dw + ch * 192 * 9,
            ws + (long)ch * 192 * HW, (long)576 * HW,
            ch == 2 ? 0 : 192,
            ch == 0 ? ws + SM_INVQ1 : ws + SM_INVK1);
    }
    // stage-1 partials at OFF_T1: qkv [0..37.7M) live, OFF_T1 [37.7M..] free.
    gramf_k<<<dim3(32, GSL), 576, 0, stream>>>(
        ws, (long)576 * HW, ws + (long)192 * HW, (long)576 * HW, ws + OFF_T1);
    softmax_k<<<32, blk, 0, stream>>>(ws + OFF_T1, ws + SM_INVQ1, ws + SM_INVK1, temp, ws + SM_ATT);
    attnapply_k<<<dim3(64, 32), blk, 0, stream>>>(
        ws + SM_ATT, ws + (long)384 * HW, (long)576 * HW, ws + OFF_T1, XB);

    // ---- kv2 = dw3(conv1x1(out1, Wf)) (+ fused k2 norms) ----
    k2m<0, 0><<<dim3(6, 64, 4), blk, 0, stream>>>(
        (const half_t*)(ws + H_WF), 192,
        ws + OFF_T1, XB, BIG, (long)HW, 0L,
        ws + OFF_KT, (long)384 * HW, BIG, (long)HW, 0L);
    dw3_k<<<dim3(384, 4), blk, 0, stream>>>(
        ws + OFF_KT, (long)384 * HW, w_kv2dw, ws + OFF_KF, (long)384 * HW,
        192, ws + SM_INVK2);

    // ---- stage 2 attention ----
    // partials at ws[0..1.18M): kv2 pre-dw tmp region, dead after dw3.
    // (NOT OFF_T1 — that aliases kv2 batch 2, the r6-r8 corruption.)
    gramf_k<<<dim3(32, GSL), 576, 0, stream>>>(
        ws + OFF_Q2, XB, ws + OFF_KF, (long)384 * HW, ws + OFF_KT);
    softmax_k<<<32, blk, 0, stream>>>(ws + OFF_KT, ws + SM_INVQ2, ws + SM_INVK2, temp, ws + SM_ATT);
    attnapply_k<<<dim3(64, 32), blk, 0, stream>>>(
        ws + SM_ATT, ws + OFF_KF + (long)192 * HW, (long)384 * HW, ws + OFF_O2, XB);
    k2m<0, 0><<<dim3(3, 64, 4), blk, 0, stream>>>(
        (const half_t*)(ws + H_PRJ), 192,
        ws + OFF_O2, XB, BIG, (long)HW, 0L,
        out, XB, BIG, (long)HW, 0L);
}